// Round 8
// baseline (519.200 us; speedup 1.0000x reference)
//
#include <hip/hip_runtime.h>
#include <hip/hip_bf16.h>

using bf16 = __hip_bfloat16;

#define D_DIM   192
#define N_DIM   3072
#define NHEAD   4
#define T_SEQ   1024
#define HN      12288      // NHEAD * N_DIM
#define NP2     1536       // N_DIM/2
#define VOCABSZ 256
#define NLAYER  4
#define LN_EPS  1e-5f
#define TWO_PI  6.2831853071795864f

typedef __attribute__((ext_vector_type(8)))  short          s16x8;
typedef __attribute__((ext_vector_type(8)))  unsigned short u16x8;
typedef __attribute__((ext_vector_type(4)))  float          f32x4;
typedef __attribute__((ext_vector_type(16))) float          f32x16;

__device__ __forceinline__ float b2f(bf16 v) { return __bfloat162float(v); }
__device__ __forceinline__ float us2f(unsigned short u) {
    unsigned int x = ((unsigned int)u) << 16;
    return __builtin_bit_cast(float, x);
}
__device__ __forceinline__ unsigned short f2us(float f) {
    bf16 b = __float2bfloat16(f);
    return __builtin_bit_cast(unsigned short, b);
}

// sentinel: encode ws_size into output (fires only if ws too small)
__global__ void fill_out(float* __restrict__ out, float val, int nelem) {
    int i = blockIdx.x * 256 + threadIdx.x;
    if (i < nelem) out[i] = val;
}

// ---------------------------------------------------------------------------
// Tiled transpose + fp32->bf16: in fp32 [R][C] -> out bf16 [C][R].
// ---------------------------------------------------------------------------
__global__ void t_cvt(const float* __restrict__ in, bf16* __restrict__ out,
                      int R, int C, long inZ, long outZ) {
    __shared__ float tile[64][65];
    in  += inZ  * blockIdx.z;
    out += outZ * blockIdx.z;
    const int tx = threadIdx.x & 63, ty = threadIdx.x >> 6;
    const int r0 = blockIdx.y * 64, c0 = blockIdx.x * 64;
    #pragma unroll
    for (int rr = 0; rr < 16; rr++) {
        int row = ty * 16 + rr;
        tile[row][tx] = in[(size_t)(r0 + row) * C + c0 + tx];
    }
    __syncthreads();
    #pragma unroll
    for (int rr = 0; rr < 16; rr++) {
        int row = ty * 16 + rr;
        out[(size_t)(c0 + row) * R + r0 + tx] = __float2bfloat16(tile[tx][row]);
    }
}

// ---------------------------------------------------------------------------
// Wave-per-row LN family (64 threads/block, 3 elems/lane, butterfly reduce)
// ---------------------------------------------------------------------------
__device__ __forceinline__ void wave_sum2(float& s, float& ss) {
    #pragma unroll
    for (int off = 1; off < 64; off <<= 1) {
        s  += __shfl_xor(s,  off, 64);
        ss += __shfl_xor(ss, off, 64);
    }
}

// writes fp32 x AND bf16 xb (bf16 A-operand for dgemm128)
__global__ void k_embed(const int* __restrict__ idx, const float* __restrict__ emb,
                        const float* __restrict__ pos, float* __restrict__ x,
                        bf16* __restrict__ xb) {
    int t = blockIdx.x, l = threadIdx.x;
    int tok = idx[t];
    const float* e = emb + tok * D_DIM;
    const float* p = pos + t * D_DIM;
    float v0 = e[l] + p[l], v1 = e[l + 64] + p[l + 64], v2 = e[l + 128] + p[l + 128];
    float s = v0 + v1 + v2, ss = v0 * v0 + v1 * v1 + v2 * v2;
    wave_sum2(s, ss);
    float m = s / D_DIM, r = rsqrtf(ss / D_DIM - m * m + LN_EPS);
    float* xr = x + t * D_DIM;
    bf16*  xo = xb + (size_t)t * D_DIM;
    float o0 = (v0 - m) * r, o1 = (v1 - m) * r, o2 = (v2 - m) * r;
    xr[l] = o0; xr[l + 64] = o1; xr[l + 128] = o2;
    xo[l] = __float2bfloat16(o0);
    xo[l + 64] = __float2bfloat16(o1);
    xo[l + 128] = __float2bfloat16(o2);
}

__global__ void k_ln(float* __restrict__ buf) {
    int l = threadIdx.x;
    float* row = buf + (size_t)blockIdx.x * D_DIM;
    float v0 = row[l], v1 = row[l + 64], v2 = row[l + 128];
    float s = v0 + v1 + v2, ss = v0 * v0 + v1 * v1 + v2 * v2;
    wave_sum2(s, ss);
    float m = s / D_DIM, r = rsqrtf(ss / D_DIM - m * m + LN_EPS);
    row[l] = (v0 - m) * r; row[l + 64] = (v1 - m) * r; row[l + 128] = (v2 - m) * r;
}

// outb = bf16( LN(P0row + P1row) )  — ykv slab combine + LN + bf16 cast
__global__ void k_ln2b(const float* __restrict__ P0, const float* __restrict__ P1,
                       bf16* __restrict__ outb) {
    int l = threadIdx.x;
    size_t off = (size_t)blockIdx.x * D_DIM;
    const float* r0 = P0 + off;
    const float* r1 = P1 + off;
    float v0 = r0[l] + r1[l];
    float v1 = r0[l + 64] + r1[l + 64];
    float v2 = r0[l + 128] + r1[l + 128];
    float s = v0 + v1 + v2, ss = v0 * v0 + v1 * v1 + v2 * v2;
    wave_sum2(s, ss);
    float m = s / D_DIM, r = rsqrtf(ss / D_DIM - m * m + LN_EPS);
    bf16* o = outb + off;
    o[l]       = __float2bfloat16((v0 - m) * r);
    o[l + 64]  = __float2bfloat16((v1 - m) * r);
    o[l + 128] = __float2bfloat16((v2 - m) * r);
}

// x = LN(x + LN(sum of NSLAB split-K partial slabs)); also writes xb (bf16)
template <int NSLAB>
__global__ void k_resid(float* __restrict__ x, const float* __restrict__ P,
                        bf16* __restrict__ xb) {
    int l = threadIdx.x, t = blockIdx.x;
    float y0 = 0.f, y1 = 0.f, y2 = 0.f;
    #pragma unroll
    for (int p = 0; p < NSLAB; p++) {
        const float* r = P + (size_t)p * T_SEQ * D_DIM + (size_t)t * D_DIM;
        y0 += r[l]; y1 += r[l + 64]; y2 += r[l + 128];
    }
    float* xr = x + (size_t)t * D_DIM;
    float s = y0 + y1 + y2, ss = y0 * y0 + y1 * y1 + y2 * y2;
    wave_sum2(s, ss);
    float m1 = s / D_DIM, r1 = rsqrtf(ss / D_DIM - m1 * m1 + LN_EPS);
    float v0 = xr[l] + (y0 - m1) * r1;
    float v1 = xr[l + 64] + (y1 - m1) * r1;
    float v2 = xr[l + 128] + (y2 - m1) * r1;
    s = v0 + v1 + v2; ss = v0 * v0 + v1 * v1 + v2 * v2;
    wave_sum2(s, ss);
    float m2 = s / D_DIM, r2 = rsqrtf(ss / D_DIM - m2 * m2 + LN_EPS);
    float o0 = (v0 - m2) * r2, o1 = (v1 - m2) * r2, o2 = (v2 - m2) * r2;
    xr[l] = o0; xr[l + 64] = o1; xr[l + 128] = o2;
    bf16* xo = xb + (size_t)t * D_DIM;
    xo[l] = __float2bfloat16(o0);
    xo[l + 64] = __float2bfloat16(o1);
    xo[l + 128] = __float2bfloat16(o2);
}

// RoPE cos/sin tables, interleaved bf16 pairs csT[t][p] = (cos, sin)
__global__ void k_tables(ushort2* __restrict__ csT) {
    int gid = blockIdx.x * 256 + threadIdx.x;
    int t = gid / NP2, p = gid % NP2;
    float qf = (float)(2 * p);
    float f = exp2f(qf * (-16.0f / 3072.0f)) * (1.0f / (float)TWO_PI);
    float ph = fmodf((float)t * f, 1.0f) * (float)TWO_PI;
    ushort2 cs;
    cs.x = f2us(cosf(ph));
    cs.y = f2us(sinf(ph));
    csT[gid] = cs;
}

// ---------------------------------------------------------------------------
// scores64: partial scores, split-K=2 over grid.y (1088 blocks).
//   kh=0: lower-K half -> lower tile (i,j), masked if diag.
//   kh=1 off-diag: upper-K half, swapped operands -> dead upper slot (j,i)
//     in (t,s) orientation. kh=1 diag: masked partial -> dbuf slab.
// ykv dual-A MFMA combines partials in fp32 (no k_comb).
// 64x64 tile, 4 waves x one 32x32x16 MFMA acc, BK=64, dbuf LDS + 2-deep
// register prefetch, LDS-staged coalesced epilogue. XCD remap (136=8*17).
// ---------------------------------------------------------------------------
__launch_bounds__(256, 4)
__global__ void scores64(const bf16* __restrict__ qr, bf16* __restrict__ sc,
                         bf16* __restrict__ dbuf) {
    const int h  = blockIdx.z;
    const int kh = blockIdx.y;                     // K-half
    const int orig = blockIdx.x;
    const int L = (orig & 7) * 17 + (orig >> 3);   // bijective: 136 = 8*17
    int i = 0;
    while (((i + 1) * (i + 2)) >> 1 <= L) ++i;
    int j = L - ((i * (i + 1)) >> 1);
    const int t0 = i * 64, s0 = j * 64;
    const bool diag = (i == j);

    int arow = t0, brow = s0;
    if (kh == 1 && !diag) { arow = s0; brow = t0; }

    __shared__ short As[2][64][72];
    __shared__ short Bs[2][64][72];

    const int tid = threadIdx.x;
    const int lane = tid & 63, w = tid >> 6;
    const int wtm = (w >> 1) * 32, wtn = (w & 1) * 32;
    const int l31 = lane & 31, lhi = lane >> 5;
    const int r0 = tid >> 2;
    const int kq = (tid & 3) * 16;

    const int kBeg = kh * (N_DIM / 2);
    const bf16* gA = qr + (size_t)(arow + r0) * HN + h * N_DIM + kBeg + kq;
    const bf16* gB = qr + (size_t)(brow + r0) * HN + h * N_DIM + kBeg + kq;

    u16x8 pa0, pa1, pb0, pb1;
    u16x8 qa0, qa1, qb0, qb1;
    auto load0 = [&](int k0) {
        pa0 = *(const u16x8*)(gA + k0);
        pa1 = *(const u16x8*)(gA + k0 + 8);
        pb0 = *(const u16x8*)(gB + k0);
        pb1 = *(const u16x8*)(gB + k0 + 8);
    };
    auto load1 = [&](int k0) {
        qa0 = *(const u16x8*)(gA + k0);
        qa1 = *(const u16x8*)(gA + k0 + 8);
        qb0 = *(const u16x8*)(gB + k0);
        qb1 = *(const u16x8*)(gB + k0 + 8);
    };
    auto dep0 = [&](int buf) {
        *(u16x8*)&As[buf][r0][kq]     = pa0;
        *(u16x8*)&As[buf][r0][kq + 8] = pa1;
        *(u16x8*)&Bs[buf][r0][kq]     = pb0;
        *(u16x8*)&Bs[buf][r0][kq + 8] = pb1;
    };
    auto dep1 = [&](int buf) {
        *(u16x8*)&As[buf][r0][kq]     = qa0;
        *(u16x8*)&As[buf][r0][kq + 8] = qa1;
        *(u16x8*)&Bs[buf][r0][kq]     = qb0;
        *(u16x8*)&Bs[buf][r0][kq + 8] = qb1;
    };

    f32x16 acc;
    #pragma unroll
    for (int r = 0; r < 16; r++) acc[r] = 0.f;

    auto mfma_step = [&](int buf) {
        #pragma unroll
        for (int ks = 0; ks < 4; ks++) {
            s16x8 a = *(const s16x8*)&As[buf][wtm + l31][ks * 16 + lhi * 8];
            s16x8 b = *(const s16x8*)&Bs[buf][wtn + l31][ks * 16 + lhi * 8];
            acc = __builtin_amdgcn_mfma_f32_32x32x16_bf16(a, b, acc, 0, 0, 0);
        }
    };

    const int NIT = (N_DIM / 2) / 64;   // 24 (even)
    load0(0);
    load1(64);
    dep0(0);
    __syncthreads();

    for (int k = 0; k < NIT; k += 2) {
        if (k + 2 < NIT) load0((k + 2) * 64);
        mfma_step(0);
        if (k + 1 < NIT) dep1(1);
        __syncthreads();
        if (k + 1 < NIT) {
            if (k + 3 < NIT) load1((k + 3) * 64);
            mfma_step(1);
            if (k + 2 < NIT) dep0(0);
            __syncthreads();
        }
    }

    __syncthreads();
    short (*S)[72] = (short(*)[72])&As[0][0][0];
    const bool trS = (kh == 1) && !diag;
    #pragma unroll
    for (int r = 0; r < 16; r++) {
        int rr = wtm + (r & 3) + 8 * (r >> 2) + 4 * lhi;
        int cc = wtn + l31;
        float v = acc[r];
        if (diag && cc >= rr) v = 0.f;
        if (trS) S[cc][rr] = (short)f2us(v);
        else     S[rr][cc] = (short)f2us(v);
    }
    __syncthreads();
    if (kh == 1 && diag) {
        bf16* P = dbuf + (size_t)(h * 16 + i) * 4096;
        #pragma unroll
        for (int e = 0; e < 2; e++) {
            int idxe = tid + e * 256;
            int row = idxe >> 3, cg = (idxe & 7) * 8;
            u16x8 v = *(const u16x8*)&S[row][cg];
            *(u16x8*)(P + row * 64 + cg) = v;
        }
    } else {
        bf16* C = sc + (size_t)h * T_SEQ * T_SEQ;
        #pragma unroll
        for (int e = 0; e < 2; e++) {
            int idxe = tid + e * 256;
            int row = idxe >> 3, cg = (idxe & 7) * 8;
            u16x8 v = *(const u16x8*)&S[row][cg];
            *(u16x8*)(C + (size_t)(arow + row) * T_SEQ + brow + cg) = v;
        }
    }
}

// ---------------------------------------------------------------------------
// scores fallback (no qr buffer): 64x64, rope fused into staging.
// ---------------------------------------------------------------------------
__device__ __forceinline__ void stage_rope8(short* dst, const bf16* src,
                                            const ushort2* csP) {
    u16x8 v  = *(const u16x8*)src;
    u16x8 cs = *(const u16x8*)csP;
    u16x8 o;
    #pragma unroll
    for (int i = 0; i < 4; i++) {
        float e  = us2f(v[2 * i]), od = us2f(v[2 * i + 1]);
        float c  = us2f(cs[2 * i]), s = us2f(cs[2 * i + 1]);
        o[2 * i]     = f2us(e * c - od * s);
        o[2 * i + 1] = f2us(od * c + e * s);
    }
    *(u16x8*)dst = o;
}

__launch_bounds__(256)
__global__ void scores_fused(const bf16* __restrict__ xs,
                             const ushort2* __restrict__ csT,
                             bf16* __restrict__ sc) {
    const int h  = blockIdx.z;
    const int s0 = blockIdx.x * 64, t0 = blockIdx.y * 64;
    if (s0 > t0) return;
    __shared__ short As[64][40];
    __shared__ short Bs[64][40];
    const int tid  = threadIdx.x;
    const int srow = tid >> 2, kq = (tid & 3) * 8;
    const int lane = tid & 63, w = tid >> 6, qd = lane >> 4, lc = lane & 15;
    const int tA = t0 + srow, tB = s0 + srow;
    const bf16* gA = xs + (size_t)tA * HN + h * N_DIM + kq;
    const bf16* gB = xs + (size_t)tB * HN + h * N_DIM + kq;
    const ushort2* cA = csT + (size_t)tA * NP2 + (kq >> 1);
    const ushort2* cB = csT + (size_t)tB * NP2 + (kq >> 1);
    f32x4 acc[4] = {{0.f,0.f,0.f,0.f},{0.f,0.f,0.f,0.f},
                    {0.f,0.f,0.f,0.f},{0.f,0.f,0.f,0.f}};
    for (int k0 = 0; k0 < N_DIM; k0 += 32) {
        stage_rope8(&As[srow][kq], gA + k0, cA + (k0 >> 1));
        stage_rope8(&Bs[srow][kq], gB + k0, cB + (k0 >> 1));
        __syncthreads();
        s16x8 a = *(const s16x8*)&As[w * 16 + lc][qd * 8];
        #pragma unroll
        for (int j = 0; j < 4; j++) {
            s16x8 b = *(const s16x8*)&Bs[j * 16 + lc][qd * 8];
            acc[j] = __builtin_amdgcn_mfma_f32_16x16x32_bf16(a, b, acc[j], 0, 0, 0);
        }
        __syncthreads();
    }
    bf16* C = sc + (size_t)h * T_SEQ * T_SEQ;
    const bool diag = (s0 == t0);
    const int tbase = t0 + w * 16 + qd * 4;
    #pragma unroll
    for (int j = 0; j < 4; j++) {
        int s = s0 + j * 16 + lc;
        #pragma unroll
        for (int r = 0; r < 4; r++) {
            int t = tbase + r;
            C[(size_t)t * T_SEQ + s] =
                __float2bfloat16((!diag || s < t) ? acc[j][r] : 0.f);
        }
    }
}

// ---------------------------------------------------------------------------
// dgemm128: 128x128 tile, 4 waves x (64x64 = 2x2 of 32x32x16 MFMA accs),
// K=192 (BK=32), double-buffered LDS + 2-deep register prefetch, LDS-staged
// coalesced epilogue (relu / rope / gate). TA = bf16 (main, pre-cast A) or
// float (fallback gate).
// ---------------------------------------------------------------------------
template <int EPI, bool WQR, typename TA>
__launch_bounds__(256)
__global__ void dgemm128(const TA* __restrict__ A, const bf16* __restrict__ Bt,
                         bf16* __restrict__ xs, bf16* __restrict__ qr,
                         const ushort2* __restrict__ csT) {
    __shared__ __align__(16) short pool[2 * 2 * 128 * 40];   // 40 KB
    short (*As)[128][40] = (short(*)[128][40])pool;
    short (*Bs)[128][40] = (short(*)[128][40])(pool + 2 * 128 * 40);

    const int tid = threadIdx.x;
    const int lane = tid & 63, w = tid >> 6;
    const int l31 = lane & 31, lhi = lane >> 5;
    const int wtm = (w >> 1) * 64, wtn = (w & 1) * 64;
    const int n0 = blockIdx.x * 128, m0 = blockIdx.y * 128;
    if constexpr (EPI == 2) A += (size_t)(n0 / N_DIM) * T_SEQ * D_DIM;

    const int r0 = tid >> 2, r1 = r0 + 64;
    const int kq = (tid & 3) * 8;

    const TA*   gA = A  + kq;
    const bf16* gB = Bt + kq;

    // two register sets for 2-deep prefetch
    float4 fa00, fa01, fa02, fa03, fa10, fa11, fa12, fa13;
    u16x8 ba00, ba01, ba10, ba11;
    u16x8 pb00, pb01, pb10, pb11;
    auto load0 = [&](int k0) {
        if constexpr (__is_same(TA, float)) {
            const TA* a0 = gA + (size_t)(m0 + r0) * D_DIM + k0;
            const TA* a1 = gA + (size_t)(m0 + r1) * D_DIM + k0;
            fa00 = *(const float4*)a0; fa01 = *(const float4*)(a0 + 4);
            fa02 = *(const float4*)a1; fa03 = *(const float4*)(a1 + 4);
        } else {
            ba00 = *(const u16x8*)(gA + (size_t)(m0 + r0) * D_DIM + k0);
            ba01 = *(const u16x8*)(gA + (size_t)(m0 + r1) * D_DIM + k0);
        }
        pb00 = *(const u16x8*)(gB + (size_t)(n0 + r0) * D_DIM + k0);
        pb01 = *(const u16x8*)(gB + (size_t)(n0 + r1) * D_DIM + k0);
    };
    auto load1 = [&](int k0) {
        if constexpr (__is_same(TA, float)) {
            const TA* a0 = gA + (size_t)(m0 + r0) * D_DIM + k0;
            const TA* a1 = gA + (size_t)(m0 + r1) * D_DIM + k0;
            fa10 = *(const float4*)a0; fa11 = *(const float4*)(a0 + 4);
            fa12 = *(const float4*)a1; fa13 = *(const float4*)(a1 + 4);
        } else {
            ba10 = *(const u16x8*)(gA + (size_t)(m0 + r0) * D_DIM + k0);
            ba11 = *(const u16x8*)(gA + (size_t)(m0 + r1) * D_DIM + k0);
        }
        pb10 = *(const u16x8*)(gB + (size_t)(n0 + r0) * D_DIM + k0);
        pb11 = *(const u16x8*)(gB + (size_t)(n0 + r1) * D_DIM + k0);
    };
    auto dep0 = [&](int buf) {
        if constexpr (__is_same(TA, float)) {
            u16x8 o0, o1;
            o0[0] = f2us(fa00.x); o0[1] = f2us(fa00.y); o0[2] = f2us(fa00.z); o0[3] = f2us(fa00.w);
            o0[4] = f2us(fa01.x); o0[5] = f2us(fa01.y); o0[6] = f2us(fa01.z); o0[7] = f2us(fa01.w);
            o1[0] = f2us(fa02.x); o1[1] = f2us(fa02.y); o1[2] = f2us(fa02.z); o1[3] = f2us(fa02.w);
            o1[4] = f2us(fa03.x); o1[5] = f2us(fa03.y); o1[6] = f2us(fa03.z); o1[7] = f2us(fa03.w);
            *(u16x8*)&As[buf][r0][kq] = o0;
            *(u16x8*)&As[buf][r1][kq] = o1;
        } else {
            *(u16x8*)&As[buf][r0][kq] = ba00;
            *(u16x8*)&As[buf][r1][kq] = ba01;
        }
        *(u16x8*)&Bs[buf][r0][kq] = pb00;
        *(u16x8*)&Bs[buf][r1][kq] = pb01;
    };
    auto dep1 = [&](int buf) {
        if constexpr (__is_same(TA, float)) {
            u16x8 o0, o1;
            o0[0] = f2us(fa10.x); o0[1] = f2us(fa10.y); o0[2] = f2us(fa10.z); o0[3] = f2us(fa10.w);
            o0[4] = f2us(fa11.x); o0[5] = f2us(fa11.y); o0[6] = f2us(fa11.z); o0[7] = f2us(fa11.w);
            o1[0] = f2us(fa12.x); o1[1] = f2us(fa12.y); o1[2] = f2us(fa12.z); o1[3] = f2us(fa12.w);
            o1[4] = f2us(fa13.x); o1[5] = f2us(fa13.y); o1[6] = f2us(fa13.z); o1[7] = f2us(fa13.w);
            *(u16x8*)&As[buf][r0][kq] = o0;
            *(u16x8*)&As[buf][r1][kq] = o1;
        } else {
            *(u16x8*)&As[buf][r0][kq] = ba10;
            *(u16x8*)&As[buf][r1][kq] = ba11;
        }
        *(u16x8*)&Bs[buf][r0][kq] = pb10;
        *(u16x8*)&Bs[buf][r1][kq] = pb11;
    };

    // 4 named 32x32 accumulators (static indexing — no scratch)
    f32x16 acc00, acc01, acc10, acc11;
    #pragma unroll
    for (int r = 0; r < 16; r++) { acc00[r] = 0.f; acc01[r] = 0.f; acc10[r] = 0.f; acc11[r] = 0.f; }

    auto mfma_step = [&](int buf) {
        #pragma unroll
        for (int ks = 0; ks < 2; ks++) {
            s16x8 a0 = *(const s16x8*)&As[buf][wtm + l31][ks * 16 + lhi * 8];
            s16x8 a1 = *(const s16x8*)&As[buf][wtm + 32 + l31][ks * 16 + lhi * 8];
            s16x8 b0 = *(const s16x8*)&Bs[buf][wtn + l31][ks * 16 + lhi * 8];
            s16x8 b1 = *(const s16x8*)&Bs[buf][wtn + 32 + l31][ks * 16 + lhi * 8];
            acc00 = __builtin_amdgcn_mfma_f32_32x32x16_bf16(a0, b0, acc00, 0, 0, 0);
            acc01 = __builtin_amdgcn_mfma_f32_32x32x16_bf16(a0, b1, acc01, 0, 0, 0);
            acc10 = __builtin_amdgcn_mfma_f32_32x32x16_bf16(a1, b0, acc10, 0, 0, 0);
            acc11 = __builtin_amdgcn_mfma_f32_32x32x16_bf16(a1, b1, acc11, 0, 0, 0);
        }
    };

    const int NIT = D_DIM / 32;   // 6 (even)
    load0(0);
    load1(32);
    dep0(0);
    __syncthreads();
    for (int k = 0; k < NIT; k += 2) {
        if (k + 2 < NIT) load0((k + 2) * 32);
        mfma_step(0);
        if (k + 1 < NIT) dep1(1);
        __syncthreads();
        if (k + 1 < NIT) {
            if (k + 3 < NIT) load1((k + 3) * 32);
            mfma_step(1);
            if (k + 2 < NIT) dep0(0);
            __syncthreads();
        }
    }

    // -------- LDS-staged epilogue --------
    short (*S)[136] = (short(*)[136])pool; // 128 x 136 shorts = 34.8 KB <= 40 KB
    #pragma unroll
    for (int r = 0; r < 16; r++) {
        int rb = (r & 3) + 8 * (r >> 2) + 4 * lhi;
        S[wtm + rb     ][wtn + l31     ] = (short)f2us(fmaxf(acc00[r], 0.f));
        S[wtm + rb     ][wtn + 32 + l31] = (short)f2us(fmaxf(acc01[r], 0.f));
        S[wtm + 32 + rb][wtn + l31     ] = (short)f2us(fmaxf(acc10[r], 0.f));
        S[wtm + 32 + rb][wtn + 32 + l31] = (short)f2us(fmaxf(acc11[r], 0.f));
    }
    __syncthreads();
    #pragma unroll
    for (int e = 0; e < 8; e++) {
        int idxe = tid + e * 256;
        int row = idxe >> 4, cg = idxe & 15;
        u16x8 v = *(const u16x8*)&S[row][cg * 8];
        int t = m0 + row, ngg = n0 + cg * 8;
        size_t ci = (size_t)t * HN + ngg;
        if constexpr (EPI == 1) {
            *(u16x8*)(xs + ci) = v;
            if constexpr (WQR) {
                int p0 = (ngg % N_DIM) >> 1;
                u16x8 cs8 = *(const u16x8*)&csT[(size_t)t * NP2 + p0];
                u16x8 o;
                #pragma unroll
                for (int q = 0; q < 4; q++) {
                    float ev = us2f(v[2 * q]), ov = us2f(v[2 * q + 1]);
                    float c = us2f(cs8[2 * q]), s = us2f(cs8[2 * q + 1]);
                    o[2 * q]     = f2us(ev * c - ov * s);
                    o[2 * q + 1] = f2us(ov * c + ev * s);
                }
                *(u16x8*)(qr + ci) = o;
            }
        } else {
            u16x8 g = *(const u16x8*)(xs + ci);
            u16x8 o;
            #pragma unroll
            for (int q = 0; q < 8; q++) o[q] = f2us(us2f(g[q]) * us2f(v[q]));
            *(u16x8*)(xs + ci) = o;
        }
    }
}

// ---------------------------------------------------------------------------
// mfma_gemm (64x64): MODE 0 = plain, 1 = causal split-K=2 WITH dual-A partial
// combine (replaces k_comb), 2 = split-K slabs over z, 3 = causal full
// (fallback). 32x32x16 MFMA, BK=64, double-buffered LDS + 2-deep prefetch.
// ---------------------------------------------------------------------------
template <typename TA, int MODE>
__launch_bounds__(256)
__global__ void mfma_gemm(const TA* __restrict__ A, const bf16* __restrict__ Bt,
                          float* __restrict__ C, const bf16* __restrict__ aux,
                          int K, int kSeg, int lda, int ldb, int ldc,
                          long aZ, long bZ, long cZ) {
    constexpr bool DUAL = (MODE == 1);
    constexpr int TILES = DUAL ? 6 : 4;
    __shared__ __align__(16) short pool[TILES * 64 * 72];
    short (*As)[64][72] = (short(*)[64][72])pool;
    short (*Bs)[64][72] = (short(*)[64][72])(pool + 2 * 64 * 72);
    short (*Ms)[64][72] = (short(*)[64][72])(pool + 4 * 64 * 72);

    const int z = blockIdx.z;
    const int tid = threadIdx.x;
    const int n0 = blockIdx.x * 64, m0 = blockIdx.y * 64;
    const int srow = tid >> 2, sk = (tid & 3) * 16;
    const int lane = tid & 63, w = tid >> 6;
    const int l31 = lane & 31, lhi = lane >> 5;
    const int wm = (w >> 1) * 32, wn = (w & 1) * 32;

    int kBeg, kEnd, zh = 0;
    if constexpr (MODE == 1) {
        zh = z >> 1;
        const int seg = z & 1;
        A += aZ * zh;
        C += cZ * zh + bZ * seg;
        const int kc = (m0 + 64 < K) ? m0 + 64 : K;
        const int half0 = ((kc + 127) >> 7) << 6;   // ceil(kc/128)*64
        kBeg = seg ? half0 : 0;
        kEnd = seg ? kc : half0;
    } else if constexpr (MODE == 2) {
        A += aZ * z; Bt += bZ * z; C += cZ * z;
        kBeg = z * kSeg; kEnd = kBeg + kSeg;
    } else if constexpr (MODE == 3) {
        A += aZ * z; Bt += bZ * z; C += cZ * z;
        kBeg = 0; kEnd = (m0 + 64 < K) ? m0 + 64 : K;
    } else {
        A += aZ * z; Bt += bZ * z; C += cZ * z;
        kBeg = 0; kEnd = K;
    }

    const TA*   ga = A  + (size_t)(m0 + srow) * lda + sk;
    const bf16* gb = Bt + (size_t)(n0 + srow) * ldb + sk;

    auto msrc = [&](int k0) -> const bf16* {
        if (k0 == m0)
            return aux + (size_t)(zh * 16 + (m0 >> 6)) * 4096
                       + (size_t)srow * 64 + sk;
        return (const bf16*)A + (size_t)(k0 + srow) * lda + m0 + sk;
    };

    float4 f00, f01, f02, f03, f10, f11, f12, f13;
    u16x8 pa00, pa01, pa10, pa11, pb00, pb01, pb10, pb11;
    u16x8 pm00, pm01, pm10, pm11;
    auto load0 = [&](int k0) {
        if constexpr (__is_same(TA, float)) {
            f00 = *(const float4*)(ga + k0);
            f01 = *(const float4*)(ga + k0 + 4);
            f02 = *(const float4*)(ga + k0 + 8);
            f03 = *(const float4*)(ga + k0 + 12);
        } else {
            pa00 = *(const u16x8*)(ga + k0);
            pa01 = *(const u16x8*)(ga + k0 + 8);
        }
        pb00 = *(const u16x8*)(gb + k0);
        pb01 = *(const u16x8*)(gb + k0 + 8);
        if constexpr (DUAL) {
            const bf16* ms = msrc(k0);
            pm00 = *(const u16x8*)ms;
            pm01 = *(const u16x8*)(ms + 8);
        }
    };
    auto load1 = [&](int k0) {
        if constexpr (__is_same(TA, float)) {
            f10 = *(const float4*)(ga + k0);
            f11 = *(const float4*)(ga + k0 + 4);
            f12 = *(const float4*)(ga + k0 + 8);
            f13 = *(const float4*)(ga + k0 + 12);
        } else {
            pa10 = *(const u16x8*)(ga + k0);
            pa11 = *(const u16x8*)(ga + k0 + 8);
        }
        pb10 = *(const u16x8*)(gb + k0);
        pb11 = *(const u16x8*)(gb + k0 + 8);
        if constexpr (DUAL) {
            const bf16* ms = msrc(k0);
            pm10 = *(const u16x8*)ms;
            pm11 = *(const u16x8*)(ms + 8);
        }
    };
    auto dep0 = [&](int buf) {
        if constexpr (__is_same(TA, float)) {
            u16x8 o0, o1;
            o0[0] = f2us(f00.x); o0[1] = f2us(f00.y); o0[2] = f2us(f00.z); o0[3] = f2us(f00.w);
            o0[4] = f2us(f01.x); o0[5] = f2us(f01.y); o0[6] = f2us(f01.z); o0[7] = f2us(f01.w);
            o1[0] = f2us(f02.x); o1[1] = f2us(f02.y); o1[2] = f2us(f02.z); o1[3] = f2us(f02.w);
            o1[4] = f2us(f03.x); o1[5] = f2us(f03.y); o1[6] = f2us(f03.z); o1[7] = f2us(f03.w);
            *(u16x8*)&As[buf][srow][sk]     = o0;
            *(u16x8*)&As[buf][srow][sk + 8] = o1;
        } else {
            *(u16x8*)&As[buf][srow][sk]     = pa00;
            *(u16x8*)&As[buf][srow][sk + 8] = pa01;
        }
        *(u16x8*)&Bs[buf][srow][sk]     = pb00;
        *(u16x8*)&Bs[buf][srow][sk + 8] = pb01;
        if constexpr (DUAL) {
            *(u16x8*)&Ms[buf][srow][sk]     = pm00;
            *(u16x8*)&Ms[buf][srow][sk + 8] = pm01;
        }
    };
    auto dep1 = [&](int buf) {
        if constexpr (__is_same(TA, float)) {
            u16x8 o0, o1;
            o0[0] = f2us(f10.x); o0[1] = f2us(f10.y); o0[2] = f2us(f10.z); o0[3] = f2us(f10.w);
            o0[4] = f2us(f11.x); o0[5] = f2us(f11.y); o0[6] = f2us(f11.z); o0[7] = f2us(f11.w);
            o1[0] = f2us(f12.x); o1[1] = f2us(f12.y); o1[2] = f2us(f12.z); o1[3] = f2us(f12.w);
            o1[4] = f2us(f13.x); o1[5] = f2us(f13.y); o1[6] = f2us(f13.z); o1[7] = f2us(f13.w);
            *(u16x8*)&As[buf][srow][sk]     = o0;
            *(u16x8*)&As[buf][srow][sk + 8] = o1;
        } else {
            *(u16x8*)&As[buf][srow][sk]     = pa10;
            *(u16x8*)&As[buf][srow][sk + 8] = pa11;
        }
        *(u16x8*)&Bs[buf][srow][sk]     = pb10;
        *(u16x8*)&Bs[buf][srow][sk + 8] = pb11;
        if constexpr (DUAL) {
            *(u16x8*)&Ms[buf][srow][sk]     = pm10;
            *(u16x8*)&Ms[buf][srow][sk + 8] = pm11;
        }
    };

    f32x16 acc;
    #pragma unroll
    for (int r = 0; r < 16; r++) acc[r] = 0.f;

    auto mfma_step = [&](int buf) {
        #pragma unroll
        for (int ks = 0; ks < 4; ks++) {
            s16x8 a = *(const s16x8*)&As[buf][wm + l31][ks * 16 + lhi * 8];
            s16x8 b = *(const s16x8*)&Bs[buf][wn + l31][ks * 16 + lhi * 8];
            acc = __builtin_amdgcn_mfma_f32_32x32x16_bf16(a, b, acc, 0, 0, 0);
            if constexpr (DUAL) {
                s16x8 m2 = *(const s16x8*)&Ms[buf][wm + l31][ks * 16 + lhi * 8];
                acc = __builtin_amdgcn_mfma_f32_32x32x16_bf16(m2, b, acc, 0, 0, 0);
            }
        }
    };

    const int NIT = (kEnd - kBeg) >> 6;
    load0(kBeg);
    load1(kBeg + 64);
    dep0(0);
    __syncthreads();

    for (int k = 0; k < NIT; k += 2) {
        if (k + 2 < NIT) load0(kBeg + (k + 2) * 64);
        mfma_step(0);
        if (k + 1 < NIT) dep1(1);
        __syncthreads();
        if (k + 1 < NIT) {
            if (k + 3 < NIT) load1(kBeg + (k + 3) * 64);
            mfma_step(1);
            if (k + 2 < NIT) dep0(0);
            __syncthreads();
        }
    }

    #pragma unroll
    for (int r = 0; r < 16; r++) {
        int row = m0 + wm + (r & 3) + 8 * (r >> 2) + 4 * lhi;
        int col = n0 + wn + l31;
        C[(size_t)row * ldc + col] = acc[r];
    }
}

extern "C" void kernel_launch(void* const* d_in, const int* in_sizes, int n_in,
                              void* d_out, int out_size, void* d_ws, size_t ws_size,
                              hipStream_t stream) {
    const int*   idx   = (const int*)  d_in[0];
    const float* dec_x = (const float*)d_in[1];   // (NH, D, N)
    const float* dec_y = (const float*)d_in[2];   // (NH, D, N)
    const float* enc   = (const float*)d_in[3];   // (NH*N, D)
    const float* emb   = (const float*)d_in[4];   // (VOCAB, D)
    const float* pose  = (const float*)d_in[5];   // (BLOCK, D)
    const float* lmh   = (const float*)d_in[6];   // (D, VOCAB)
    float* out = (float*)d_out;                   // (T, VOCAB) fp32

    // workspace layout — identical to passing r11 (ws >= 84,377,600 proven)
    char* wp = (char*)d_ws;
    float*   x    = (float*)wp;              wp += (size_t)T_SEQ * D_DIM * 4;
    bf16*    xs   = (bf16*)wp;               wp += (size_t)T_SEQ * HN * 2;
    ushort2* csT  = (ushort2*)wp;            wp += (size_t)T_SEQ * NP2 * 4;
    bf16*    sc   = (bf16*)wp;               wp += (size_t)NHEAD * T_SEQ * T_SEQ * 2;
    float*   ykv  = (float*)wp;              wp += (size_t)NHEAD * T_SEQ * D_DIM * 4;
    float*   ymlp = (float*)wp;              wp += (size_t)T_SEQ * D_DIM * 4;   // dbuf home
    bf16*    xT   = (bf16*)wp;               wp += (size_t)D_DIM * T_SEQ * 2;
    bf16*    wX   = (bf16*)wp;               wp += (size_t)NHEAD * N_DIM * D_DIM * 2;
    bf16*    wY   = (bf16*)wp;               wp += (size_t)NHEAD * N_DIM * D_DIM * 2;
    bf16*    wE   = (bf16*)wp;               wp += (size_t)D_DIM * HN * 2;
    bf16*    wL   = (bf16*)wp;               wp += (size_t)VOCABSZ * D_DIM * 2;
    const size_t BASE_NEED = (size_t)(wp - (char*)d_ws);
    bf16*    qr   = (bf16*)wp;
    const size_t FULL_NEED = BASE_NEED + (size_t)T_SEQ * HN * 2;
    bf16*  dbuf  = (bf16*)ymlp;    // 512 KB diag partials on idle ymlp keeper

    if (ws_size < BASE_NEED) {
        fill_out<<<(out_size + 255) / 256, 256, 0, stream>>>(out, (float)ws_size, out_size);
        return;
    }
    const bool USE_QR = (ws_size >= FULL_NEED);

    // bf16 A-operand homes:
    //   main: xb on dead sc head (rewritten each layer by k_resid AFTER
    //         scores64/ykv consumed sc); ymlpP16 + ykvb on dead qr region.
    //   fallback: xb on ymlp keeper (dbuf unused); ymlpP8 on sc; ykv fp32.
    bf16*  xb_main = (bf16*)sc;
    bf16*  xb_fb   = (bf16*)ymlp;
    float* ymlpP16 = (float*)qr;                               // 16 x 786KB
    bf16*  ykvb    = (bf16*)((char*)qr + (size_t)16 * T_SEQ * D_DIM * 4);
    float* ymlpP8  = (float*)sc;                               // fallback slabs

    bf16* xb = USE_QR ? xb_main : xb_fb;

    // weight mirrors (bf16, [n][k])
    t_cvt<<<dim3(48, 3, 4), 256, 0, stream>>>(dec_x, wX, D_DIM, N_DIM,
                                              (long)D_DIM * N_DIM, (long)N_DIM * D_DIM);
    t_cvt<<<dim3(48, 3, 4), 256, 0, stream>>>(dec_y, wY, D_DIM, N_DIM,
                                              (long)D_DIM * N_DIM, (long)N_DIM * D_DIM);
    t_cvt<<<dim3(3, 192, 1), 256, 0, stream>>>(enc, wE, HN, D_DIM, 0L, 0L);
    t_cvt<<<dim3(4, 3, 1), 256, 0, stream>>>(lmh, wL, D_DIM, VOCABSZ, 0L, 0L);

    k_tables<<<(T_SEQ * NP2) / 256, 256, 0, stream>>>(csT);
    k_embed<<<T_SEQ, 64, 0, stream>>>(idx, emb, pose, x, xb);

    for (int l = 0; l < NLAYER; ++l) {
        // xT = x^T (bf16) for ykv's B operand
        t_cvt<<<dim3(3, 16, 1), 256, 0, stream>>>(x, xT, T_SEQ, D_DIM, 0L, 0L);
        if (USE_QR) {
            // xs = relu(x @ dec_x), qr = rope(xs)
            dgemm128<1, true, bf16><<<dim3(96, 8), 256, 0, stream>>>(xb, wX, xs, qr, csT);
            scores64<<<dim3(136, 2, NHEAD), 256, 0, stream>>>(qr, sc, dbuf);
            // ykv = sc @ x  (causal, split-K=2, dual-A partial combine;
            // slab1 on qr head — dead until k_ln2b consumes it)
            long segZ = (long)((float*)qr - ykv);
            mfma_gemm<bf16, 1><<<dim3(3, 16, NHEAD * 2), 256, 0, stream>>>(
                sc, xT, ykv, dbuf, T_SEQ, 0, T_SEQ, T_SEQ, D_DIM,
                (long)T_SEQ * T_SEQ, segZ, (long)T_SEQ * D_DIM);
            // ykvb = bf16(LN(slab0 + slab1))
            k_ln2b<<<NHEAD * T_SEQ, 64, 0, stream>>>(ykv, (const float*)qr, ykvb);
            // xs *= relu(ykvb @ dec_y)
            dgemm128<2, false, bf16><<<dim3(96, 8), 256, 0, stream>>>(
                ykvb, wY, xs, nullptr, nullptr);
            // ymlp partials = xy @ enc (split-K=16 -> slabs on qr region)
            mfma_gemm<bf16, 2><<<dim3(3, 16, 16), 256, 0, stream>>>(
                xs, wE, ymlpP16, nullptr, HN, HN / 16, HN, HN, D_DIM,
                0L, 0L, (long)T_SEQ * D_DIM);
            // x = LN(x + LN(sum partials)); xb refreshed
            k_resid<16><<<T_SEQ, 64, 0, stream>>>(x, ymlpP16, xb);
        } else {
            dgemm128<1, false, bf16><<<dim3(96, 8), 256, 0, stream>>>(xb, wX, xs, qr, csT);
            scores_fused<<<dim3(16, 16, NHEAD), 256, 0, stream>>>(xs, csT, sc);
            mfma_gemm<bf16, 3><<<dim3(3, 16, NHEAD), 256, 0, stream>>>(
                sc, xT, ykv, nullptr, T_SEQ, 0, T_SEQ, T_SEQ, D_DIM,
                (long)T_SEQ * T_SEQ, 0L, (long)T_SEQ * D_DIM);
            k_ln<<<NHEAD * T_SEQ, 64, 0, stream>>>(ykv);
            dgemm128<2, false, float><<<dim3(96, 8), 256, 0, stream>>>(
                ykv, wY, xs, nullptr, nullptr);
            mfma_gemm<bf16, 2><<<dim3(3, 16, 8), 256, 0, stream>>>(
                xs, wE, ymlpP8, nullptr, HN, HN / 8, HN, HN, D_DIM,
                0L, 0L, (long)T_SEQ * D_DIM);
            k_resid<8><<<T_SEQ, 64, 0, stream>>>(x, ymlpP8, xb);
        }
    }

    // logits = x @ lm_head
    mfma_gemm<float, 0><<<dim3(4, 16, 1), 256, 0, stream>>>(
        x, wL, out, nullptr, D_DIM, 0, D_DIM, D_DIM, VOCABSZ, 0L, 0L, 0L);
}

// Round 9
// 501.215 us; speedup vs baseline: 1.0359x; 1.0359x over previous
//
#include <hip/hip_runtime.h>
#include <hip/hip_bf16.h>

using bf16 = __hip_bfloat16;

#define D_DIM   192
#define N_DIM   3072
#define NHEAD   4
#define T_SEQ   1024
#define HN      12288      // NHEAD * N_DIM
#define NP2     1536       // N_DIM/2
#define VOCABSZ 256
#define NLAYER  4
#define LN_EPS  1e-5f
#define TWO_PI  6.2831853071795864f

typedef __attribute__((ext_vector_type(8)))  short          s16x8;
typedef __attribute__((ext_vector_type(8)))  unsigned short u16x8;
typedef __attribute__((ext_vector_type(4)))  float          f32x4;
typedef __attribute__((ext_vector_type(16))) float          f32x16;

__device__ __forceinline__ float b2f(bf16 v) { return __bfloat162float(v); }
__device__ __forceinline__ float us2f(unsigned short u) {
    unsigned int x = ((unsigned int)u) << 16;
    return __builtin_bit_cast(float, x);
}
__device__ __forceinline__ unsigned short f2us(float f) {
    bf16 b = __float2bfloat16(f);
    return __builtin_bit_cast(unsigned short, b);
}

// sentinel: encode ws_size into output (fires only if ws too small)
__global__ void fill_out(float* __restrict__ out, float val, int nelem) {
    int i = blockIdx.x * 256 + threadIdx.x;
    if (i < nelem) out[i] = val;
}

// ---------------------------------------------------------------------------
// Tiled transpose + fp32->bf16: in fp32 [R][C] -> out bf16 [C][R].
// ---------------------------------------------------------------------------
__global__ void t_cvt(const float* __restrict__ in, bf16* __restrict__ out,
                      int R, int C, long inZ, long outZ) {
    __shared__ float tile[64][65];
    in  += inZ  * blockIdx.z;
    out += outZ * blockIdx.z;
    const int tx = threadIdx.x & 63, ty = threadIdx.x >> 6;
    const int r0 = blockIdx.y * 64, c0 = blockIdx.x * 64;
    #pragma unroll
    for (int rr = 0; rr < 16; rr++) {
        int row = ty * 16 + rr;
        tile[row][tx] = in[(size_t)(r0 + row) * C + c0 + tx];
    }
    __syncthreads();
    #pragma unroll
    for (int rr = 0; rr < 16; rr++) {
        int row = ty * 16 + rr;
        out[(size_t)(c0 + row) * R + r0 + tx] = __float2bfloat16(tile[tx][row]);
    }
}

// ---------------------------------------------------------------------------
// Wave-per-row LN family (64 threads/block, 3 elems/lane, butterfly reduce)
// ---------------------------------------------------------------------------
__device__ __forceinline__ void wave_sum2(float& s, float& ss) {
    #pragma unroll
    for (int off = 1; off < 64; off <<= 1) {
        s  += __shfl_xor(s,  off, 64);
        ss += __shfl_xor(ss, off, 64);
    }
}

// writes fp32 x AND bf16 xb (bf16 A-operand for dgemm128)
__global__ void k_embed(const int* __restrict__ idx, const float* __restrict__ emb,
                        const float* __restrict__ pos, float* __restrict__ x,
                        bf16* __restrict__ xb) {
    int t = blockIdx.x, l = threadIdx.x;
    int tok = idx[t];
    const float* e = emb + tok * D_DIM;
    const float* p = pos + t * D_DIM;
    float v0 = e[l] + p[l], v1 = e[l + 64] + p[l + 64], v2 = e[l + 128] + p[l + 128];
    float s = v0 + v1 + v2, ss = v0 * v0 + v1 * v1 + v2 * v2;
    wave_sum2(s, ss);
    float m = s / D_DIM, r = rsqrtf(ss / D_DIM - m * m + LN_EPS);
    float* xr = x + t * D_DIM;
    bf16*  xo = xb + (size_t)t * D_DIM;
    float o0 = (v0 - m) * r, o1 = (v1 - m) * r, o2 = (v2 - m) * r;
    xr[l] = o0; xr[l + 64] = o1; xr[l + 128] = o2;
    xo[l] = __float2bfloat16(o0);
    xo[l + 64] = __float2bfloat16(o1);
    xo[l + 128] = __float2bfloat16(o2);
}

__global__ void k_ln(float* __restrict__ buf) {
    int l = threadIdx.x;
    float* row = buf + (size_t)blockIdx.x * D_DIM;
    float v0 = row[l], v1 = row[l + 64], v2 = row[l + 128];
    float s = v0 + v1 + v2, ss = v0 * v0 + v1 * v1 + v2 * v2;
    wave_sum2(s, ss);
    float m = s / D_DIM, r = rsqrtf(ss / D_DIM - m * m + LN_EPS);
    row[l] = (v0 - m) * r; row[l + 64] = (v1 - m) * r; row[l + 128] = (v2 - m) * r;
}

// outb = bf16( LN(P0row + P1row) )  — ykv slab combine + LN + bf16 cast
__global__ void k_ln2b(const float* __restrict__ P0, const float* __restrict__ P1,
                       bf16* __restrict__ outb) {
    int l = threadIdx.x;
    size_t off = (size_t)blockIdx.x * D_DIM;
    const float* r0 = P0 + off;
    const float* r1 = P1 + off;
    float v0 = r0[l] + r1[l];
    float v1 = r0[l + 64] + r1[l + 64];
    float v2 = r0[l + 128] + r1[l + 128];
    float s = v0 + v1 + v2, ss = v0 * v0 + v1 * v1 + v2 * v2;
    wave_sum2(s, ss);
    float m = s / D_DIM, r = rsqrtf(ss / D_DIM - m * m + LN_EPS);
    bf16* o = outb + off;
    o[l]       = __float2bfloat16((v0 - m) * r);
    o[l + 64]  = __float2bfloat16((v1 - m) * r);
    o[l + 128] = __float2bfloat16((v2 - m) * r);
}

// x = LN(x + LN(sum of NSLAB split-K partial slabs)); also writes xb (bf16)
template <int NSLAB>
__global__ void k_resid(float* __restrict__ x, const float* __restrict__ P,
                        bf16* __restrict__ xb) {
    int l = threadIdx.x, t = blockIdx.x;
    float y0 = 0.f, y1 = 0.f, y2 = 0.f;
    #pragma unroll
    for (int p = 0; p < NSLAB; p++) {
        const float* r = P + (size_t)p * T_SEQ * D_DIM + (size_t)t * D_DIM;
        y0 += r[l]; y1 += r[l + 64]; y2 += r[l + 128];
    }
    float* xr = x + (size_t)t * D_DIM;
    float s = y0 + y1 + y2, ss = y0 * y0 + y1 * y1 + y2 * y2;
    wave_sum2(s, ss);
    float m1 = s / D_DIM, r1 = rsqrtf(ss / D_DIM - m1 * m1 + LN_EPS);
    float v0 = xr[l] + (y0 - m1) * r1;
    float v1 = xr[l + 64] + (y1 - m1) * r1;
    float v2 = xr[l + 128] + (y2 - m1) * r1;
    s = v0 + v1 + v2; ss = v0 * v0 + v1 * v1 + v2 * v2;
    wave_sum2(s, ss);
    float m2 = s / D_DIM, r2 = rsqrtf(ss / D_DIM - m2 * m2 + LN_EPS);
    float o0 = (v0 - m2) * r2, o1 = (v1 - m2) * r2, o2 = (v2 - m2) * r2;
    xr[l] = o0; xr[l + 64] = o1; xr[l + 128] = o2;
    bf16* xo = xb + (size_t)t * D_DIM;
    xo[l] = __float2bfloat16(o0);
    xo[l + 64] = __float2bfloat16(o1);
    xo[l + 128] = __float2bfloat16(o2);
}

// RoPE cos/sin tables, interleaved bf16 pairs csT[t][p] = (cos, sin)
__global__ void k_tables(ushort2* __restrict__ csT) {
    int gid = blockIdx.x * 256 + threadIdx.x;
    int t = gid / NP2, p = gid % NP2;
    float qf = (float)(2 * p);
    float f = exp2f(qf * (-16.0f / 3072.0f)) * (1.0f / (float)TWO_PI);
    float ph = fmodf((float)t * f, 1.0f) * (float)TWO_PI;
    ushort2 cs;
    cs.x = f2us(cosf(ph));
    cs.y = f2us(sinf(ph));
    csT[gid] = cs;
}

// ---------------------------------------------------------------------------
// scores64: partial scores, split-K=2 over grid.y (1088 blocks).
//   kh=0: lower-K half -> lower tile (i,j), masked if diag.
//   kh=1 off-diag: upper-K half, swapped operands -> dead upper slot (j,i)
//     in (t,s) orientation. kh=1 diag: masked partial -> dbuf slab.
// ykv dual-A MFMA combines partials in fp32 (no k_comb).
// 64x64 tile, 4 waves x one 32x32x16 MFMA acc, BK=64, dbuf LDS + 2-deep
// register prefetch, LDS-staged coalesced epilogue. XCD remap (136=8*17).
// ---------------------------------------------------------------------------
__launch_bounds__(256, 4)
__global__ void scores64(const bf16* __restrict__ qr, bf16* __restrict__ sc,
                         bf16* __restrict__ dbuf) {
    const int h  = blockIdx.z;
    const int kh = blockIdx.y;                     // K-half
    const int orig = blockIdx.x;
    const int L = (orig & 7) * 17 + (orig >> 3);   // bijective: 136 = 8*17
    int i = 0;
    while (((i + 1) * (i + 2)) >> 1 <= L) ++i;
    int j = L - ((i * (i + 1)) >> 1);
    const int t0 = i * 64, s0 = j * 64;
    const bool diag = (i == j);

    int arow = t0, brow = s0;
    if (kh == 1 && !diag) { arow = s0; brow = t0; }

    __shared__ short As[2][64][72];
    __shared__ short Bs[2][64][72];

    const int tid = threadIdx.x;
    const int lane = tid & 63, w = tid >> 6;
    const int wtm = (w >> 1) * 32, wtn = (w & 1) * 32;
    const int l31 = lane & 31, lhi = lane >> 5;
    const int r0 = tid >> 2;
    const int kq = (tid & 3) * 16;

    const int kBeg = kh * (N_DIM / 2);
    const bf16* gA = qr + (size_t)(arow + r0) * HN + h * N_DIM + kBeg + kq;
    const bf16* gB = qr + (size_t)(brow + r0) * HN + h * N_DIM + kBeg + kq;

    u16x8 pa0, pa1, pb0, pb1;
    u16x8 qa0, qa1, qb0, qb1;
    auto load0 = [&](int k0) {
        pa0 = *(const u16x8*)(gA + k0);
        pa1 = *(const u16x8*)(gA + k0 + 8);
        pb0 = *(const u16x8*)(gB + k0);
        pb1 = *(const u16x8*)(gB + k0 + 8);
    };
    auto load1 = [&](int k0) {
        qa0 = *(const u16x8*)(gA + k0);
        qa1 = *(const u16x8*)(gA + k0 + 8);
        qb0 = *(const u16x8*)(gB + k0);
        qb1 = *(const u16x8*)(gB + k0 + 8);
    };
    auto dep0 = [&](int buf) {
        *(u16x8*)&As[buf][r0][kq]     = pa0;
        *(u16x8*)&As[buf][r0][kq + 8] = pa1;
        *(u16x8*)&Bs[buf][r0][kq]     = pb0;
        *(u16x8*)&Bs[buf][r0][kq + 8] = pb1;
    };
    auto dep1 = [&](int buf) {
        *(u16x8*)&As[buf][r0][kq]     = qa0;
        *(u16x8*)&As[buf][r0][kq + 8] = qa1;
        *(u16x8*)&Bs[buf][r0][kq]     = qb0;
        *(u16x8*)&Bs[buf][r0][kq + 8] = qb1;
    };

    f32x16 acc;
    #pragma unroll
    for (int r = 0; r < 16; r++) acc[r] = 0.f;

    auto mfma_step = [&](int buf) {
        #pragma unroll
        for (int ks = 0; ks < 4; ks++) {
            s16x8 a = *(const s16x8*)&As[buf][wtm + l31][ks * 16 + lhi * 8];
            s16x8 b = *(const s16x8*)&Bs[buf][wtn + l31][ks * 16 + lhi * 8];
            acc = __builtin_amdgcn_mfma_f32_32x32x16_bf16(a, b, acc, 0, 0, 0);
        }
    };

    const int NIT = (N_DIM / 2) / 64;   // 24 (even)
    load0(0);
    load1(64);
    dep0(0);
    __syncthreads();

    for (int k = 0; k < NIT; k += 2) {
        if (k + 2 < NIT) load0((k + 2) * 64);
        mfma_step(0);
        if (k + 1 < NIT) dep1(1);
        __syncthreads();
        if (k + 1 < NIT) {
            if (k + 3 < NIT) load1((k + 3) * 64);
            mfma_step(1);
            if (k + 2 < NIT) dep0(0);
            __syncthreads();
        }
    }

    __syncthreads();
    short (*S)[72] = (short(*)[72])&As[0][0][0];
    const bool trS = (kh == 1) && !diag;
    #pragma unroll
    for (int r = 0; r < 16; r++) {
        int rr = wtm + (r & 3) + 8 * (r >> 2) + 4 * lhi;
        int cc = wtn + l31;
        float v = acc[r];
        if (diag && cc >= rr) v = 0.f;
        if (trS) S[cc][rr] = (short)f2us(v);
        else     S[rr][cc] = (short)f2us(v);
    }
    __syncthreads();
    if (kh == 1 && diag) {
        bf16* P = dbuf + (size_t)(h * 16 + i) * 4096;
        #pragma unroll
        for (int e = 0; e < 2; e++) {
            int idxe = tid + e * 256;
            int row = idxe >> 3, cg = (idxe & 7) * 8;
            u16x8 v = *(const u16x8*)&S[row][cg];
            *(u16x8*)(P + row * 64 + cg) = v;
        }
    } else {
        bf16* C = sc + (size_t)h * T_SEQ * T_SEQ;
        #pragma unroll
        for (int e = 0; e < 2; e++) {
            int idxe = tid + e * 256;
            int row = idxe >> 3, cg = (idxe & 7) * 8;
            u16x8 v = *(const u16x8*)&S[row][cg];
            *(u16x8*)(C + (size_t)(arow + row) * T_SEQ + brow + cg) = v;
        }
    }
}

// ---------------------------------------------------------------------------
// scores fallback (no qr buffer): 64x64, rope fused into staging.
// ---------------------------------------------------------------------------
__device__ __forceinline__ void stage_rope8(short* dst, const bf16* src,
                                            const ushort2* csP) {
    u16x8 v  = *(const u16x8*)src;
    u16x8 cs = *(const u16x8*)csP;
    u16x8 o;
    #pragma unroll
    for (int i = 0; i < 4; i++) {
        float e  = us2f(v[2 * i]), od = us2f(v[2 * i + 1]);
        float c  = us2f(cs[2 * i]), s = us2f(cs[2 * i + 1]);
        o[2 * i]     = f2us(e * c - od * s);
        o[2 * i + 1] = f2us(od * c + e * s);
    }
    *(u16x8*)dst = o;
}

__launch_bounds__(256)
__global__ void scores_fused(const bf16* __restrict__ xs,
                             const ushort2* __restrict__ csT,
                             bf16* __restrict__ sc) {
    const int h  = blockIdx.z;
    const int s0 = blockIdx.x * 64, t0 = blockIdx.y * 64;
    if (s0 > t0) return;
    __shared__ short As[64][40];
    __shared__ short Bs[64][40];
    const int tid  = threadIdx.x;
    const int srow = tid >> 2, kq = (tid & 3) * 8;
    const int lane = tid & 63, w = tid >> 6, qd = lane >> 4, lc = lane & 15;
    const int tA = t0 + srow, tB = s0 + srow;
    const bf16* gA = xs + (size_t)tA * HN + h * N_DIM + kq;
    const bf16* gB = xs + (size_t)tB * HN + h * N_DIM + kq;
    const ushort2* cA = csT + (size_t)tA * NP2 + (kq >> 1);
    const ushort2* cB = csT + (size_t)tB * NP2 + (kq >> 1);
    f32x4 acc[4] = {{0.f,0.f,0.f,0.f},{0.f,0.f,0.f,0.f},
                    {0.f,0.f,0.f,0.f},{0.f,0.f,0.f,0.f}};
    for (int k0 = 0; k0 < N_DIM; k0 += 32) {
        stage_rope8(&As[srow][kq], gA + k0, cA + (k0 >> 1));
        stage_rope8(&Bs[srow][kq], gB + k0, cB + (k0 >> 1));
        __syncthreads();
        s16x8 a = *(const s16x8*)&As[w * 16 + lc][qd * 8];
        #pragma unroll
        for (int j = 0; j < 4; j++) {
            s16x8 b = *(const s16x8*)&Bs[j * 16 + lc][qd * 8];
            acc[j] = __builtin_amdgcn_mfma_f32_16x16x32_bf16(a, b, acc[j], 0, 0, 0);
        }
        __syncthreads();
    }
    bf16* C = sc + (size_t)h * T_SEQ * T_SEQ;
    const bool diag = (s0 == t0);
    const int tbase = t0 + w * 16 + qd * 4;
    #pragma unroll
    for (int j = 0; j < 4; j++) {
        int s = s0 + j * 16 + lc;
        #pragma unroll
        for (int r = 0; r < 4; r++) {
            int t = tbase + r;
            C[(size_t)t * T_SEQ + s] =
                __float2bfloat16((!diag || s < t) ? acc[j][r] : 0.f);
        }
    }
}

// ---------------------------------------------------------------------------
// dgemm128: 128x128 tile, 4 waves x (64x64 = 2x2 of 32x32x16 MFMA accs),
// K=192 (BK=32), double-buffered LDS + 2-deep register prefetch, LDS-staged
// coalesced epilogue (relu / rope / gate). TA = bf16 or float.
// ---------------------------------------------------------------------------
template <int EPI, bool WQR, typename TA>
__launch_bounds__(256)
__global__ void dgemm128(const TA* __restrict__ A, const bf16* __restrict__ Bt,
                         bf16* __restrict__ xs, bf16* __restrict__ qr,
                         const ushort2* __restrict__ csT) {
    __shared__ __align__(16) short pool[2 * 2 * 128 * 40];   // 40 KB
    short (*As)[128][40] = (short(*)[128][40])pool;
    short (*Bs)[128][40] = (short(*)[128][40])(pool + 2 * 128 * 40);

    const int tid = threadIdx.x;
    const int lane = tid & 63, w = tid >> 6;
    const int l31 = lane & 31, lhi = lane >> 5;
    const int wtm = (w >> 1) * 64, wtn = (w & 1) * 64;
    const int n0 = blockIdx.x * 128, m0 = blockIdx.y * 128;
    if constexpr (EPI == 2) A += (size_t)(n0 / N_DIM) * T_SEQ * D_DIM;

    const int r0 = tid >> 2, r1 = r0 + 64;
    const int kq = (tid & 3) * 8;

    const TA*   gA = A  + kq;
    const bf16* gB = Bt + kq;

    float4 fa00, fa01, fa02, fa03, fa10, fa11, fa12, fa13;
    u16x8 ba00, ba01, ba10, ba11;
    u16x8 pb00, pb01, pb10, pb11;
    auto load0 = [&](int k0) {
        if constexpr (__is_same(TA, float)) {
            const TA* a0 = gA + (size_t)(m0 + r0) * D_DIM + k0;
            const TA* a1 = gA + (size_t)(m0 + r1) * D_DIM + k0;
            fa00 = *(const float4*)a0; fa01 = *(const float4*)(a0 + 4);
            fa02 = *(const float4*)a1; fa03 = *(const float4*)(a1 + 4);
        } else {
            ba00 = *(const u16x8*)(gA + (size_t)(m0 + r0) * D_DIM + k0);
            ba01 = *(const u16x8*)(gA + (size_t)(m0 + r1) * D_DIM + k0);
        }
        pb00 = *(const u16x8*)(gB + (size_t)(n0 + r0) * D_DIM + k0);
        pb01 = *(const u16x8*)(gB + (size_t)(n0 + r1) * D_DIM + k0);
    };
    auto load1 = [&](int k0) {
        if constexpr (__is_same(TA, float)) {
            const TA* a0 = gA + (size_t)(m0 + r0) * D_DIM + k0;
            const TA* a1 = gA + (size_t)(m0 + r1) * D_DIM + k0;
            fa10 = *(const float4*)a0; fa11 = *(const float4*)(a0 + 4);
            fa12 = *(const float4*)a1; fa13 = *(const float4*)(a1 + 4);
        } else {
            ba10 = *(const u16x8*)(gA + (size_t)(m0 + r0) * D_DIM + k0);
            ba11 = *(const u16x8*)(gA + (size_t)(m0 + r1) * D_DIM + k0);
        }
        pb10 = *(const u16x8*)(gB + (size_t)(n0 + r0) * D_DIM + k0);
        pb11 = *(const u16x8*)(gB + (size_t)(n0 + r1) * D_DIM + k0);
    };
    auto dep0 = [&](int buf) {
        if constexpr (__is_same(TA, float)) {
            u16x8 o0, o1;
            o0[0] = f2us(fa00.x); o0[1] = f2us(fa00.y); o0[2] = f2us(fa00.z); o0[3] = f2us(fa00.w);
            o0[4] = f2us(fa01.x); o0[5] = f2us(fa01.y); o0[6] = f2us(fa01.z); o0[7] = f2us(fa01.w);
            o1[0] = f2us(fa02.x); o1[1] = f2us(fa02.y); o1[2] = f2us(fa02.z); o1[3] = f2us(fa02.w);
            o1[4] = f2us(fa03.x); o1[5] = f2us(fa03.y); o1[6] = f2us(fa03.z); o1[7] = f2us(fa03.w);
            *(u16x8*)&As[buf][r0][kq] = o0;
            *(u16x8*)&As[buf][r1][kq] = o1;
        } else {
            *(u16x8*)&As[buf][r0][kq] = ba00;
            *(u16x8*)&As[buf][r1][kq] = ba01;
        }
        *(u16x8*)&Bs[buf][r0][kq] = pb00;
        *(u16x8*)&Bs[buf][r1][kq] = pb01;
    };
    auto dep1 = [&](int buf) {
        if constexpr (__is_same(TA, float)) {
            u16x8 o0, o1;
            o0[0] = f2us(fa10.x); o0[1] = f2us(fa10.y); o0[2] = f2us(fa10.z); o0[3] = f2us(fa10.w);
            o0[4] = f2us(fa11.x); o0[5] = f2us(fa11.y); o0[6] = f2us(fa11.z); o0[7] = f2us(fa11.w);
            o1[0] = f2us(fa12.x); o1[1] = f2us(fa12.y); o1[2] = f2us(fa12.z); o1[3] = f2us(fa12.w);
            o1[4] = f2us(fa13.x); o1[5] = f2us(fa13.y); o1[6] = f2us(fa13.z); o1[7] = f2us(fa13.w);
            *(u16x8*)&As[buf][r0][kq] = o0;
            *(u16x8*)&As[buf][r1][kq] = o1;
        } else {
            *(u16x8*)&As[buf][r0][kq] = ba10;
            *(u16x8*)&As[buf][r1][kq] = ba11;
        }
        *(u16x8*)&Bs[buf][r0][kq] = pb10;
        *(u16x8*)&Bs[buf][r1][kq] = pb11;
    };

    f32x16 acc00, acc01, acc10, acc11;
    #pragma unroll
    for (int r = 0; r < 16; r++) { acc00[r] = 0.f; acc01[r] = 0.f; acc10[r] = 0.f; acc11[r] = 0.f; }

    auto mfma_step = [&](int buf) {
        #pragma unroll
        for (int ks = 0; ks < 2; ks++) {
            s16x8 a0 = *(const s16x8*)&As[buf][wtm + l31][ks * 16 + lhi * 8];
            s16x8 a1 = *(const s16x8*)&As[buf][wtm + 32 + l31][ks * 16 + lhi * 8];
            s16x8 b0 = *(const s16x8*)&Bs[buf][wtn + l31][ks * 16 + lhi * 8];
            s16x8 b1 = *(const s16x8*)&Bs[buf][wtn + 32 + l31][ks * 16 + lhi * 8];
            acc00 = __builtin_amdgcn_mfma_f32_32x32x16_bf16(a0, b0, acc00, 0, 0, 0);
            acc01 = __builtin_amdgcn_mfma_f32_32x32x16_bf16(a0, b1, acc01, 0, 0, 0);
            acc10 = __builtin_amdgcn_mfma_f32_32x32x16_bf16(a1, b0, acc10, 0, 0, 0);
            acc11 = __builtin_amdgcn_mfma_f32_32x32x16_bf16(a1, b1, acc11, 0, 0, 0);
        }
    };

    const int NIT = D_DIM / 32;   // 6 (even)
    load0(0);
    load1(32);
    dep0(0);
    __syncthreads();
    for (int k = 0; k < NIT; k += 2) {
        if (k + 2 < NIT) load0((k + 2) * 32);
        mfma_step(0);
        if (k + 1 < NIT) dep1(1);
        __syncthreads();
        if (k + 1 < NIT) {
            if (k + 3 < NIT) load1((k + 3) * 32);
            mfma_step(1);
            if (k + 2 < NIT) dep0(0);
            __syncthreads();
        }
    }

    // -------- LDS-staged epilogue --------
    short (*S)[136] = (short(*)[136])pool; // 128 x 136 shorts = 34.8 KB <= 40 KB
    #pragma unroll
    for (int r = 0; r < 16; r++) {
        int rb = (r & 3) + 8 * (r >> 2) + 4 * lhi;
        S[wtm + rb     ][wtn + l31     ] = (short)f2us(fmaxf(acc00[r], 0.f));
        S[wtm + rb     ][wtn + 32 + l31] = (short)f2us(fmaxf(acc01[r], 0.f));
        S[wtm + 32 + rb][wtn + l31     ] = (short)f2us(fmaxf(acc10[r], 0.f));
        S[wtm + 32 + rb][wtn + 32 + l31] = (short)f2us(fmaxf(acc11[r], 0.f));
    }
    __syncthreads();
    #pragma unroll
    for (int e = 0; e < 8; e++) {
        int idxe = tid + e * 256;
        int row = idxe >> 4, cg = idxe & 15;
        u16x8 v = *(const u16x8*)&S[row][cg * 8];
        int t = m0 + row, ngg = n0 + cg * 8;
        size_t ci = (size_t)t * HN + ngg;
        if constexpr (EPI == 1) {
            *(u16x8*)(xs + ci) = v;
            if constexpr (WQR) {
                int p0 = (ngg % N_DIM) >> 1;
                u16x8 cs8 = *(const u16x8*)&csT[(size_t)t * NP2 + p0];
                u16x8 o;
                #pragma unroll
                for (int q = 0; q < 4; q++) {
                    float ev = us2f(v[2 * q]), ov = us2f(v[2 * q + 1]);
                    float c = us2f(cs8[2 * q]), s = us2f(cs8[2 * q + 1]);
                    o[2 * q]     = f2us(ev * c - ov * s);
                    o[2 * q + 1] = f2us(ov * c + ev * s);
                }
                *(u16x8*)(qr + ci) = o;
            }
        } else {
            u16x8 g = *(const u16x8*)(xs + ci);
            u16x8 o;
            #pragma unroll
            for (int q = 0; q < 8; q++) o[q] = f2us(us2f(g[q]) * us2f(v[q]));
            *(u16x8*)(xs + ci) = o;
        }
    }
}

// ---------------------------------------------------------------------------
// gate_ymlp: fused  ymlp_slab = (xs ⊙ relu(ykvb @ decY)) @ enc.
// Eliminates the gated-xs HBM round-trip (50 MB/layer) and one launch.
// Grid (16 t-blocks, 16 n-segments of 768). Per 64-wide n-chunk:
//   stage1: ys = relu(A1(ykvb 64x192, LDS-resident) @ wY-chunk) -> xyA LDS
//   RMW:    xyA *= xs-chunk (coalesced global read)
//   stage2: out(64x192) += xyA @ wE-chunk   (3 f32x16 accs/wave)
// Single-buffered, 5 barriers/chunk (correctness-first).
// ---------------------------------------------------------------------------
__launch_bounds__(256, 2)
__global__ void gate_ymlp(const bf16* __restrict__ ykvb, const bf16* __restrict__ wY,
                          const bf16* __restrict__ xs, const bf16* __restrict__ wE,
                          float* __restrict__ P) {
    const int tb = blockIdx.x, s = blockIdx.y;
    const int t0  = tb * 64;
    const int h   = s >> 2;               // 4 segments of 768 per head
    const int ng0 = s * 768;              // global n base of this slab
    const int nh0 = (s & 3) * 768;        // within-head n base

    __shared__ __align__(16) short A1s[64][200];   // ykvb tile   (25.6 KB)
    __shared__ __align__(16) short Bsh[192][72];   // B2 view     (27.6 KB)
    __shared__ __align__(16) short xyA[64][72];    // xy chunk    ( 9.2 KB)
    short (*B1)[200] = (short(*)[200])&Bsh[0][0];  // B1 overlays B2 (12800<=13824)

    const int tid = threadIdx.x;
    const int lane = tid & 63, w = tid >> 6;
    const int l31 = lane & 31, lhi = lane >> 5;
    const int wm  = (w >> 1) * 32;        // t-offset of wave
    const int wn1 = (w & 1) * 32;         // n-offset (stage1)
    const int wn2 = (w & 1) * 96;         // d-offset (stage2)

    // load A1 = ykvb[h][t0..t0+64][0..192] once
    {
        const bf16* src = ykvb + ((size_t)h * T_SEQ + t0 + (tid >> 2)) * D_DIM
                        + (tid & 3) * 48;
        #pragma unroll
        for (int j = 0; j < 6; j++) {
            u16x8 v = *(const u16x8*)(src + j * 8);
            *(u16x8*)&A1s[tid >> 2][(tid & 3) * 48 + j * 8] = v;
        }
    }

    f32x16 oc0, oc1, oc2;
    #pragma unroll
    for (int r = 0; r < 16; r++) { oc0[r] = 0.f; oc1[r] = 0.f; oc2[r] = 0.f; }

    __syncthreads();

    for (int c = 0; c < 12; c++) {
        const int nc = c * 64;
        // stage B1 = wY[h][nh0+nc+r][0..192]
        {
            const bf16* src = wY + ((size_t)h * N_DIM + nh0 + nc + (tid >> 2)) * D_DIM
                            + (tid & 3) * 48;
            #pragma unroll
            for (int j = 0; j < 6; j++) {
                u16x8 v = *(const u16x8*)(src + j * 8);
                *(u16x8*)&B1[tid >> 2][(tid & 3) * 48 + j * 8] = v;
            }
        }
        __syncthreads();
        // stage1: ys(64x64) over K=192
        f32x16 ys;
        #pragma unroll
        for (int r = 0; r < 16; r++) ys[r] = 0.f;
        #pragma unroll
        for (int ks = 0; ks < 12; ks++) {
            s16x8 a = *(const s16x8*)&A1s[wm + l31][ks * 16 + lhi * 8];
            s16x8 b = *(const s16x8*)&B1[wn1 + l31][ks * 16 + lhi * 8];
            ys = __builtin_amdgcn_mfma_f32_32x32x16_bf16(a, b, ys, 0, 0, 0);
        }
        __syncthreads();                      // all waves done with B1 / prev xyA
        // scatter relu(ys) -> xyA (bf16)
        #pragma unroll
        for (int r = 0; r < 16; r++) {
            int rr = wm + (r & 3) + 8 * (r >> 2) + 4 * lhi;
            xyA[rr][wn1 + l31] = (short)f2us(fmaxf(ys[r], 0.f));
        }
        __syncthreads();
        // RMW with xs chunk (coalesced u16x8)
        {
            int row = tid >> 2, c0l = (tid & 3) * 16;
            const bf16* sx = xs + (size_t)(t0 + row) * HN + ng0 + nc + c0l;
            #pragma unroll
            for (int e = 0; e < 2; e++) {
                u16x8 g = *(const u16x8*)(sx + e * 8);
                u16x8 y = *(const u16x8*)&xyA[row][c0l + e * 8];
                u16x8 o;
                #pragma unroll
                for (int q = 0; q < 8; q++) o[q] = f2us(us2f(g[q]) * us2f(y[q]));
                *(u16x8*)&xyA[row][c0l + e * 8] = o;
            }
        }
        // stage B2 = wE[d][ng0+nc .. +64]   (overwrites B1 — stage1 done)
        {
            #pragma unroll
            for (int j = 0; j < 3; j++) {
                int d  = (tid >> 2) * 3 + j;          // 0..191
                int cc = (tid & 3) * 16;
                const bf16* src = wE + (size_t)d * HN + ng0 + nc + cc;
                u16x8 v0 = *(const u16x8*)src;
                u16x8 v1 = *(const u16x8*)(src + 8);
                *(u16x8*)&Bsh[d][cc]     = v0;
                *(u16x8*)&Bsh[d][cc + 8] = v1;
            }
        }
        __syncthreads();
        // stage2: out += xyA(64x64) @ wE-chunk^T(192x64), K=64
        #pragma unroll
        for (int ks = 0; ks < 4; ks++) {
            s16x8 a  = *(const s16x8*)&xyA[wm + l31][ks * 16 + lhi * 8];
            s16x8 b0 = *(const s16x8*)&Bsh[wn2 + l31     ][ks * 16 + lhi * 8];
            s16x8 b1 = *(const s16x8*)&Bsh[wn2 + 32 + l31][ks * 16 + lhi * 8];
            s16x8 b2 = *(const s16x8*)&Bsh[wn2 + 64 + l31][ks * 16 + lhi * 8];
            oc0 = __builtin_amdgcn_mfma_f32_32x32x16_bf16(a, b0, oc0, 0, 0, 0);
            oc1 = __builtin_amdgcn_mfma_f32_32x32x16_bf16(a, b1, oc1, 0, 0, 0);
            oc2 = __builtin_amdgcn_mfma_f32_32x32x16_bf16(a, b2, oc2, 0, 0, 0);
        }
        __syncthreads();                      // before next chunk's B1/xyA writes
    }

    // write slab P[s][t][d]
    float* O = P + (size_t)s * T_SEQ * D_DIM;
    #pragma unroll
    for (int r = 0; r < 16; r++) {
        int rt = t0 + wm + (r & 3) + 8 * (r >> 2) + 4 * lhi;
        O[(size_t)rt * D_DIM + wn2 +      l31] = oc0[r];
        O[(size_t)rt * D_DIM + wn2 + 32 + l31] = oc1[r];
        O[(size_t)rt * D_DIM + wn2 + 64 + l31] = oc2[r];
    }
}

// ---------------------------------------------------------------------------
// mfma_gemm (64x64): MODE 0 = plain, 1 = causal split-K=2 WITH dual-A partial
// combine, 2 = split-K slabs over z (fallback ymlp), 3 = causal full
// (fallback). 32x32x16 MFMA, BK=64, double-buffered LDS + 2-deep prefetch.
// ---------------------------------------------------------------------------
template <typename TA, int MODE>
__launch_bounds__(256)
__global__ void mfma_gemm(const TA* __restrict__ A, const bf16* __restrict__ Bt,
                          float* __restrict__ C, const bf16* __restrict__ aux,
                          int K, int kSeg, int lda, int ldb, int ldc,
                          long aZ, long bZ, long cZ) {
    constexpr bool DUAL = (MODE == 1);
    constexpr int TILES = DUAL ? 6 : 4;
    __shared__ __align__(16) short pool[TILES * 64 * 72];
    short (*As)[64][72] = (short(*)[64][72])pool;
    short (*Bs)[64][72] = (short(*)[64][72])(pool + 2 * 64 * 72);
    short (*Ms)[64][72] = (short(*)[64][72])(pool + 4 * 64 * 72);

    const int z = blockIdx.z;
    const int tid = threadIdx.x;
    const int n0 = blockIdx.x * 64, m0 = blockIdx.y * 64;
    const int srow = tid >> 2, sk = (tid & 3) * 16;
    const int lane = tid & 63, w = tid >> 6;
    const int l31 = lane & 31, lhi = lane >> 5;
    const int wm = (w >> 1) * 32, wn = (w & 1) * 32;

    int kBeg, kEnd, zh = 0;
    if constexpr (MODE == 1) {
        zh = z >> 1;
        const int seg = z & 1;
        A += aZ * zh;
        C += cZ * zh + bZ * seg;
        const int kc = (m0 + 64 < K) ? m0 + 64 : K;
        const int half0 = ((kc + 127) >> 7) << 6;   // ceil(kc/128)*64
        kBeg = seg ? half0 : 0;
        kEnd = seg ? kc : half0;
    } else if constexpr (MODE == 2) {
        A += aZ * z; Bt += bZ * z; C += cZ * z;
        kBeg = z * kSeg; kEnd = kBeg + kSeg;
    } else if constexpr (MODE == 3) {
        A += aZ * z; Bt += bZ * z; C += cZ * z;
        kBeg = 0; kEnd = (m0 + 64 < K) ? m0 + 64 : K;
    } else {
        A += aZ * z; Bt += bZ * z; C += cZ * z;
        kBeg = 0; kEnd = K;
    }

    const TA*   ga = A  + (size_t)(m0 + srow) * lda + sk;
    const bf16* gb = Bt + (size_t)(n0 + srow) * ldb + sk;

    auto msrc = [&](int k0) -> const bf16* {
        if (k0 == m0)
            return aux + (size_t)(zh * 16 + (m0 >> 6)) * 4096
                       + (size_t)srow * 64 + sk;
        return (const bf16*)A + (size_t)(k0 + srow) * lda + m0 + sk;
    };

    float4 f00, f01, f02, f03, f10, f11, f12, f13;
    u16x8 pa00, pa01, pa10, pa11, pb00, pb01, pb10, pb11;
    u16x8 pm00, pm01, pm10, pm11;
    auto load0 = [&](int k0) {
        if constexpr (__is_same(TA, float)) {
            f00 = *(const float4*)(ga + k0);
            f01 = *(const float4*)(ga + k0 + 4);
            f02 = *(const float4*)(ga + k0 + 8);
            f03 = *(const float4*)(ga + k0 + 12);
        } else {
            pa00 = *(const u16x8*)(ga + k0);
            pa01 = *(const u16x8*)(ga + k0 + 8);
        }
        pb00 = *(const u16x8*)(gb + k0);
        pb01 = *(const u16x8*)(gb + k0 + 8);
        if constexpr (DUAL) {
            const bf16* ms = msrc(k0);
            pm00 = *(const u16x8*)ms;
            pm01 = *(const u16x8*)(ms + 8);
        }
    };
    auto load1 = [&](int k0) {
        if constexpr (__is_same(TA, float)) {
            f10 = *(const float4*)(ga + k0);
            f11 = *(const float4*)(ga + k0 + 4);
            f12 = *(const float4*)(ga + k0 + 8);
            f13 = *(const float4*)(ga + k0 + 12);
        } else {
            pa10 = *(const u16x8*)(ga + k0);
            pa11 = *(const u16x8*)(ga + k0 + 8);
        }
        pb10 = *(const u16x8*)(gb + k0);
        pb11 = *(const u16x8*)(gb + k0 + 8);
        if constexpr (DUAL) {
            const bf16* ms = msrc(k0);
            pm10 = *(const u16x8*)ms;
            pm11 = *(const u16x8*)(ms + 8);
        }
    };
    auto dep0 = [&](int buf) {
        if constexpr (__is_same(TA, float)) {
            u16x8 o0, o1;
            o0[0] = f2us(f00.x); o0[1] = f2us(f00.y); o0[2] = f2us(f00.z); o0[3] = f2us(f00.w);
            o0[4] = f2us(f01.x); o0[5] = f2us(f01.y); o0[6] = f2us(f01.z); o0[7] = f2us(f01.w);
            o1[0] = f2us(f02.x); o1[1] = f2us(f02.y); o1[2] = f2us(f02.z); o1[3] = f2us(f02.w);
            o1[4] = f2us(f03.x); o1[5] = f2us(f03.y); o1[6] = f2us(f03.z); o1[7] = f2us(f03.w);
            *(u16x8*)&As[buf][srow][sk]     = o0;
            *(u16x8*)&As[buf][srow][sk + 8] = o1;
        } else {
            *(u16x8*)&As[buf][srow][sk]     = pa00;
            *(u16x8*)&As[buf][srow][sk + 8] = pa01;
        }
        *(u16x8*)&Bs[buf][srow][sk]     = pb00;
        *(u16x8*)&Bs[buf][srow][sk + 8] = pb01;
        if constexpr (DUAL) {
            *(u16x8*)&Ms[buf][srow][sk]     = pm00;
            *(u16x8*)&Ms[buf][srow][sk + 8] = pm01;
        }
    };
    auto dep1 = [&](int buf) {
        if constexpr (__is_same(TA, float)) {
            u16x8 o0, o1;
            o0[0] = f2us(f10.x); o0[1] = f2us(f10.y); o0[2] = f2us(f10.z); o0[3] = f2us(f10.w);
            o0[4] = f2us(f11.x); o0[5] = f2us(f11.y); o0[6] = f2us(f11.z); o0[7] = f2us(f11.w);
            o1[0] = f2us(f12.x); o1[1] = f2us(f12.y); o1[2] = f2us(f12.z); o1[3] = f2us(f12.w);
            o1[4] = f2us(f13.x); o1[5] = f2us(f13.y); o1[6] = f2us(f13.z); o1[7] = f2us(f13.w);
            *(u16x8*)&As[buf][srow][sk]     = o0;
            *(u16x8*)&As[buf][srow][sk + 8] = o1;
        } else {
            *(u16x8*)&As[buf][srow][sk]     = pa10;
            *(u16x8*)&As[buf][srow][sk + 8] = pa11;
        }
        *(u16x8*)&Bs[buf][srow][sk]     = pb10;
        *(u16x8*)&Bs[buf][srow][sk + 8] = pb11;
        if constexpr (DUAL) {
            *(u16x8*)&Ms[buf][srow][sk]     = pm10;
            *(u16x8*)&Ms[buf][srow][sk + 8] = pm11;
        }
    };

    f32x16 acc;
    #pragma unroll
    for (int r = 0; r < 16; r++) acc[r] = 0.f;

    auto mfma_step = [&](int buf) {
        #pragma unroll
        for (int ks = 0; ks < 4; ks++) {
            s16x8 a = *(const s16x8*)&As[buf][wm + l31][ks * 16 + lhi * 8];
            s16x8 b = *(const s16x8*)&Bs[buf][wn + l31][ks * 16 + lhi * 8];
            acc = __builtin_amdgcn_mfma_f32_32x32x16_bf16(a, b, acc, 0, 0, 0);
            if constexpr (DUAL) {
                s16x8 m2 = *(const s16x8*)&Ms[buf][wm + l31][ks * 16 + lhi * 8];
                acc = __builtin_amdgcn_mfma_f32_32x32x16_bf16(m2, b, acc, 0, 0, 0);
            }
        }
    };

    const int NIT = (kEnd - kBeg) >> 6;
    load0(kBeg);
    load1(kBeg + 64);
    dep0(0);
    __syncthreads();

    for (int k = 0; k < NIT; k += 2) {
        if (k + 2 < NIT) load0(kBeg + (k + 2) * 64);
        mfma_step(0);
        if (k + 1 < NIT) dep1(1);
        __syncthreads();
        if (k + 1 < NIT) {
            if (k + 3 < NIT) load1(kBeg + (k + 3) * 64);
            mfma_step(1);
            if (k + 2 < NIT) dep0(0);
            __syncthreads();
        }
    }

    #pragma unroll
    for (int r = 0; r < 16; r++) {
        int row = m0 + wm + (r & 3) + 8 * (r >> 2) + 4 * lhi;
        int col = n0 + wn + l31;
        C[(size_t)row * ldc + col] = acc[r];
    }
}

extern "C" void kernel_launch(void* const* d_in, const int* in_sizes, int n_in,
                              void* d_out, int out_size, void* d_ws, size_t ws_size,
                              hipStream_t stream) {
    const int*   idx   = (const int*)  d_in[0];
    const float* dec_x = (const float*)d_in[1];   // (NH, D, N)
    const float* dec_y = (const float*)d_in[2];   // (NH, D, N)
    const float* enc   = (const float*)d_in[3];   // (NH*N, D)
    const float* emb   = (const float*)d_in[4];   // (VOCAB, D)
    const float* pose  = (const float*)d_in[5];   // (BLOCK, D)
    const float* lmh   = (const float*)d_in[6];   // (D, VOCAB)
    float* out = (float*)d_out;                   // (T, VOCAB) fp32

    // workspace layout — identical to passing r11 (ws >= 84,377,600 proven)
    char* wp = (char*)d_ws;
    float*   x    = (float*)wp;              wp += (size_t)T_SEQ * D_DIM * 4;
    bf16*    xs   = (bf16*)wp;               wp += (size_t)T_SEQ * HN * 2;
    ushort2* csT  = (ushort2*)wp;            wp += (size_t)T_SEQ * NP2 * 4;
    bf16*    sc   = (bf16*)wp;               wp += (size_t)NHEAD * T_SEQ * T_SEQ * 2;
    float*   ykv  = (float*)wp;              wp += (size_t)NHEAD * T_SEQ * D_DIM * 4;
    float*   ymlp = (float*)wp;              wp += (size_t)T_SEQ * D_DIM * 4;   // dbuf home
    bf16*    xT   = (bf16*)wp;               wp += (size_t)D_DIM * T_SEQ * 2;
    bf16*    wX   = (bf16*)wp;               wp += (size_t)NHEAD * N_DIM * D_DIM * 2;
    bf16*    wY   = (bf16*)wp;               wp += (size_t)NHEAD * N_DIM * D_DIM * 2;
    bf16*    wE   = (bf16*)wp;               wp += (size_t)D_DIM * HN * 2;
    bf16*    wL   = (bf16*)wp;               wp += (size_t)VOCABSZ * D_DIM * 2;
    const size_t BASE_NEED = (size_t)(wp - (char*)d_ws);
    bf16*    qr   = (bf16*)wp;
    const size_t FULL_NEED = BASE_NEED + (size_t)T_SEQ * HN * 2;
    bf16*  dbuf  = (bf16*)ymlp;    // 512 KB diag partials on idle ymlp keeper

    if (ws_size < BASE_NEED) {
        fill_out<<<(out_size + 255) / 256, 256, 0, stream>>>(out, (float)ws_size, out_size);
        return;
    }
    const bool USE_QR = (ws_size >= FULL_NEED);

    // bf16 A-operand homes (main path): xb on dead sc head; ymlpP16 + ykvb
    // on dead qr region. Fallback: xb on ymlp keeper; ymlpP8 on sc.
    bf16*  xb_main = (bf16*)sc;
    bf16*  xb_fb   = (bf16*)ymlp;
    float* ymlpP16 = (float*)qr;                               // 16 slabs
    bf16*  ykvb    = (bf16*)((char*)qr + (size_t)16 * T_SEQ * D_DIM * 4);
    float* ymlpP8  = (float*)sc;                               // fallback slabs

    bf16* xb = USE_QR ? xb_main : xb_fb;

    // weight mirrors (bf16, [n][k])
    t_cvt<<<dim3(48, 3, 4), 256, 0, stream>>>(dec_x, wX, D_DIM, N_DIM,
                                              (long)D_DIM * N_DIM, (long)N_DIM * D_DIM);
    t_cvt<<<dim3(48, 3, 4), 256, 0, stream>>>(dec_y, wY, D_DIM, N_DIM,
                                              (long)D_DIM * N_DIM, (long)N_DIM * D_DIM);
    t_cvt<<<dim3(3, 192, 1), 256, 0, stream>>>(enc, wE, HN, D_DIM, 0L, 0L);
    t_cvt<<<dim3(4, 3, 1), 256, 0, stream>>>(lmh, wL, D_DIM, VOCABSZ, 0L, 0L);

    k_tables<<<(T_SEQ * NP2) / 256, 256, 0, stream>>>(csT);
    k_embed<<<T_SEQ, 64, 0, stream>>>(idx, emb, pose, x, xb);

    for (int l = 0; l < NLAYER; ++l) {
        // xT = x^T (bf16) for ykv's B operand
        t_cvt<<<dim3(3, 16, 1), 256, 0, stream>>>(x, xT, T_SEQ, D_DIM, 0L, 0L);
        if (USE_QR) {
            // xs = relu(x @ dec_x), qr = rope(xs)
            dgemm128<1, true, bf16><<<dim3(96, 8), 256, 0, stream>>>(xb, wX, xs, qr, csT);
            scores64<<<dim3(136, 2, NHEAD), 256, 0, stream>>>(qr, sc, dbuf);
            // ykv = sc @ x  (causal, split-K=2, dual-A partial combine;
            // slab1 on qr head — dead until k_ln2b consumes it)
            long segZ = (long)((float*)qr - ykv);
            mfma_gemm<bf16, 1><<<dim3(3, 16, NHEAD * 2), 256, 0, stream>>>(
                sc, xT, ykv, dbuf, T_SEQ, 0, T_SEQ, T_SEQ, D_DIM,
                (long)T_SEQ * T_SEQ, segZ, (long)T_SEQ * D_DIM);
            // ykvb = bf16(LN(slab0 + slab1))
            k_ln2b<<<NHEAD * T_SEQ, 64, 0, stream>>>(ykv, (const float*)qr, ykvb);
            // fused: ymlp slabs = (xs ⊙ relu(ykvb @ decY)) @ enc
            gate_ymlp<<<dim3(16, 16), 256, 0, stream>>>(ykvb, wY, xs, wE, ymlpP16);
            // x = LN(x + LN(sum partials)); xb refreshed
            k_resid<16><<<T_SEQ, 64, 0, stream>>>(x, ymlpP16, xb);
        } else {
            dgemm128<1, false, bf16><<<dim3(96, 8), 256, 0, stream>>>(xb, wX, xs, qr, csT);
            scores_fused<<<dim3(16, 16, NHEAD), 256, 0, stream>>>(xs, csT, sc);
            mfma_gemm<bf16, 3><<<dim3(3, 16, NHEAD), 256, 0, stream>>>(
                sc, xT, ykv, nullptr, T_SEQ, 0, T_SEQ, T_SEQ, D_DIM,
                (long)T_SEQ * T_SEQ, 0L, (long)T_SEQ * D_DIM);
            k_ln<<<NHEAD * T_SEQ, 64, 0, stream>>>(ykv);
            dgemm128<2, false, float><<<dim3(96, 8), 256, 0, stream>>>(
                ykv, wY, xs, nullptr, nullptr);
            mfma_gemm<bf16, 2><<<dim3(3, 16, 8), 256, 0, stream>>>(
                xs, wE, ymlpP8, nullptr, HN, HN / 8, HN, HN, D_DIM,
                0L, 0L, (long)T_SEQ * D_DIM);
            k_resid<8><<<T_SEQ, 64, 0, stream>>>(x, ymlpP8, xb);
        }
    }

    // logits = x @ lm_head
    mfma_gemm<float, 0><<<dim3(4, 16, 1), 256, 0, stream>>>(
        x, wL, out, nullptr, D_DIM, 0, D_DIM, D_DIM, VOCABSZ, 0L, 0L, 0L);
}

// Round 11
// 467.930 us; speedup vs baseline: 1.1096x; 1.0711x over previous
//
#include <hip/hip_runtime.h>
#include <hip/hip_bf16.h>

using bf16 = __hip_bfloat16;

#define D_DIM   192
#define N_DIM   3072
#define NHEAD   4
#define T_SEQ   1024
#define HN      12288      // NHEAD * N_DIM
#define NP2     1536       // N_DIM/2
#define VOCABSZ 256
#define NLAYER  4
#define LN_EPS  1e-5f
#define TWO_PI  6.2831853071795864f

typedef __attribute__((ext_vector_type(8)))  short          s16x8;
typedef __attribute__((ext_vector_type(8)))  unsigned short u16x8;
typedef __attribute__((ext_vector_type(4)))  float          f32x4;
typedef __attribute__((ext_vector_type(16))) float          f32x16;

__device__ __forceinline__ float b2f(bf16 v) { return __bfloat162float(v); }
__device__ __forceinline__ float us2f(unsigned short u) {
    unsigned int x = ((unsigned int)u) << 16;
    return __builtin_bit_cast(float, x);
}
__device__ __forceinline__ unsigned short f2us(float f) {
    bf16 b = __float2bfloat16(f);
    return __builtin_bit_cast(unsigned short, b);
}

// sentinel: encode ws_size into output (fires only if ws too small)
__global__ void fill_out(float* __restrict__ out, float val, int nelem) {
    int i = blockIdx.x * 256 + threadIdx.x;
    if (i < nelem) out[i] = val;
}

// ---------------------------------------------------------------------------
// Tiled transpose + fp32->bf16: in fp32 [R][C] -> out bf16 [C][R].
// ---------------------------------------------------------------------------
__global__ void t_cvt(const float* __restrict__ in, bf16* __restrict__ out,
                      int R, int C, long inZ, long outZ) {
    __shared__ float tile[64][65];
    in  += inZ  * blockIdx.z;
    out += outZ * blockIdx.z;
    const int tx = threadIdx.x & 63, ty = threadIdx.x >> 6;
    const int r0 = blockIdx.y * 64, c0 = blockIdx.x * 64;
    #pragma unroll
    for (int rr = 0; rr < 16; rr++) {
        int row = ty * 16 + rr;
        tile[row][tx] = in[(size_t)(r0 + row) * C + c0 + tx];
    }
    __syncthreads();
    #pragma unroll
    for (int rr = 0; rr < 16; rr++) {
        int row = ty * 16 + rr;
        out[(size_t)(c0 + row) * R + r0 + tx] = __float2bfloat16(tile[tx][row]);
    }
}

// ---------------------------------------------------------------------------
// Wave-per-row LN family (64 threads/block, 3 elems/lane, butterfly reduce)
// ---------------------------------------------------------------------------
__device__ __forceinline__ void wave_sum2(float& s, float& ss) {
    #pragma unroll
    for (int off = 1; off < 64; off <<= 1) {
        s  += __shfl_xor(s,  off, 64);
        ss += __shfl_xor(ss, off, 64);
    }
}

// writes fp32 x AND bf16 xb (bf16 A-operand for dgemm128)
__global__ void k_embed(const int* __restrict__ idx, const float* __restrict__ emb,
                        const float* __restrict__ pos, float* __restrict__ x,
                        bf16* __restrict__ xb) {
    int t = blockIdx.x, l = threadIdx.x;
    int tok = idx[t];
    const float* e = emb + tok * D_DIM;
    const float* p = pos + t * D_DIM;
    float v0 = e[l] + p[l], v1 = e[l + 64] + p[l + 64], v2 = e[l + 128] + p[l + 128];
    float s = v0 + v1 + v2, ss = v0 * v0 + v1 * v1 + v2 * v2;
    wave_sum2(s, ss);
    float m = s / D_DIM, r = rsqrtf(ss / D_DIM - m * m + LN_EPS);
    float* xr = x + t * D_DIM;
    bf16*  xo = xb + (size_t)t * D_DIM;
    float o0 = (v0 - m) * r, o1 = (v1 - m) * r, o2 = (v2 - m) * r;
    xr[l] = o0; xr[l + 64] = o1; xr[l + 128] = o2;
    xo[l] = __float2bfloat16(o0);
    xo[l + 64] = __float2bfloat16(o1);
    xo[l + 128] = __float2bfloat16(o2);
}

__global__ void k_ln(float* __restrict__ buf) {
    int l = threadIdx.x;
    float* row = buf + (size_t)blockIdx.x * D_DIM;
    float v0 = row[l], v1 = row[l + 64], v2 = row[l + 128];
    float s = v0 + v1 + v2, ss = v0 * v0 + v1 * v1 + v2 * v2;
    wave_sum2(s, ss);
    float m = s / D_DIM, r = rsqrtf(ss / D_DIM - m * m + LN_EPS);
    row[l] = (v0 - m) * r; row[l + 64] = (v1 - m) * r; row[l + 128] = (v2 - m) * r;
}

// outb = bf16( LN(P0row + P1row) )  — ykv slab combine + LN + bf16 cast
__global__ void k_ln2b(const float* __restrict__ P0, const float* __restrict__ P1,
                       bf16* __restrict__ outb) {
    int l = threadIdx.x;
    size_t off = (size_t)blockIdx.x * D_DIM;
    const float* r0 = P0 + off;
    const float* r1 = P1 + off;
    float v0 = r0[l] + r1[l];
    float v1 = r0[l + 64] + r1[l + 64];
    float v2 = r0[l + 128] + r1[l + 128];
    float s = v0 + v1 + v2, ss = v0 * v0 + v1 * v1 + v2 * v2;
    wave_sum2(s, ss);
    float m = s / D_DIM, r = rsqrtf(ss / D_DIM - m * m + LN_EPS);
    bf16* o = outb + off;
    o[l]       = __float2bfloat16((v0 - m) * r);
    o[l + 64]  = __float2bfloat16((v1 - m) * r);
    o[l + 128] = __float2bfloat16((v2 - m) * r);
}

// x = LN(x + LN(sum of NSLAB split-K partial slabs)); also writes xb (bf16)
template <int NSLAB>
__global__ void k_resid(float* __restrict__ x, const float* __restrict__ P,
                        bf16* __restrict__ xb) {
    int l = threadIdx.x, t = blockIdx.x;
    float y0 = 0.f, y1 = 0.f, y2 = 0.f;
    #pragma unroll
    for (int p = 0; p < NSLAB; p++) {
        const float* r = P + (size_t)p * T_SEQ * D_DIM + (size_t)t * D_DIM;
        y0 += r[l]; y1 += r[l + 64]; y2 += r[l + 128];
    }
    float* xr = x + (size_t)t * D_DIM;
    float s = y0 + y1 + y2, ss = y0 * y0 + y1 * y1 + y2 * y2;
    wave_sum2(s, ss);
    float m1 = s / D_DIM, r1 = rsqrtf(ss / D_DIM - m1 * m1 + LN_EPS);
    float v0 = xr[l] + (y0 - m1) * r1;
    float v1 = xr[l + 64] + (y1 - m1) * r1;
    float v2 = xr[l + 128] + (y2 - m1) * r1;
    s = v0 + v1 + v2; ss = v0 * v0 + v1 * v1 + v2 * v2;
    wave_sum2(s, ss);
    float m2 = s / D_DIM, r2 = rsqrtf(ss / D_DIM - m2 * m2 + LN_EPS);
    float o0 = (v0 - m2) * r2, o1 = (v1 - m2) * r2, o2 = (v2 - m2) * r2;
    xr[l] = o0; xr[l + 64] = o1; xr[l + 128] = o2;
    bf16* xo = xb + (size_t)t * D_DIM;
    xo[l] = __float2bfloat16(o0);
    xo[l + 64] = __float2bfloat16(o1);
    xo[l + 128] = __float2bfloat16(o2);
}

// RoPE cos/sin tables, interleaved bf16 pairs csT[t][p] = (cos, sin)
__global__ void k_tables(ushort2* __restrict__ csT) {
    int gid = blockIdx.x * 256 + threadIdx.x;
    int t = gid / NP2, p = gid % NP2;
    float qf = (float)(2 * p);
    float f = exp2f(qf * (-16.0f / 3072.0f)) * (1.0f / (float)TWO_PI);
    float ph = fmodf((float)t * f, 1.0f) * (float)TWO_PI;
    ushort2 cs;
    cs.x = f2us(cosf(ph));
    cs.y = f2us(sinf(ph));
    csT[gid] = cs;
}

// ---------------------------------------------------------------------------
// scores64: partial scores, split-K=2, FLAT 1-D grid of 1088 with XCD
// pinning: xcd = bid&7 -> (h = xcd>>1, kh = xcd&1), L = bid>>3. Each XCD's
// working set is one (head, K-half) slice of qr = 3 MB -> resident in its
// private 4 MB L2 (vs 74 MB HBM refetch with the scattered mapping).
//   kh=0: lower-K half -> lower tile (i,j), masked if diag.
//   kh=1 off-diag: upper-K half, swapped operands -> dead upper slot (j,i)
//     in (t,s) orientation. kh=1 diag: masked partial -> dbuf slab.
// ykv dual-A MFMA combines partials in fp32 (no k_comb).
// 64x64 tile, 4 waves x one 32x32x16 MFMA acc, BK=64, double-buffered LDS +
// 2-deep register prefetch, LDS-staged coalesced epilogue.
// ---------------------------------------------------------------------------
__launch_bounds__(256, 4)
__global__ void scores64(const bf16* __restrict__ qr, bf16* __restrict__ sc,
                         bf16* __restrict__ dbuf) {
    const int bid = blockIdx.x;
    const int xcd = bid & 7;
    const int h   = xcd >> 1;
    const int kh  = xcd & 1;
    const int L   = bid >> 3;                      // 0..135, in-order per XCD
    int i = 0;
    while (((i + 1) * (i + 2)) >> 1 <= L) ++i;
    int j = L - ((i * (i + 1)) >> 1);
    const int t0 = i * 64, s0 = j * 64;
    const bool diag = (i == j);

    int arow = t0, brow = s0;
    if (kh == 1 && !diag) { arow = s0; brow = t0; }

    __shared__ short As[2][64][72];
    __shared__ short Bs[2][64][72];

    const int tid = threadIdx.x;
    const int lane = tid & 63, w = tid >> 6;
    const int wtm = (w >> 1) * 32, wtn = (w & 1) * 32;
    const int l31 = lane & 31, lhi = lane >> 5;
    const int r0 = tid >> 2;
    const int kq = (tid & 3) * 16;

    const int kBeg = kh * (N_DIM / 2);
    const bf16* gA = qr + (size_t)(arow + r0) * HN + h * N_DIM + kBeg + kq;
    const bf16* gB = qr + (size_t)(brow + r0) * HN + h * N_DIM + kBeg + kq;

    u16x8 pa0, pa1, pb0, pb1;
    u16x8 qa0, qa1, qb0, qb1;
    auto load0 = [&](int k0) {
        pa0 = *(const u16x8*)(gA + k0);
        pa1 = *(const u16x8*)(gA + k0 + 8);
        pb0 = *(const u16x8*)(gB + k0);
        pb1 = *(const u16x8*)(gB + k0 + 8);
    };
    auto load1 = [&](int k0) {
        qa0 = *(const u16x8*)(gA + k0);
        qa1 = *(const u16x8*)(gA + k0 + 8);
        qb0 = *(const u16x8*)(gB + k0);
        qb1 = *(const u16x8*)(gB + k0 + 8);
    };
    auto dep0 = [&](int buf) {
        *(u16x8*)&As[buf][r0][kq]     = pa0;
        *(u16x8*)&As[buf][r0][kq + 8] = pa1;
        *(u16x8*)&Bs[buf][r0][kq]     = pb0;
        *(u16x8*)&Bs[buf][r0][kq + 8] = pb1;
    };
    auto dep1 = [&](int buf) {
        *(u16x8*)&As[buf][r0][kq]     = qa0;
        *(u16x8*)&As[buf][r0][kq + 8] = qa1;
        *(u16x8*)&Bs[buf][r0][kq]     = qb0;
        *(u16x8*)&Bs[buf][r0][kq + 8] = qb1;
    };

    f32x16 acc;
    #pragma unroll
    for (int r = 0; r < 16; r++) acc[r] = 0.f;

    auto mfma_step = [&](int buf) {
        #pragma unroll
        for (int ks = 0; ks < 4; ks++) {
            s16x8 a = *(const s16x8*)&As[buf][wtm + l31][ks * 16 + lhi * 8];
            s16x8 b = *(const s16x8*)&Bs[buf][wtn + l31][ks * 16 + lhi * 8];
            acc = __builtin_amdgcn_mfma_f32_32x32x16_bf16(a, b, acc, 0, 0, 0);
        }
    };

    const int NIT = (N_DIM / 2) / 64;   // 24 (even)
    load0(0);
    load1(64);
    dep0(0);
    __syncthreads();

    for (int k = 0; k < NIT; k += 2) {
        if (k + 2 < NIT) load0((k + 2) * 64);
        mfma_step(0);
        if (k + 1 < NIT) dep1(1);
        __syncthreads();
        if (k + 1 < NIT) {
            if (k + 3 < NIT) load1((k + 3) * 64);
            mfma_step(1);
            if (k + 2 < NIT) dep0(0);
            __syncthreads();
        }
    }

    __syncthreads();
    short (*S)[72] = (short(*)[72])&As[0][0][0];
    const bool trS = (kh == 1) && !diag;
    #pragma unroll
    for (int r = 0; r < 16; r++) {
        int rr = wtm + (r & 3) + 8 * (r >> 2) + 4 * lhi;
        int cc = wtn + l31;
        float v = acc[r];
        if (diag && cc >= rr) v = 0.f;
        if (trS) S[cc][rr] = (short)f2us(v);
        else     S[rr][cc] = (short)f2us(v);
    }
    __syncthreads();
    if (kh == 1 && diag) {
        bf16* P = dbuf + (size_t)(h * 16 + i) * 4096;
        #pragma unroll
        for (int e = 0; e < 2; e++) {
            int idxe = tid + e * 256;
            int row = idxe >> 3, cg = (idxe & 7) * 8;
            u16x8 v = *(const u16x8*)&S[row][cg];
            *(u16x8*)(P + row * 64 + cg) = v;
        }
    } else {
        bf16* C = sc + (size_t)h * T_SEQ * T_SEQ;
        #pragma unroll
        for (int e = 0; e < 2; e++) {
            int idxe = tid + e * 256;
            int row = idxe >> 3, cg = (idxe & 7) * 8;
            u16x8 v = *(const u16x8*)&S[row][cg];
            *(u16x8*)(C + (size_t)(arow + row) * T_SEQ + brow + cg) = v;
        }
    }
}

// ---------------------------------------------------------------------------
// scores fallback (no qr buffer): 64x64, rope fused into staging.
// ---------------------------------------------------------------------------
__device__ __forceinline__ void stage_rope8(short* dst, const bf16* src,
                                            const ushort2* csP) {
    u16x8 v  = *(const u16x8*)src;
    u16x8 cs = *(const u16x8*)csP;
    u16x8 o;
    #pragma unroll
    for (int i = 0; i < 4; i++) {
        float e  = us2f(v[2 * i]), od = us2f(v[2 * i + 1]);
        float c  = us2f(cs[2 * i]), s = us2f(cs[2 * i + 1]);
        o[2 * i]     = f2us(e * c - od * s);
        o[2 * i + 1] = f2us(od * c + e * s);
    }
    *(u16x8*)dst = o;
}

__launch_bounds__(256)
__global__ void scores_fused(const bf16* __restrict__ xs,
                             const ushort2* __restrict__ csT,
                             bf16* __restrict__ sc) {
    const int h  = blockIdx.z;
    const int s0 = blockIdx.x * 64, t0 = blockIdx.y * 64;
    if (s0 > t0) return;
    __shared__ short As[64][40];
    __shared__ short Bs[64][40];
    const int tid  = threadIdx.x;
    const int srow = tid >> 2, kq = (tid & 3) * 8;
    const int lane = tid & 63, w = tid >> 6, qd = lane >> 4, lc = lane & 15;
    const int tA = t0 + srow, tB = s0 + srow;
    const bf16* gA = xs + (size_t)tA * HN + h * N_DIM + kq;
    const bf16* gB = xs + (size_t)tB * HN + h * N_DIM + kq;
    const ushort2* cA = csT + (size_t)tA * NP2 + (kq >> 1);
    const ushort2* cB = csT + (size_t)tB * NP2 + (kq >> 1);
    f32x4 acc[4] = {{0.f,0.f,0.f,0.f},{0.f,0.f,0.f,0.f},
                    {0.f,0.f,0.f,0.f},{0.f,0.f,0.f,0.f}};
    for (int k0 = 0; k0 < N_DIM; k0 += 32) {
        stage_rope8(&As[srow][kq], gA + k0, cA + (k0 >> 1));
        stage_rope8(&Bs[srow][kq], gB + k0, cB + (k0 >> 1));
        __syncthreads();
        s16x8 a = *(const s16x8*)&As[w * 16 + lc][qd * 8];
        #pragma unroll
        for (int j = 0; j < 4; j++) {
            s16x8 b = *(const s16x8*)&Bs[j * 16 + lc][qd * 8];
            acc[j] = __builtin_amdgcn_mfma_f32_16x16x32_bf16(a, b, acc[j], 0, 0, 0);
        }
        __syncthreads();
    }
    bf16* C = sc + (size_t)h * T_SEQ * T_SEQ;
    const bool diag = (s0 == t0);
    const int tbase = t0 + w * 16 + qd * 4;
    #pragma unroll
    for (int j = 0; j < 4; j++) {
        int s = s0 + j * 16 + lc;
        #pragma unroll
        for (int r = 0; r < 4; r++) {
            int t = tbase + r;
            C[(size_t)t * T_SEQ + s] =
                __float2bfloat16((!diag || s < t) ? acc[j][r] : 0.f);
        }
    }
}

// ---------------------------------------------------------------------------
// dgemm128: 128x128 tile, 4 waves x (64x64 = 2x2 of 32x32x16 MFMA accs),
// K=192 (BK=32), double-buffered LDS + 2-deep register prefetch, LDS-staged
// coalesced epilogue (relu / rope / gate). TA = bf16 or float.
// ---------------------------------------------------------------------------
template <int EPI, bool WQR, typename TA>
__launch_bounds__(256)
__global__ void dgemm128(const TA* __restrict__ A, const bf16* __restrict__ Bt,
                         bf16* __restrict__ xs, bf16* __restrict__ qr,
                         const ushort2* __restrict__ csT) {
    __shared__ __align__(16) short pool[2 * 2 * 128 * 40];   // 40 KB
    short (*As)[128][40] = (short(*)[128][40])pool;
    short (*Bs)[128][40] = (short(*)[128][40])(pool + 2 * 128 * 40);

    const int tid = threadIdx.x;
    const int lane = tid & 63, w = tid >> 6;
    const int l31 = lane & 31, lhi = lane >> 5;
    const int wtm = (w >> 1) * 64, wtn = (w & 1) * 64;
    const int n0 = blockIdx.x * 128, m0 = blockIdx.y * 128;
    if constexpr (EPI == 2) A += (size_t)(n0 / N_DIM) * T_SEQ * D_DIM;

    const int r0 = tid >> 2, r1 = r0 + 64;
    const int kq = (tid & 3) * 8;

    const TA*   gA = A  + kq;
    const bf16* gB = Bt + kq;

    float4 fa00, fa01, fa02, fa03, fa10, fa11, fa12, fa13;
    u16x8 ba00, ba01, ba10, ba11;
    u16x8 pb00, pb01, pb10, pb11;
    auto load0 = [&](int k0) {
        if constexpr (__is_same(TA, float)) {
            const TA* a0 = gA + (size_t)(m0 + r0) * D_DIM + k0;
            const TA* a1 = gA + (size_t)(m0 + r1) * D_DIM + k0;
            fa00 = *(const float4*)a0; fa01 = *(const float4*)(a0 + 4);
            fa02 = *(const float4*)a1; fa03 = *(const float4*)(a1 + 4);
        } else {
            ba00 = *(const u16x8*)(gA + (size_t)(m0 + r0) * D_DIM + k0);
            ba01 = *(const u16x8*)(gA + (size_t)(m0 + r1) * D_DIM + k0);
        }
        pb00 = *(const u16x8*)(gB + (size_t)(n0 + r0) * D_DIM + k0);
        pb01 = *(const u16x8*)(gB + (size_t)(n0 + r1) * D_DIM + k0);
    };
    auto load1 = [&](int k0) {
        if constexpr (__is_same(TA, float)) {
            const TA* a0 = gA + (size_t)(m0 + r0) * D_DIM + k0;
            const TA* a1 = gA + (size_t)(m0 + r1) * D_DIM + k0;
            fa10 = *(const float4*)a0; fa11 = *(const float4*)(a0 + 4);
            fa12 = *(const float4*)a1; fa13 = *(const float4*)(a1 + 4);
        } else {
            ba10 = *(const u16x8*)(gA + (size_t)(m0 + r0) * D_DIM + k0);
            ba11 = *(const u16x8*)(gA + (size_t)(m0 + r1) * D_DIM + k0);
        }
        pb10 = *(const u16x8*)(gB + (size_t)(n0 + r0) * D_DIM + k0);
        pb11 = *(const u16x8*)(gB + (size_t)(n0 + r1) * D_DIM + k0);
    };
    auto dep0 = [&](int buf) {
        if constexpr (__is_same(TA, float)) {
            u16x8 o0, o1;
            o0[0] = f2us(fa00.x); o0[1] = f2us(fa00.y); o0[2] = f2us(fa00.z); o0[3] = f2us(fa00.w);
            o0[4] = f2us(fa01.x); o0[5] = f2us(fa01.y); o0[6] = f2us(fa01.z); o0[7] = f2us(fa01.w);
            o1[0] = f2us(fa02.x); o1[1] = f2us(fa02.y); o1[2] = f2us(fa02.z); o1[3] = f2us(fa02.w);
            o1[4] = f2us(fa03.x); o1[5] = f2us(fa03.y); o1[6] = f2us(fa03.z); o1[7] = f2us(fa03.w);
            *(u16x8*)&As[buf][r0][kq] = o0;
            *(u16x8*)&As[buf][r1][kq] = o1;
        } else {
            *(u16x8*)&As[buf][r0][kq] = ba00;
            *(u16x8*)&As[buf][r1][kq] = ba01;
        }
        *(u16x8*)&Bs[buf][r0][kq] = pb00;
        *(u16x8*)&Bs[buf][r1][kq] = pb01;
    };
    auto dep1 = [&](int buf) {
        if constexpr (__is_same(TA, float)) {
            u16x8 o0, o1;
            o0[0] = f2us(fa10.x); o0[1] = f2us(fa10.y); o0[2] = f2us(fa10.z); o0[3] = f2us(fa10.w);
            o0[4] = f2us(fa11.x); o0[5] = f2us(fa11.y); o0[6] = f2us(fa11.z); o0[7] = f2us(fa11.w);
            o1[0] = f2us(fa12.x); o1[1] = f2us(fa12.y); o1[2] = f2us(fa12.z); o1[3] = f2us(fa12.w);
            o1[4] = f2us(fa13.x); o1[5] = f2us(fa13.y); o1[6] = f2us(fa13.z); o1[7] = f2us(fa13.w);
            *(u16x8*)&As[buf][r0][kq] = o0;
            *(u16x8*)&As[buf][r1][kq] = o1;
        } else {
            *(u16x8*)&As[buf][r0][kq] = ba10;
            *(u16x8*)&As[buf][r1][kq] = ba11;
        }
        *(u16x8*)&Bs[buf][r0][kq] = pb10;
        *(u16x8*)&Bs[buf][r1][kq] = pb11;
    };

    f32x16 acc00, acc01, acc10, acc11;
    #pragma unroll
    for (int r = 0; r < 16; r++) { acc00[r] = 0.f; acc01[r] = 0.f; acc10[r] = 0.f; acc11[r] = 0.f; }

    auto mfma_step = [&](int buf) {
        #pragma unroll
        for (int ks = 0; ks < 2; ks++) {
            s16x8 a0 = *(const s16x8*)&As[buf][wtm + l31][ks * 16 + lhi * 8];
            s16x8 a1 = *(const s16x8*)&As[buf][wtm + 32 + l31][ks * 16 + lhi * 8];
            s16x8 b0 = *(const s16x8*)&Bs[buf][wtn + l31][ks * 16 + lhi * 8];
            s16x8 b1 = *(const s16x8*)&Bs[buf][wtn + 32 + l31][ks * 16 + lhi * 8];
            acc00 = __builtin_amdgcn_mfma_f32_32x32x16_bf16(a0, b0, acc00, 0, 0, 0);
            acc01 = __builtin_amdgcn_mfma_f32_32x32x16_bf16(a0, b1, acc01, 0, 0, 0);
            acc10 = __builtin_amdgcn_mfma_f32_32x32x16_bf16(a1, b0, acc10, 0, 0, 0);
            acc11 = __builtin_amdgcn_mfma_f32_32x32x16_bf16(a1, b1, acc11, 0, 0, 0);
        }
    };

    const int NIT = D_DIM / 32;   // 6 (even)
    load0(0);
    load1(32);
    dep0(0);
    __syncthreads();
    for (int k = 0; k < NIT; k += 2) {
        if (k + 2 < NIT) load0((k + 2) * 32);
        mfma_step(0);
        if (k + 1 < NIT) dep1(1);
        __syncthreads();
        if (k + 1 < NIT) {
            if (k + 3 < NIT) load1((k + 3) * 32);
            mfma_step(1);
            if (k + 2 < NIT) dep0(0);
            __syncthreads();
        }
    }

    // -------- LDS-staged epilogue --------
    short (*S)[136] = (short(*)[136])pool; // 128 x 136 shorts = 34.8 KB <= 40 KB
    #pragma unroll
    for (int r = 0; r < 16; r++) {
        int rb = (r & 3) + 8 * (r >> 2) + 4 * lhi;
        S[wtm + rb     ][wtn + l31     ] = (short)f2us(fmaxf(acc00[r], 0.f));
        S[wtm + rb     ][wtn + 32 + l31] = (short)f2us(fmaxf(acc01[r], 0.f));
        S[wtm + 32 + rb][wtn + l31     ] = (short)f2us(fmaxf(acc10[r], 0.f));
        S[wtm + 32 + rb][wtn + 32 + l31] = (short)f2us(fmaxf(acc11[r], 0.f));
    }
    __syncthreads();
    #pragma unroll
    for (int e = 0; e < 8; e++) {
        int idxe = tid + e * 256;
        int row = idxe >> 4, cg = idxe & 15;
        u16x8 v = *(const u16x8*)&S[row][cg * 8];
        int t = m0 + row, ngg = n0 + cg * 8;
        size_t ci = (size_t)t * HN + ngg;
        if constexpr (EPI == 1) {
            *(u16x8*)(xs + ci) = v;
            if constexpr (WQR) {
                int p0 = (ngg % N_DIM) >> 1;
                u16x8 cs8 = *(const u16x8*)&csT[(size_t)t * NP2 + p0];
                u16x8 o;
                #pragma unroll
                for (int q = 0; q < 4; q++) {
                    float ev = us2f(v[2 * q]), ov = us2f(v[2 * q + 1]);
                    float c = us2f(cs8[2 * q]), s = us2f(cs8[2 * q + 1]);
                    o[2 * q]     = f2us(ev * c - ov * s);
                    o[2 * q + 1] = f2us(ov * c + ev * s);
                }
                *(u16x8*)(qr + ci) = o;
            }
        } else {
            u16x8 g = *(const u16x8*)(xs + ci);
            u16x8 o;
            #pragma unroll
            for (int q = 0; q < 8; q++) o[q] = f2us(us2f(g[q]) * us2f(v[q]));
            *(u16x8*)(xs + ci) = o;
        }
    }
}

// ---------------------------------------------------------------------------
// gate_ymlp: fused  ymlp_slab = (xs ⊙ relu(ykvb @ decY)) @ enc.
// FLAT grid of 256 with XCD pinning: s = (bid&7) + 8*(bid>>7),
// tb = (bid>>3)&15 — each XCD owns 2 n-segments (weights 1.2 MB + xs slice
// 3 MB -> L2-resident).
// ---------------------------------------------------------------------------
__launch_bounds__(256, 2)
__global__ void gate_ymlp(const bf16* __restrict__ ykvb, const bf16* __restrict__ wY,
                          const bf16* __restrict__ xs, const bf16* __restrict__ wE,
                          float* __restrict__ P) {
    const int bid = blockIdx.x;
    const int s   = (bid & 7) + ((bid >> 7) << 3);   // 0..15, pinned by XCD
    const int tb  = (bid >> 3) & 15;                 // 0..15
    const int t0  = tb * 64;
    const int h   = s >> 2;               // 4 segments of 768 per head
    const int ng0 = s * 768;              // global n base of this slab
    const int nh0 = (s & 3) * 768;        // within-head n base

    __shared__ __align__(16) short A1s[64][200];   // ykvb tile   (25.6 KB)
    __shared__ __align__(16) short Bsh[192][72];   // B2 view     (27.6 KB)
    __shared__ __align__(16) short xyA[64][72];    // xy chunk    ( 9.2 KB)
    short (*B1)[200] = (short(*)[200])&Bsh[0][0];  // B1 overlays B2 (12800<=13824)

    const int tid = threadIdx.x;
    const int lane = tid & 63, w = tid >> 6;
    const int l31 = lane & 31, lhi = lane >> 5;
    const int wm  = (w >> 1) * 32;        // t-offset of wave
    const int wn1 = (w & 1) * 32;         // n-offset (stage1)
    const int wn2 = (w & 1) * 96;         // d-offset (stage2)

    // load A1 = ykvb[h][t0..t0+64][0..192] once
    {
        const bf16* src = ykvb + ((size_t)h * T_SEQ + t0 + (tid >> 2)) * D_DIM
                        + (tid & 3) * 48;
        #pragma unroll
        for (int j = 0; j < 6; j++) {
            u16x8 v = *(const u16x8*)(src + j * 8);
            *(u16x8*)&A1s[tid >> 2][(tid & 3) * 48 + j * 8] = v;
        }
    }

    f32x16 oc0, oc1, oc2;
    #pragma unroll
    for (int r = 0; r < 16; r++) { oc0[r] = 0.f; oc1[r] = 0.f; oc2[r] = 0.f; }

    __syncthreads();

    for (int c = 0; c < 12; c++) {
        const int nc = c * 64;
        // stage B1 = wY[h][nh0+nc+r][0..192]
        {
            const bf16* src = wY + ((size_t)h * N_DIM + nh0 + nc + (tid >> 2)) * D_DIM
                            + (tid & 3) * 48;
            #pragma unroll
            for (int j = 0; j < 6; j++) {
                u16x8 v = *(const u16x8*)(src + j * 8);
                *(u16x8*)&B1[tid >> 2][(tid & 3) * 48 + j * 8] = v;
            }
        }
        __syncthreads();
        // stage1: ys(64x64) over K=192
        f32x16 ys;
        #pragma unroll
        for (int r = 0; r < 16; r++) ys[r] = 0.f;
        #pragma unroll
        for (int ks = 0; ks < 12; ks++) {
            s16x8 a = *(const s16x8*)&A1s[wm + l31][ks * 16 + lhi * 8];
            s16x8 b = *(const s16x8*)&B1[wn1 + l31][ks * 16 + lhi * 8];
            ys = __builtin_amdgcn_mfma_f32_32x32x16_bf16(a, b, ys, 0, 0, 0);
        }
        __syncthreads();                      // all waves done with B1 / prev xyA
        // scatter relu(ys) -> xyA (bf16)
        #pragma unroll
        for (int r = 0; r < 16; r++) {
            int rr = wm + (r & 3) + 8 * (r >> 2) + 4 * lhi;
            xyA[rr][wn1 + l31] = (short)f2us(fmaxf(ys[r], 0.f));
        }
        __syncthreads();
        // RMW with xs chunk (coalesced u16x8)
        {
            int row = tid >> 2, c0l = (tid & 3) * 16;
            const bf16* sx = xs + (size_t)(t0 + row) * HN + ng0 + nc + c0l;
            #pragma unroll
            for (int e = 0; e < 2; e++) {
                u16x8 g = *(const u16x8*)(sx + e * 8);
                u16x8 y = *(const u16x8*)&xyA[row][c0l + e * 8];
                u16x8 o;
                #pragma unroll
                for (int q = 0; q < 8; q++) o[q] = f2us(us2f(g[q]) * us2f(y[q]));
                *(u16x8*)&xyA[row][c0l + e * 8] = o;
            }
        }
        // stage B2 = wE[d][ng0+nc .. +64]   (overwrites B1 — stage1 done)
        {
            #pragma unroll
            for (int j = 0; j < 3; j++) {
                int d  = (tid >> 2) * 3 + j;          // 0..191
                int cc = (tid & 3) * 16;
                const bf16* src = wE + (size_t)d * HN + ng0 + nc + cc;
                u16x8 v0 = *(const u16x8*)src;
                u16x8 v1 = *(const u16x8*)(src + 8);
                *(u16x8*)&Bsh[d][cc]     = v0;
                *(u16x8*)&Bsh[d][cc + 8] = v1;
            }
        }
        __syncthreads();
        // stage2: out += xyA(64x64) @ wE-chunk^T(192x64), K=64
        #pragma unroll
        for (int ks = 0; ks < 4; ks++) {
            s16x8 a  = *(const s16x8*)&xyA[wm + l31][ks * 16 + lhi * 8];
            s16x8 b0 = *(const s16x8*)&Bsh[wn2 + l31     ][ks * 16 + lhi * 8];
            s16x8 b1 = *(const s16x8*)&Bsh[wn2 + 32 + l31][ks * 16 + lhi * 8];
            s16x8 b2 = *(const s16x8*)&Bsh[wn2 + 64 + l31][ks * 16 + lhi * 8];
            oc0 = __builtin_amdgcn_mfma_f32_32x32x16_bf16(a, b0, oc0, 0, 0, 0);
            oc1 = __builtin_amdgcn_mfma_f32_32x32x16_bf16(a, b1, oc1, 0, 0, 0);
            oc2 = __builtin_amdgcn_mfma_f32_32x32x16_bf16(a, b2, oc2, 0, 0, 0);
        }
        __syncthreads();                      // before next chunk's B1/xyA writes
    }

    // write slab P[s][t][d]
    float* O = P + (size_t)s * T_SEQ * D_DIM;
    #pragma unroll
    for (int r = 0; r < 16; r++) {
        int rt = t0 + wm + (r & 3) + 8 * (r >> 2) + 4 * lhi;
        O[(size_t)rt * D_DIM + wn2 +      l31] = oc0[r];
        O[(size_t)rt * D_DIM + wn2 + 32 + l31] = oc1[r];
        O[(size_t)rt * D_DIM + wn2 + 64 + l31] = oc2[r];
    }
}

// ---------------------------------------------------------------------------
// mfma_gemm (64x64): MODE 0 = plain, 1 = causal split-K=2 WITH dual-A partial
// combine AND flat-grid XCD pinning (bid&7 = z = head*2+seg: each XCD owns
// one (head,seg) -> sc slice + xT resident in its L2), 2 = split-K slabs
// over z (fallback ymlp), 3 = causal full (fallback). 32x32x16 MFMA, BK=64,
// double-buffered LDS + 2-deep prefetch.
// ---------------------------------------------------------------------------
template <typename TA, int MODE>
__launch_bounds__(256)
__global__ void mfma_gemm(const TA* __restrict__ A, const bf16* __restrict__ Bt,
                          float* __restrict__ C, const bf16* __restrict__ aux,
                          int K, int kSeg, int lda, int ldb, int ldc,
                          long aZ, long bZ, long cZ) {
    constexpr bool DUAL = (MODE == 1);
    constexpr int TILES = DUAL ? 6 : 4;
    __shared__ __align__(16) short pool[TILES * 64 * 72];
    short (*As)[64][72] = (short(*)[64][72])pool;
    short (*Bs)[64][72] = (short(*)[64][72])(pool + 2 * 64 * 72);
    short (*Ms)[64][72] = (short(*)[64][72])(pool + 4 * 64 * 72);

    int bx, by, z;
    if constexpr (MODE == 1) {
        // flat grid 384: xcd = bid&7 = z (head*2+seg); rest enumerates (x,y)
        const int bid  = blockIdx.x;
        z = bid & 7;
        const int rest = bid >> 3;      // 0..47
        bx = rest % 3;
        by = rest / 3;
    } else {
        bx = blockIdx.x; by = blockIdx.y; z = blockIdx.z;
    }

    const int tid = threadIdx.x;
    const int n0 = bx * 64, m0 = by * 64;
    const int srow = tid >> 2, sk = (tid & 3) * 16;
    const int lane = tid & 63, w = tid >> 6;
    const int l31 = lane & 31, lhi = lane >> 5;
    const int wm = (w >> 1) * 32, wn = (w & 1) * 32;

    int kBeg, kEnd, zh = 0;
    if constexpr (MODE == 1) {
        zh = z >> 1;
        const int seg = z & 1;
        A += aZ * zh;
        C += cZ * zh + bZ * seg;
        const int kc = (m0 + 64 < K) ? m0 + 64 : K;
        const int half0 = ((kc + 127) >> 7) << 6;   // ceil(kc/128)*64
        kBeg = seg ? half0 : 0;
        kEnd = seg ? kc : half0;
    } else if constexpr (MODE == 2) {
        A += aZ * z; Bt += bZ * z; C += cZ * z;
        kBeg = z * kSeg; kEnd = kBeg + kSeg;
    } else if constexpr (MODE == 3) {
        A += aZ * z; Bt += bZ * z; C += cZ * z;
        kBeg = 0; kEnd = (m0 + 64 < K) ? m0 + 64 : K;
    } else {
        A += aZ * z; Bt += bZ * z; C += cZ * z;
        kBeg = 0; kEnd = K;
    }

    const TA*   ga = A  + (size_t)(m0 + srow) * lda + sk;
    const bf16* gb = Bt + (size_t)(n0 + srow) * ldb + sk;

    auto msrc = [&](int k0) -> const bf16* {
        if (k0 == m0)
            return aux + (size_t)(zh * 16 + (m0 >> 6)) * 4096
                       + (size_t)srow * 64 + sk;
        return (const bf16*)A + (size_t)(k0 + srow) * lda + m0 + sk;
    };

    float4 f00, f01, f02, f03, f10, f11, f12, f13;
    u16x8 pa00, pa01, pa10, pa11, pb00, pb01, pb10, pb11;
    u16x8 pm00, pm01, pm10, pm11;
    auto load0 = [&](int k0) {
        if constexpr (__is_same(TA, float)) {
            f00 = *(const float4*)(ga + k0);
            f01 = *(const float4*)(ga + k0 + 4);
            f02 = *(const float4*)(ga + k0 + 8);
            f03 = *(const float4*)(ga + k0 + 12);
        } else {
            pa00 = *(const u16x8*)(ga + k0);
            pa01 = *(const u16x8*)(ga + k0 + 8);
        }
        pb00 = *(const u16x8*)(gb + k0);
        pb01 = *(const u16x8*)(gb + k0 + 8);
        if constexpr (DUAL) {
            const bf16* ms = msrc(k0);
            pm00 = *(const u16x8*)ms;
            pm01 = *(const u16x8*)(ms + 8);
        }
    };
    auto load1 = [&](int k0) {
        if constexpr (__is_same(TA, float)) {
            f10 = *(const float4*)(ga + k0);
            f11 = *(const float4*)(ga + k0 + 4);
            f12 = *(const float4*)(ga + k0 + 8);
            f13 = *(const float4*)(ga + k0 + 12);
        } else {
            pa10 = *(const u16x8*)(ga + k0);
            pa11 = *(const u16x8*)(ga + k0 + 8);
        }
        pb10 = *(const u16x8*)(gb + k0);
        pb11 = *(const u16x8*)(gb + k0 + 8);
        if constexpr (DUAL) {
            const bf16* ms = msrc(k0);
            pm10 = *(const u16x8*)ms;
            pm11 = *(const u16x8*)(ms + 8);
        }
    };
    auto dep0 = [&](int buf) {
        if constexpr (__is_same(TA, float)) {
            u16x8 o0, o1;
            o0[0] = f2us(f00.x); o0[1] = f2us(f00.y); o0[2] = f2us(f00.z); o0[3] = f2us(f00.w);
            o0[4] = f2us(f01.x); o0[5] = f2us(f01.y); o0[6] = f2us(f01.z); o0[7] = f2us(f01.w);
            o1[0] = f2us(f02.x); o1[1] = f2us(f02.y); o1[2] = f2us(f02.z); o1[3] = f2us(f02.w);
            o1[4] = f2us(f03.x); o1[5] = f2us(f03.y); o1[6] = f2us(f03.z); o1[7] = f2us(f03.w);
            *(u16x8*)&As[buf][srow][sk]     = o0;
            *(u16x8*)&As[buf][srow][sk + 8] = o1;
        } else {
            *(u16x8*)&As[buf][srow][sk]     = pa00;
            *(u16x8*)&As[buf][srow][sk + 8] = pa01;
        }
        *(u16x8*)&Bs[buf][srow][sk]     = pb00;
        *(u16x8*)&Bs[buf][srow][sk + 8] = pb01;
        if constexpr (DUAL) {
            *(u16x8*)&Ms[buf][srow][sk]     = pm00;
            *(u16x8*)&Ms[buf][srow][sk + 8] = pm01;
        }
    };
    auto dep1 = [&](int buf) {
        if constexpr (__is_same(TA, float)) {
            u16x8 o0, o1;
            o0[0] = f2us(f10.x); o0[1] = f2us(f10.y); o0[2] = f2us(f10.z); o0[3] = f2us(f10.w);
            o0[4] = f2us(f11.x); o0[5] = f2us(f11.y); o0[6] = f2us(f11.z); o0[7] = f2us(f11.w);
            o1[0] = f2us(f12.x); o1[1] = f2us(f12.y); o1[2] = f2us(f12.z); o1[3] = f2us(f12.w);
            o1[4] = f2us(f13.x); o1[5] = f2us(f13.y); o1[6] = f2us(f13.z); o1[7] = f2us(f13.w);
            *(u16x8*)&As[buf][srow][sk]     = o0;
            *(u16x8*)&As[buf][srow][sk + 8] = o1;
        } else {
            *(u16x8*)&As[buf][srow][sk]     = pa10;
            *(u16x8*)&As[buf][srow][sk + 8] = pa11;
        }
        *(u16x8*)&Bs[buf][srow][sk]     = pb10;
        *(u16x8*)&Bs[buf][srow][sk + 8] = pb11;
        if constexpr (DUAL) {
            *(u16x8*)&Ms[buf][srow][sk]     = pm10;
            *(u16x8*)&Ms[buf][srow][sk + 8] = pm11;
        }
    };

    f32x16 acc;
    #pragma unroll
    for (int r = 0; r < 16; r++) acc[r] = 0.f;

    auto mfma_step = [&](int buf) {
        #pragma unroll
        for (int ks = 0; ks < 4; ks++) {
            s16x8 a = *(const s16x8*)&As[buf][wm + l31][ks * 16 + lhi * 8];
            s16x8 b = *(const s16x8*)&Bs[buf][wn + l31][ks * 16 + lhi * 8];
            acc = __builtin_amdgcn_mfma_f32_32x32x16_bf16(a, b, acc, 0, 0, 0);
            if constexpr (DUAL) {
                s16x8 m2 = *(const s16x8*)&Ms[buf][wm + l31][ks * 16 + lhi * 8];
                acc = __builtin_amdgcn_mfma_f32_32x32x16_bf16(m2, b, acc, 0, 0, 0);
            }
        }
    };

    const int NIT = (kEnd - kBeg) >> 6;
    load0(kBeg);
    load1(kBeg + 64);
    dep0(0);
    __syncthreads();

    for (int k = 0; k < NIT; k += 2) {
        if (k + 2 < NIT) load0(kBeg + (k + 2) * 64);
        mfma_step(0);
        if (k + 1 < NIT) dep1(1);
        __syncthreads();
        if (k + 1 < NIT) {
            if (k + 3 < NIT) load1(kBeg + (k + 3) * 64);
            mfma_step(1);
            if (k + 2 < NIT) dep0(0);
            __syncthreads();
        }
    }

    #pragma unroll
    for (int r = 0; r < 16; r++) {
        int row = m0 + wm + (r & 3) + 8 * (r >> 2) + 4 * lhi;
        int col = n0 + wn + l31;
        C[(size_t)row * ldc + col] = acc[r];
    }
}

extern "C" void kernel_launch(void* const* d_in, const int* in_sizes, int n_in,
                              void* d_out, int out_size, void* d_ws, size_t ws_size,
                              hipStream_t stream) {
    const int*   idx   = (const int*)  d_in[0];
    const float* dec_x = (const float*)d_in[1];   // (NH, D, N)
    const float* dec_y = (const float*)d_in[2];   // (NH, D, N)
    const float* enc   = (const float*)d_in[3];   // (NH*N, D)
    const float* emb   = (const float*)d_in[4];   // (VOCAB, D)
    const float* pose  = (const float*)d_in[5];   // (BLOCK, D)
    const float* lmh   = (const float*)d_in[6];   // (D, VOCAB)
    float* out = (float*)d_out;                   // (T, VOCAB) fp32

    // workspace layout — identical to passing r11 (ws >= 84,377,600 proven)
    char* wp = (char*)d_ws;
    float*   x    = (float*)wp;              wp += (size_t)T_SEQ * D_DIM * 4;
    bf16*    xs   = (bf16*)wp;               wp += (size_t)T_SEQ * HN * 2;
    ushort2* csT  = (ushort2*)wp;            wp += (size_t)T_SEQ * NP2 * 4;
    bf16*    sc   = (bf16*)wp;               wp += (size_t)NHEAD * T_SEQ * T_SEQ * 2;
    float*   ykv  = (float*)wp;              wp += (size_t)NHEAD * T_SEQ * D_DIM * 4;
    float*   ymlp = (float*)wp;              wp += (size_t)T_SEQ * D_DIM * 4;   // dbuf home
    bf16*    xT   = (bf16*)wp;               wp += (size_t)D_DIM * T_SEQ * 2;
    bf16*    wX   = (bf16*)wp;               wp += (size_t)NHEAD * N_DIM * D_DIM * 2;
    bf16*    wY   = (bf16*)wp;               wp += (size_t)NHEAD * N_DIM * D_DIM * 2;
    bf16*    wE   = (bf16*)wp;               wp += (size_t)D_DIM * HN * 2;
    bf16*    wL   = (bf16*)wp;               wp += (size_t)VOCABSZ * D_DIM * 2;
    const size_t BASE_NEED = (size_t)(wp - (char*)d_ws);
    bf16*    qr   = (bf16*)wp;
    const size_t FULL_NEED = BASE_NEED + (size_t)T_SEQ * HN * 2;
    bf16*  dbuf  = (bf16*)ymlp;    // 512 KB diag partials on idle ymlp keeper

    if (ws_size < BASE_NEED) {
        fill_out<<<(out_size + 255) / 256, 256, 0, stream>>>(out, (float)ws_size, out_size);
        return;
    }
    const bool USE_QR = (ws_size >= FULL_NEED);

    // bf16 A-operand homes (main path): xb on dead sc head; ymlpP16 + ykvb
    // on dead qr region. Fallback: xb on ymlp keeper; ymlpP8 on sc.
    bf16*  xb_main = (bf16*)sc;
    bf16*  xb_fb   = (bf16*)ymlp;
    float* ymlpP16 = (float*)qr;                               // 16 slabs
    bf16*  ykvb    = (bf16*)((char*)qr + (size_t)16 * T_SEQ * D_DIM * 4);
    float* ymlpP8  = (float*)sc;                               // fallback slabs

    bf16* xb = USE_QR ? xb_main : xb_fb;

    // weight mirrors (bf16, [n][k])
    t_cvt<<<dim3(48, 3, 4), 256, 0, stream>>>(dec_x, wX, D_DIM, N_DIM,
                                              (long)D_DIM * N_DIM, (long)N_DIM * D_DIM);
    t_cvt<<<dim3(48, 3, 4), 256, 0, stream>>>(dec_y, wY, D_DIM, N_DIM,
                                              (long)D_DIM * N_DIM, (long)N_DIM * D_DIM);
    t_cvt<<<dim3(3, 192, 1), 256, 0, stream>>>(enc, wE, HN, D_DIM, 0L, 0L);
    t_cvt<<<dim3(4, 3, 1), 256, 0, stream>>>(lmh, wL, D_DIM, VOCABSZ, 0L, 0L);

    k_tables<<<(T_SEQ * NP2) / 256, 256, 0, stream>>>(csT);
    k_embed<<<T_SEQ, 64, 0, stream>>>(idx, emb, pose, x, xb);

    for (int l = 0; l < NLAYER; ++l) {
        // xT = x^T (bf16) for ykv's B operand
        t_cvt<<<dim3(3, 16, 1), 256, 0, stream>>>(x, xT, T_SEQ, D_DIM, 0L, 0L);
        if (USE_QR) {
            // xs = relu(x @ dec_x), qr = rope(xs)
            dgemm128<1, true, bf16><<<dim3(96, 8), 256, 0, stream>>>(xb, wX, xs, qr, csT);
            // flat 1088, XCD-pinned (h,kh)
            scores64<<<dim3(1088), 256, 0, stream>>>(qr, sc, dbuf);
            // ykv = sc @ x  (causal, split-K=2, dual-A partial combine;
            // slab1 on qr head; flat 384, XCD-pinned (h,seg))
            long segZ = (long)((float*)qr - ykv);
            mfma_gemm<bf16, 1><<<dim3(384), 256, 0, stream>>>(
                sc, xT, ykv, dbuf, T_SEQ, 0, T_SEQ, T_SEQ, D_DIM,
                (long)T_SEQ * T_SEQ, segZ, (long)T_SEQ * D_DIM);
            // ykvb = bf16(LN(slab0 + slab1))
            k_ln2b<<<NHEAD * T_SEQ, 64, 0, stream>>>(ykv, (const float*)qr, ykvb);
            // fused: ymlp slabs = (xs ⊙ relu(ykvb @ decY)) @ enc
            // flat 256, XCD-pinned segments
            gate_ymlp<<<dim3(256), 256, 0, stream>>>(ykvb, wY, xs, wE, ymlpP16);
            // x = LN(x + LN(sum partials)); xb refreshed
            k_resid<16><<<T_SEQ, 64, 0, stream>>>(x, ymlpP16, xb);
        } else {
            dgemm128<1, false, bf16><<<dim3(96, 8), 256, 0, stream>>>(xb, wX, xs, qr, csT);
            scores_fused<<<dim3(16, 16, NHEAD), 256, 0, stream>>>(xs, csT, sc);
            mfma_gemm<bf16, 3><<<dim3(3, 16, NHEAD), 256, 0, stream>>>(
                sc, xT, ykv, nullptr, T_SEQ, 0, T_SEQ, T_SEQ, D_DIM,
                (long)T_SEQ * T_SEQ, 0L, (long)T_SEQ * D_DIM);
            k_ln<<<NHEAD * T_SEQ, 64, 0, stream>>>(ykv);
            dgemm128<2, false, float><<<dim3(96, 8), 256, 0, stream>>>(
                ykv, wY, xs, nullptr, nullptr);
            mfma_gemm<bf16, 2><<<dim3(3, 16, 8), 256, 0, stream>>>(
                xs, wE, ymlpP8, nullptr, HN, HN / 8, HN, HN, D_DIM,
                0L, 0L, (long)T_SEQ * D_DIM);
            k_resid<8><<<T_SEQ, 64, 0, stream>>>(x, ymlpP8, xb);
        }
    }

    // logits = x @ lm_head
    mfma_gemm<float, 0><<<dim3(4, 16, 1), 256, 0, stream>>>(
        x, wL, out, nullptr, D_DIM, 0, D_DIM, D_DIM, VOCABSZ, 0L, 0L, 0L);
}

// Round 12
// 466.423 us; speedup vs baseline: 1.1132x; 1.0032x over previous
//
#include <hip/hip_runtime.h>
#include <hip/hip_bf16.h>

using bf16 = __hip_bfloat16;

#define D_DIM   192
#define N_DIM   3072
#define NHEAD   4
#define T_SEQ   1024
#define HN      12288      // NHEAD * N_DIM
#define NP2     1536       // N_DIM/2
#define VOCABSZ 256
#define NLAYER  4
#define LN_EPS  1e-5f
#define TWO_PI  6.2831853071795864f

typedef __attribute__((ext_vector_type(8)))  short          s16x8;
typedef __attribute__((ext_vector_type(8)))  unsigned short u16x8;
typedef __attribute__((ext_vector_type(4)))  float          f32x4;
typedef __attribute__((ext_vector_type(16))) float          f32x16;

__device__ __forceinline__ float b2f(bf16 v) { return __bfloat162float(v); }
__device__ __forceinline__ float us2f(unsigned short u) {
    unsigned int x = ((unsigned int)u) << 16;
    return __builtin_bit_cast(float, x);
}
__device__ __forceinline__ unsigned short f2us(float f) {
    bf16 b = __float2bfloat16(f);
    return __builtin_bit_cast(unsigned short, b);
}

// sentinel: encode ws_size into output (fires only if ws too small)
__global__ void fill_out(float* __restrict__ out, float val, int nelem) {
    int i = blockIdx.x * 256 + threadIdx.x;
    if (i < nelem) out[i] = val;
}

// ---------------------------------------------------------------------------
// Tiled transpose + fp32->bf16: in fp32 [R][C] -> out bf16 [C][R].
// (setup-only now: weight mirrors; per-layer x^T is fused into k_embed/k_resid)
// ---------------------------------------------------------------------------
__global__ void t_cvt(const float* __restrict__ in, bf16* __restrict__ out,
                      int R, int C, long inZ, long outZ) {
    __shared__ float tile[64][65];
    in  += inZ  * blockIdx.z;
    out += outZ * blockIdx.z;
    const int tx = threadIdx.x & 63, ty = threadIdx.x >> 6;
    const int r0 = blockIdx.y * 64, c0 = blockIdx.x * 64;
    #pragma unroll
    for (int rr = 0; rr < 16; rr++) {
        int row = ty * 16 + rr;
        tile[row][tx] = in[(size_t)(r0 + row) * C + c0 + tx];
    }
    __syncthreads();
    #pragma unroll
    for (int rr = 0; rr < 16; rr++) {
        int row = ty * 16 + rr;
        out[(size_t)(c0 + row) * R + r0 + tx] = __float2bfloat16(tile[tx][row]);
    }
}

// ---------------------------------------------------------------------------
// Wave-per-row LN family (64 threads/block, 3 elems/lane, butterfly reduce)
// ---------------------------------------------------------------------------
__device__ __forceinline__ void wave_sum2(float& s, float& ss) {
    #pragma unroll
    for (int off = 1; off < 64; off <<= 1) {
        s  += __shfl_xor(s,  off, 64);
        ss += __shfl_xor(ss, off, 64);
    }
}

// writes fp32 x, bf16 xb, AND transposed bf16 xT[d][t]
__global__ void k_embed(const int* __restrict__ idx, const float* __restrict__ emb,
                        const float* __restrict__ pos, float* __restrict__ x,
                        bf16* __restrict__ xb, bf16* __restrict__ xT) {
    int t = blockIdx.x, l = threadIdx.x;
    int tok = idx[t];
    const float* e = emb + tok * D_DIM;
    const float* p = pos + t * D_DIM;
    float v0 = e[l] + p[l], v1 = e[l + 64] + p[l + 64], v2 = e[l + 128] + p[l + 128];
    float s = v0 + v1 + v2, ss = v0 * v0 + v1 * v1 + v2 * v2;
    wave_sum2(s, ss);
    float m = s / D_DIM, r = rsqrtf(ss / D_DIM - m * m + LN_EPS);
    float* xr = x + t * D_DIM;
    bf16*  xo = xb + (size_t)t * D_DIM;
    float o0 = (v0 - m) * r, o1 = (v1 - m) * r, o2 = (v2 - m) * r;
    xr[l] = o0; xr[l + 64] = o1; xr[l + 128] = o2;
    bf16 b0 = __float2bfloat16(o0), b1 = __float2bfloat16(o1), b2 = __float2bfloat16(o2);
    xo[l] = b0; xo[l + 64] = b1; xo[l + 128] = b2;
    bf16* col = xT + t;
    col[(size_t)l * T_SEQ]         = b0;
    col[(size_t)(l + 64) * T_SEQ]  = b1;
    col[(size_t)(l + 128) * T_SEQ] = b2;
}

__global__ void k_ln(float* __restrict__ buf) {
    int l = threadIdx.x;
    float* row = buf + (size_t)blockIdx.x * D_DIM;
    float v0 = row[l], v1 = row[l + 64], v2 = row[l + 128];
    float s = v0 + v1 + v2, ss = v0 * v0 + v1 * v1 + v2 * v2;
    wave_sum2(s, ss);
    float m = s / D_DIM, r = rsqrtf(ss / D_DIM - m * m + LN_EPS);
    row[l] = (v0 - m) * r; row[l + 64] = (v1 - m) * r; row[l + 128] = (v2 - m) * r;
}

// x = LN(x + LN(sum of NSLAB split-K partial slabs)); writes xb + xT too
template <int NSLAB>
__global__ void k_resid(float* __restrict__ x, const float* __restrict__ P,
                        bf16* __restrict__ xb, bf16* __restrict__ xT) {
    int l = threadIdx.x, t = blockIdx.x;
    float y0 = 0.f, y1 = 0.f, y2 = 0.f;
    #pragma unroll
    for (int p = 0; p < NSLAB; p++) {
        const float* r = P + (size_t)p * T_SEQ * D_DIM + (size_t)t * D_DIM;
        y0 += r[l]; y1 += r[l + 64]; y2 += r[l + 128];
    }
    float* xr = x + (size_t)t * D_DIM;
    float s = y0 + y1 + y2, ss = y0 * y0 + y1 * y1 + y2 * y2;
    wave_sum2(s, ss);
    float m1 = s / D_DIM, r1 = rsqrtf(ss / D_DIM - m1 * m1 + LN_EPS);
    float v0 = xr[l] + (y0 - m1) * r1;
    float v1 = xr[l + 64] + (y1 - m1) * r1;
    float v2 = xr[l + 128] + (y2 - m1) * r1;
    s = v0 + v1 + v2; ss = v0 * v0 + v1 * v1 + v2 * v2;
    wave_sum2(s, ss);
    float m2 = s / D_DIM, r2 = rsqrtf(ss / D_DIM - m2 * m2 + LN_EPS);
    float o0 = (v0 - m2) * r2, o1 = (v1 - m2) * r2, o2 = (v2 - m2) * r2;
    xr[l] = o0; xr[l + 64] = o1; xr[l + 128] = o2;
    bf16 b0 = __float2bfloat16(o0), b1 = __float2bfloat16(o1), b2 = __float2bfloat16(o2);
    bf16* xo = xb + (size_t)t * D_DIM;
    xo[l] = b0; xo[l + 64] = b1; xo[l + 128] = b2;
    bf16* col = xT + t;
    col[(size_t)l * T_SEQ]         = b0;
    col[(size_t)(l + 64) * T_SEQ]  = b1;
    col[(size_t)(l + 128) * T_SEQ] = b2;
}

// RoPE cos/sin tables, interleaved bf16 pairs csT[t][p] = (cos, sin)
__global__ void k_tables(ushort2* __restrict__ csT) {
    int gid = blockIdx.x * 256 + threadIdx.x;
    int t = gid / NP2, p = gid % NP2;
    float qf = (float)(2 * p);
    float f = exp2f(qf * (-16.0f / 3072.0f)) * (1.0f / (float)TWO_PI);
    float ph = fmodf((float)t * f, 1.0f) * (float)TWO_PI;
    ushort2 cs;
    cs.x = f2us(cosf(ph));
    cs.y = f2us(sinf(ph));
    csT[gid] = cs;
}

// ---------------------------------------------------------------------------
// scores64: partial scores, split-K=2, FLAT 1-D grid of 1088 with XCD
// pinning: xcd = bid&7 -> (h = xcd>>1, kh = xcd&1), L = bid>>3. Each XCD's
// working set is one (head, K-half) slice of qr = 3 MB -> L2-resident.
//   kh=0: lower-K half -> lower tile (i,j), masked if diag.
//   kh=1 off-diag: upper-K half, swapped operands -> dead upper slot (j,i)
//     in (t,s) orientation. kh=1 diag: masked partial -> dbuf slab.
// ykv dual-A MFMA combines partials in fp32 (no k_comb).
// 64x64 tile, 4 waves x one 32x32x16 MFMA acc, BK=64, double-buffered LDS +
// 2-deep register prefetch, LDS-staged coalesced epilogue.
// ---------------------------------------------------------------------------
__launch_bounds__(256, 4)
__global__ void scores64(const bf16* __restrict__ qr, bf16* __restrict__ sc,
                         bf16* __restrict__ dbuf) {
    const int bid = blockIdx.x;
    const int xcd = bid & 7;
    const int h   = xcd >> 1;
    const int kh  = xcd & 1;
    const int L   = bid >> 3;                      // 0..135, in-order per XCD
    int i = 0;
    while (((i + 1) * (i + 2)) >> 1 <= L) ++i;
    int j = L - ((i * (i + 1)) >> 1);
    const int t0 = i * 64, s0 = j * 64;
    const bool diag = (i == j);

    int arow = t0, brow = s0;
    if (kh == 1 && !diag) { arow = s0; brow = t0; }

    __shared__ short As[2][64][72];
    __shared__ short Bs[2][64][72];

    const int tid = threadIdx.x;
    const int lane = tid & 63, w = tid >> 6;
    const int wtm = (w >> 1) * 32, wtn = (w & 1) * 32;
    const int l31 = lane & 31, lhi = lane >> 5;
    const int r0 = tid >> 2;
    const int kq = (tid & 3) * 16;

    const int kBeg = kh * (N_DIM / 2);
    const bf16* gA = qr + (size_t)(arow + r0) * HN + h * N_DIM + kBeg + kq;
    const bf16* gB = qr + (size_t)(brow + r0) * HN + h * N_DIM + kBeg + kq;

    u16x8 pa0, pa1, pb0, pb1;
    u16x8 qa0, qa1, qb0, qb1;
    auto load0 = [&](int k0) {
        pa0 = *(const u16x8*)(gA + k0);
        pa1 = *(const u16x8*)(gA + k0 + 8);
        pb0 = *(const u16x8*)(gB + k0);
        pb1 = *(const u16x8*)(gB + k0 + 8);
    };
    auto load1 = [&](int k0) {
        qa0 = *(const u16x8*)(gA + k0);
        qa1 = *(const u16x8*)(gA + k0 + 8);
        qb0 = *(const u16x8*)(gB + k0);
        qb1 = *(const u16x8*)(gB + k0 + 8);
    };
    auto dep0 = [&](int buf) {
        *(u16x8*)&As[buf][r0][kq]     = pa0;
        *(u16x8*)&As[buf][r0][kq + 8] = pa1;
        *(u16x8*)&Bs[buf][r0][kq]     = pb0;
        *(u16x8*)&Bs[buf][r0][kq + 8] = pb1;
    };
    auto dep1 = [&](int buf) {
        *(u16x8*)&As[buf][r0][kq]     = qa0;
        *(u16x8*)&As[buf][r0][kq + 8] = qa1;
        *(u16x8*)&Bs[buf][r0][kq]     = qb0;
        *(u16x8*)&Bs[buf][r0][kq + 8] = qb1;
    };

    f32x16 acc;
    #pragma unroll
    for (int r = 0; r < 16; r++) acc[r] = 0.f;

    auto mfma_step = [&](int buf) {
        #pragma unroll
        for (int ks = 0; ks < 4; ks++) {
            s16x8 a = *(const s16x8*)&As[buf][wtm + l31][ks * 16 + lhi * 8];
            s16x8 b = *(const s16x8*)&Bs[buf][wtn + l31][ks * 16 + lhi * 8];
            acc = __builtin_amdgcn_mfma_f32_32x32x16_bf16(a, b, acc, 0, 0, 0);
        }
    };

    const int NIT = (N_DIM / 2) / 64;   // 24 (even)
    load0(0);
    load1(64);
    dep0(0);
    __syncthreads();

    for (int k = 0; k < NIT; k += 2) {
        if (k + 2 < NIT) load0((k + 2) * 64);
        mfma_step(0);
        if (k + 1 < NIT) dep1(1);
        __syncthreads();
        if (k + 1 < NIT) {
            if (k + 3 < NIT) load1((k + 3) * 64);
            mfma_step(1);
            if (k + 2 < NIT) dep0(0);
            __syncthreads();
        }
    }

    __syncthreads();
    short (*S)[72] = (short(*)[72])&As[0][0][0];
    const bool trS = (kh == 1) && !diag;
    #pragma unroll
    for (int r = 0; r < 16; r++) {
        int rr = wtm + (r & 3) + 8 * (r >> 2) + 4 * lhi;
        int cc = wtn + l31;
        float v = acc[r];
        if (diag && cc >= rr) v = 0.f;
        if (trS) S[cc][rr] = (short)f2us(v);
        else     S[rr][cc] = (short)f2us(v);
    }
    __syncthreads();
    if (kh == 1 && diag) {
        bf16* P = dbuf + (size_t)(h * 16 + i) * 4096;
        #pragma unroll
        for (int e = 0; e < 2; e++) {
            int idxe = tid + e * 256;
            int row = idxe >> 3, cg = (idxe & 7) * 8;
            u16x8 v = *(const u16x8*)&S[row][cg];
            *(u16x8*)(P + row * 64 + cg) = v;
        }
    } else {
        bf16* C = sc + (size_t)h * T_SEQ * T_SEQ;
        #pragma unroll
        for (int e = 0; e < 2; e++) {
            int idxe = tid + e * 256;
            int row = idxe >> 3, cg = (idxe & 7) * 8;
            u16x8 v = *(const u16x8*)&S[row][cg];
            *(u16x8*)(C + (size_t)(arow + row) * T_SEQ + brow + cg) = v;
        }
    }
}

// ---------------------------------------------------------------------------
// scores fallback (no qr buffer): 64x64, rope fused into staging.
// ---------------------------------------------------------------------------
__device__ __forceinline__ void stage_rope8(short* dst, const bf16* src,
                                            const ushort2* csP) {
    u16x8 v  = *(const u16x8*)src;
    u16x8 cs = *(const u16x8*)csP;
    u16x8 o;
    #pragma unroll
    for (int i = 0; i < 4; i++) {
        float e  = us2f(v[2 * i]), od = us2f(v[2 * i + 1]);
        float c  = us2f(cs[2 * i]), s = us2f(cs[2 * i + 1]);
        o[2 * i]     = f2us(e * c - od * s);
        o[2 * i + 1] = f2us(od * c + e * s);
    }
    *(u16x8*)dst = o;
}

__launch_bounds__(256)
__global__ void scores_fused(const bf16* __restrict__ xs,
                             const ushort2* __restrict__ csT,
                             bf16* __restrict__ sc) {
    const int h  = blockIdx.z;
    const int s0 = blockIdx.x * 64, t0 = blockIdx.y * 64;
    if (s0 > t0) return;
    __shared__ short As[64][40];
    __shared__ short Bs[64][40];
    const int tid  = threadIdx.x;
    const int srow = tid >> 2, kq = (tid & 3) * 8;
    const int lane = tid & 63, w = tid >> 6, qd = lane >> 4, lc = lane & 15;
    const int tA = t0 + srow, tB = s0 + srow;
    const bf16* gA = xs + (size_t)tA * HN + h * N_DIM + kq;
    const bf16* gB = xs + (size_t)tB * HN + h * N_DIM + kq;
    const ushort2* cA = csT + (size_t)tA * NP2 + (kq >> 1);
    const ushort2* cB = csT + (size_t)tB * NP2 + (kq >> 1);
    f32x4 acc[4] = {{0.f,0.f,0.f,0.f},{0.f,0.f,0.f,0.f},
                    {0.f,0.f,0.f,0.f},{0.f,0.f,0.f,0.f}};
    for (int k0 = 0; k0 < N_DIM; k0 += 32) {
        stage_rope8(&As[srow][kq], gA + k0, cA + (k0 >> 1));
        stage_rope8(&Bs[srow][kq], gB + k0, cB + (k0 >> 1));
        __syncthreads();
        s16x8 a = *(const s16x8*)&As[w * 16 + lc][qd * 8];
        #pragma unroll
        for (int j = 0; j < 4; j++) {
            s16x8 b = *(const s16x8*)&Bs[j * 16 + lc][qd * 8];
            acc[j] = __builtin_amdgcn_mfma_f32_16x16x32_bf16(a, b, acc[j], 0, 0, 0);
        }
        __syncthreads();
    }
    bf16* C = sc + (size_t)h * T_SEQ * T_SEQ;
    const bool diag = (s0 == t0);
    const int tbase = t0 + w * 16 + qd * 4;
    #pragma unroll
    for (int j = 0; j < 4; j++) {
        int s = s0 + j * 16 + lc;
        #pragma unroll
        for (int r = 0; r < 4; r++) {
            int t = tbase + r;
            C[(size_t)t * T_SEQ + s] =
                __float2bfloat16((!diag || s < t) ? acc[j][r] : 0.f);
        }
    }
}

// ---------------------------------------------------------------------------
// dgemm128: 128x128 tile, 4 waves x (64x64 = 2x2 of 32x32x16 MFMA accs),
// K=192 (BK=32), double-buffered LDS + 2-deep register prefetch, LDS-staged
// coalesced epilogue (relu / rope / gate). TA = bf16 or float.
// ---------------------------------------------------------------------------
template <int EPI, bool WQR, typename TA>
__launch_bounds__(256)
__global__ void dgemm128(const TA* __restrict__ A, const bf16* __restrict__ Bt,
                         bf16* __restrict__ xs, bf16* __restrict__ qr,
                         const ushort2* __restrict__ csT) {
    __shared__ __align__(16) short pool[2 * 2 * 128 * 40];   // 40 KB
    short (*As)[128][40] = (short(*)[128][40])pool;
    short (*Bs)[128][40] = (short(*)[128][40])(pool + 2 * 128 * 40);

    const int tid = threadIdx.x;
    const int lane = tid & 63, w = tid >> 6;
    const int l31 = lane & 31, lhi = lane >> 5;
    const int wtm = (w >> 1) * 64, wtn = (w & 1) * 64;
    const int n0 = blockIdx.x * 128, m0 = blockIdx.y * 128;
    if constexpr (EPI == 2) A += (size_t)(n0 / N_DIM) * T_SEQ * D_DIM;

    const int r0 = tid >> 2, r1 = r0 + 64;
    const int kq = (tid & 3) * 8;

    const TA*   gA = A  + kq;
    const bf16* gB = Bt + kq;

    float4 fa00, fa01, fa02, fa03, fa10, fa11, fa12, fa13;
    u16x8 ba00, ba01, ba10, ba11;
    u16x8 pb00, pb01, pb10, pb11;
    auto load0 = [&](int k0) {
        if constexpr (__is_same(TA, float)) {
            const TA* a0 = gA + (size_t)(m0 + r0) * D_DIM + k0;
            const TA* a1 = gA + (size_t)(m0 + r1) * D_DIM + k0;
            fa00 = *(const float4*)a0; fa01 = *(const float4*)(a0 + 4);
            fa02 = *(const float4*)a1; fa03 = *(const float4*)(a1 + 4);
        } else {
            ba00 = *(const u16x8*)(gA + (size_t)(m0 + r0) * D_DIM + k0);
            ba01 = *(const u16x8*)(gA + (size_t)(m0 + r1) * D_DIM + k0);
        }
        pb00 = *(const u16x8*)(gB + (size_t)(n0 + r0) * D_DIM + k0);
        pb01 = *(const u16x8*)(gB + (size_t)(n0 + r1) * D_DIM + k0);
    };
    auto load1 = [&](int k0) {
        if constexpr (__is_same(TA, float)) {
            const TA* a0 = gA + (size_t)(m0 + r0) * D_DIM + k0;
            const TA* a1 = gA + (size_t)(m0 + r1) * D_DIM + k0;
            fa10 = *(const float4*)a0; fa11 = *(const float4*)(a0 + 4);
            fa12 = *(const float4*)a1; fa13 = *(const float4*)(a1 + 4);
        } else {
            ba10 = *(const u16x8*)(gA + (size_t)(m0 + r0) * D_DIM + k0);
            ba11 = *(const u16x8*)(gA + (size_t)(m0 + r1) * D_DIM + k0);
        }
        pb10 = *(const u16x8*)(gB + (size_t)(n0 + r0) * D_DIM + k0);
        pb11 = *(const u16x8*)(gB + (size_t)(n0 + r1) * D_DIM + k0);
    };
    auto dep0 = [&](int buf) {
        if constexpr (__is_same(TA, float)) {
            u16x8 o0, o1;
            o0[0] = f2us(fa00.x); o0[1] = f2us(fa00.y); o0[2] = f2us(fa00.z); o0[3] = f2us(fa00.w);
            o0[4] = f2us(fa01.x); o0[5] = f2us(fa01.y); o0[6] = f2us(fa01.z); o0[7] = f2us(fa01.w);
            o1[0] = f2us(fa02.x); o1[1] = f2us(fa02.y); o1[2] = f2us(fa02.z); o1[3] = f2us(fa02.w);
            o1[4] = f2us(fa03.x); o1[5] = f2us(fa03.y); o1[6] = f2us(fa03.z); o1[7] = f2us(fa03.w);
            *(u16x8*)&As[buf][r0][kq] = o0;
            *(u16x8*)&As[buf][r1][kq] = o1;
        } else {
            *(u16x8*)&As[buf][r0][kq] = ba00;
            *(u16x8*)&As[buf][r1][kq] = ba01;
        }
        *(u16x8*)&Bs[buf][r0][kq] = pb00;
        *(u16x8*)&Bs[buf][r1][kq] = pb01;
    };
    auto dep1 = [&](int buf) {
        if constexpr (__is_same(TA, float)) {
            u16x8 o0, o1;
            o0[0] = f2us(fa10.x); o0[1] = f2us(fa10.y); o0[2] = f2us(fa10.z); o0[3] = f2us(fa10.w);
            o0[4] = f2us(fa11.x); o0[5] = f2us(fa11.y); o0[6] = f2us(fa11.z); o0[7] = f2us(fa11.w);
            o1[0] = f2us(fa12.x); o1[1] = f2us(fa12.y); o1[2] = f2us(fa12.z); o1[3] = f2us(fa12.w);
            o1[4] = f2us(fa13.x); o1[5] = f2us(fa13.y); o1[6] = f2us(fa13.z); o1[7] = f2us(fa13.w);
            *(u16x8*)&As[buf][r0][kq] = o0;
            *(u16x8*)&As[buf][r1][kq] = o1;
        } else {
            *(u16x8*)&As[buf][r0][kq] = ba10;
            *(u16x8*)&As[buf][r1][kq] = ba11;
        }
        *(u16x8*)&Bs[buf][r0][kq] = pb10;
        *(u16x8*)&Bs[buf][r1][kq] = pb11;
    };

    f32x16 acc00, acc01, acc10, acc11;
    #pragma unroll
    for (int r = 0; r < 16; r++) { acc00[r] = 0.f; acc01[r] = 0.f; acc10[r] = 0.f; acc11[r] = 0.f; }

    auto mfma_step = [&](int buf) {
        #pragma unroll
        for (int ks = 0; ks < 2; ks++) {
            s16x8 a0 = *(const s16x8*)&As[buf][wtm + l31][ks * 16 + lhi * 8];
            s16x8 a1 = *(const s16x8*)&As[buf][wtm + 32 + l31][ks * 16 + lhi * 8];
            s16x8 b0 = *(const s16x8*)&Bs[buf][wtn + l31][ks * 16 + lhi * 8];
            s16x8 b1 = *(const s16x8*)&Bs[buf][wtn + 32 + l31][ks * 16 + lhi * 8];
            acc00 = __builtin_amdgcn_mfma_f32_32x32x16_bf16(a0, b0, acc00, 0, 0, 0);
            acc01 = __builtin_amdgcn_mfma_f32_32x32x16_bf16(a0, b1, acc01, 0, 0, 0);
            acc10 = __builtin_amdgcn_mfma_f32_32x32x16_bf16(a1, b0, acc10, 0, 0, 0);
            acc11 = __builtin_amdgcn_mfma_f32_32x32x16_bf16(a1, b1, acc11, 0, 0, 0);
        }
    };

    const int NIT = D_DIM / 32;   // 6 (even)
    load0(0);
    load1(32);
    dep0(0);
    __syncthreads();
    for (int k = 0; k < NIT; k += 2) {
        if (k + 2 < NIT) load0((k + 2) * 32);
        mfma_step(0);
        if (k + 1 < NIT) dep1(1);
        __syncthreads();
        if (k + 1 < NIT) {
            if (k + 3 < NIT) load1((k + 3) * 32);
            mfma_step(1);
            if (k + 2 < NIT) dep0(0);
            __syncthreads();
        }
    }

    // -------- LDS-staged epilogue --------
    short (*S)[136] = (short(*)[136])pool; // 128 x 136 shorts = 34.8 KB <= 40 KB
    #pragma unroll
    for (int r = 0; r < 16; r++) {
        int rb = (r & 3) + 8 * (r >> 2) + 4 * lhi;
        S[wtm + rb     ][wtn + l31     ] = (short)f2us(fmaxf(acc00[r], 0.f));
        S[wtm + rb     ][wtn + 32 + l31] = (short)f2us(fmaxf(acc01[r], 0.f));
        S[wtm + 32 + rb][wtn + l31     ] = (short)f2us(fmaxf(acc10[r], 0.f));
        S[wtm + 32 + rb][wtn + 32 + l31] = (short)f2us(fmaxf(acc11[r], 0.f));
    }
    __syncthreads();
    #pragma unroll
    for (int e = 0; e < 8; e++) {
        int idxe = tid + e * 256;
        int row = idxe >> 4, cg = idxe & 15;
        u16x8 v = *(const u16x8*)&S[row][cg * 8];
        int t = m0 + row, ngg = n0 + cg * 8;
        size_t ci = (size_t)t * HN + ngg;
        if constexpr (EPI == 1) {
            *(u16x8*)(xs + ci) = v;
            if constexpr (WQR) {
                int p0 = (ngg % N_DIM) >> 1;
                u16x8 cs8 = *(const u16x8*)&csT[(size_t)t * NP2 + p0];
                u16x8 o;
                #pragma unroll
                for (int q = 0; q < 4; q++) {
                    float ev = us2f(v[2 * q]), ov = us2f(v[2 * q + 1]);
                    float c = us2f(cs8[2 * q]), s = us2f(cs8[2 * q + 1]);
                    o[2 * q]     = f2us(ev * c - ov * s);
                    o[2 * q + 1] = f2us(ov * c + ev * s);
                }
                *(u16x8*)(qr + ci) = o;
            }
        } else {
            u16x8 g = *(const u16x8*)(xs + ci);
            u16x8 o;
            #pragma unroll
            for (int q = 0; q < 8; q++) o[q] = f2us(us2f(g[q]) * us2f(v[q]));
            *(u16x8*)(xs + ci) = o;
        }
    }
}

// ---------------------------------------------------------------------------
// gate_ymlp: fused  ymlp_slab = (xs ⊙ relu(LN(ykv0+ykv1) @ decY)) @ enc.
// Now ALSO fuses the ykv slab-combine + LN + bf16 cast (was k_ln2b): each
// block loads the two fp32 ykv slabs for its 64 rows, sums + LNs in-register
// (4-lane shfl reduce, static indexing), writes bf16 into A1s.
// FLAT grid of 256 with XCD pinning: s = (bid&7) + 8*(bid>>7),
// tb = (bid>>3)&15 — each XCD owns 2 n-segments (L2-resident).
// ---------------------------------------------------------------------------
__launch_bounds__(256, 2)
__global__ void gate_ymlp(const float* __restrict__ ykv0, const float* __restrict__ ykv1,
                          const bf16* __restrict__ wY,
                          const bf16* __restrict__ xs, const bf16* __restrict__ wE,
                          float* __restrict__ P) {
    const int bid = blockIdx.x;
    const int s   = (bid & 7) + ((bid >> 7) << 3);   // 0..15, pinned by XCD
    const int tb  = (bid >> 3) & 15;                 // 0..15
    const int t0  = tb * 64;
    const int h   = s >> 2;               // 4 segments of 768 per head
    const int ng0 = s * 768;              // global n base of this slab
    const int nh0 = (s & 3) * 768;        // within-head n base

    __shared__ __align__(16) short A1s[64][200];   // LN(ykv) tile (25.6 KB)
    __shared__ __align__(16) short Bsh[192][72];   // B2 view      (27.6 KB)
    __shared__ __align__(16) short xyA[64][72];    // xy chunk     ( 9.2 KB)
    short (*B1)[200] = (short(*)[200])&Bsh[0][0];  // B1 overlays B2 (12800<=13824)

    const int tid = threadIdx.x;
    const int lane = tid & 63, w = tid >> 6;
    const int l31 = lane & 31, lhi = lane >> 5;
    const int wm  = (w >> 1) * 32;        // t-offset of wave
    const int wn1 = (w & 1) * 32;         // n-offset (stage1)
    const int wn2 = (w & 1) * 96;         // d-offset (stage2)

    // ---- fused slab-combine + LN + bf16 -> A1s (was k_ln2b) ----
    // 4 threads per row: row = tid>>2 (0..63), quarter q = tid&3 (48 elems).
    // Lanes 4k..4k+3 are the same row -> shfl_xor(1),(2) reduces the row.
    {
        const int row = tid >> 2, q = tid & 3;
        size_t off = ((size_t)h * T_SEQ + t0 + row) * D_DIM + q * 48;
        const float* p0 = ykv0 + off;
        const float* p1 = ykv1 + off;
        float v[48];
        float sm = 0.f, ssq = 0.f;
        #pragma unroll
        for (int e = 0; e < 12; e++) {
            float4 a = *(const float4*)(p0 + e * 4);
            float4 b = *(const float4*)(p1 + e * 4);
            float c0 = a.x + b.x, c1 = a.y + b.y, c2 = a.z + b.z, c3 = a.w + b.w;
            v[e * 4 + 0] = c0; v[e * 4 + 1] = c1; v[e * 4 + 2] = c2; v[e * 4 + 3] = c3;
            sm  += c0 + c1 + c2 + c3;
            ssq += c0 * c0 + c1 * c1 + c2 * c2 + c3 * c3;
        }
        sm  += __shfl_xor(sm, 1, 64);  ssq += __shfl_xor(ssq, 1, 64);
        sm  += __shfl_xor(sm, 2, 64);  ssq += __shfl_xor(ssq, 2, 64);
        float m = sm / D_DIM, r = rsqrtf(ssq / D_DIM - m * m + LN_EPS);
        #pragma unroll
        for (int e = 0; e < 6; e++) {
            u16x8 o;
            #pragma unroll
            for (int k2 = 0; k2 < 8; k2++) o[k2] = f2us((v[e * 8 + k2] - m) * r);
            *(u16x8*)&A1s[row][q * 48 + e * 8] = o;
        }
    }

    f32x16 oc0, oc1, oc2;
    #pragma unroll
    for (int r = 0; r < 16; r++) { oc0[r] = 0.f; oc1[r] = 0.f; oc2[r] = 0.f; }

    __syncthreads();

    for (int c = 0; c < 12; c++) {
        const int nc = c * 64;
        // stage B1 = wY[h][nh0+nc+r][0..192]
        {
            const bf16* src = wY + ((size_t)h * N_DIM + nh0 + nc + (tid >> 2)) * D_DIM
                            + (tid & 3) * 48;
            #pragma unroll
            for (int j = 0; j < 6; j++) {
                u16x8 v = *(const u16x8*)(src + j * 8);
                *(u16x8*)&B1[tid >> 2][(tid & 3) * 48 + j * 8] = v;
            }
        }
        __syncthreads();
        // stage1: ys(64x64) over K=192
        f32x16 ys;
        #pragma unroll
        for (int r = 0; r < 16; r++) ys[r] = 0.f;
        #pragma unroll
        for (int ks = 0; ks < 12; ks++) {
            s16x8 a = *(const s16x8*)&A1s[wm + l31][ks * 16 + lhi * 8];
            s16x8 b = *(const s16x8*)&B1[wn1 + l31][ks * 16 + lhi * 8];
            ys = __builtin_amdgcn_mfma_f32_32x32x16_bf16(a, b, ys, 0, 0, 0);
        }
        __syncthreads();                      // all waves done with B1 / prev xyA
        // scatter relu(ys) -> xyA (bf16)
        #pragma unroll
        for (int r = 0; r < 16; r++) {
            int rr = wm + (r & 3) + 8 * (r >> 2) + 4 * lhi;
            xyA[rr][wn1 + l31] = (short)f2us(fmaxf(ys[r], 0.f));
        }
        __syncthreads();
        // RMW with xs chunk (coalesced u16x8)
        {
            int row = tid >> 2, c0l = (tid & 3) * 16;
            const bf16* sx = xs + (size_t)(t0 + row) * HN + ng0 + nc + c0l;
            #pragma unroll
            for (int e = 0; e < 2; e++) {
                u16x8 g = *(const u16x8*)(sx + e * 8);
                u16x8 y = *(const u16x8*)&xyA[row][c0l + e * 8];
                u16x8 o;
                #pragma unroll
                for (int q = 0; q < 8; q++) o[q] = f2us(us2f(g[q]) * us2f(y[q]));
                *(u16x8*)&xyA[row][c0l + e * 8] = o;
            }
        }
        // stage B2 = wE[d][ng0+nc .. +64]   (overwrites B1 — stage1 done)
        {
            #pragma unroll
            for (int j = 0; j < 3; j++) {
                int d  = (tid >> 2) * 3 + j;          // 0..191
                int cc = (tid & 3) * 16;
                const bf16* src = wE + (size_t)d * HN + ng0 + nc + cc;
                u16x8 v0 = *(const u16x8*)src;
                u16x8 v1 = *(const u16x8*)(src + 8);
                *(u16x8*)&Bsh[d][cc]     = v0;
                *(u16x8*)&Bsh[d][cc + 8] = v1;
            }
        }
        __syncthreads();
        // stage2: out += xyA(64x64) @ wE-chunk^T(192x64), K=64
        #pragma unroll
        for (int ks = 0; ks < 4; ks++) {
            s16x8 a  = *(const s16x8*)&xyA[wm + l31][ks * 16 + lhi * 8];
            s16x8 b0 = *(const s16x8*)&Bsh[wn2 + l31     ][ks * 16 + lhi * 8];
            s16x8 b1 = *(const s16x8*)&Bsh[wn2 + 32 + l31][ks * 16 + lhi * 8];
            s16x8 b2 = *(const s16x8*)&Bsh[wn2 + 64 + l31][ks * 16 + lhi * 8];
            oc0 = __builtin_amdgcn_mfma_f32_32x32x16_bf16(a, b0, oc0, 0, 0, 0);
            oc1 = __builtin_amdgcn_mfma_f32_32x32x16_bf16(a, b1, oc1, 0, 0, 0);
            oc2 = __builtin_amdgcn_mfma_f32_32x32x16_bf16(a, b2, oc2, 0, 0, 0);
        }
        __syncthreads();                      // before next chunk's B1/xyA writes
    }

    // write slab P[s][t][d]
    float* O = P + (size_t)s * T_SEQ * D_DIM;
    #pragma unroll
    for (int r = 0; r < 16; r++) {
        int rt = t0 + wm + (r & 3) + 8 * (r >> 2) + 4 * lhi;
        O[(size_t)rt * D_DIM + wn2 +      l31] = oc0[r];
        O[(size_t)rt * D_DIM + wn2 + 32 + l31] = oc1[r];
        O[(size_t)rt * D_DIM + wn2 + 64 + l31] = oc2[r];
    }
}

// ---------------------------------------------------------------------------
// mfma_gemm (64x64): MODE 0 = plain, 1 = causal split-K=2 WITH dual-A partial
// combine AND flat-grid XCD pinning (bid&7 = z = head*2+seg), 2 = split-K
// slabs over z (fallback ymlp), 3 = causal full (fallback). 32x32x16 MFMA,
// BK=64, double-buffered LDS + 2-deep prefetch.
// ---------------------------------------------------------------------------
template <typename TA, int MODE>
__launch_bounds__(256)
__global__ void mfma_gemm(const TA* __restrict__ A, const bf16* __restrict__ Bt,
                          float* __restrict__ C, const bf16* __restrict__ aux,
                          int K, int kSeg, int lda, int ldb, int ldc,
                          long aZ, long bZ, long cZ) {
    constexpr bool DUAL = (MODE == 1);
    constexpr int TILES = DUAL ? 6 : 4;
    __shared__ __align__(16) short pool[TILES * 64 * 72];
    short (*As)[64][72] = (short(*)[64][72])pool;
    short (*Bs)[64][72] = (short(*)[64][72])(pool + 2 * 64 * 72);
    short (*Ms)[64][72] = (short(*)[64][72])(pool + 4 * 64 * 72);

    int bx, by, z;
    if constexpr (MODE == 1) {
        // flat grid 384: xcd = bid&7 = z (head*2+seg); rest enumerates (x,y)
        const int bid  = blockIdx.x;
        z = bid & 7;
        const int rest = bid >> 3;      // 0..47
        bx = rest % 3;
        by = rest / 3;
    } else {
        bx = blockIdx.x; by = blockIdx.y; z = blockIdx.z;
    }

    const int tid = threadIdx.x;
    const int n0 = bx * 64, m0 = by * 64;
    const int srow = tid >> 2, sk = (tid & 3) * 16;
    const int lane = tid & 63, w = tid >> 6;
    const int l31 = lane & 31, lhi = lane >> 5;
    const int wm = (w >> 1) * 32, wn = (w & 1) * 32;

    int kBeg, kEnd, zh = 0;
    if constexpr (MODE == 1) {
        zh = z >> 1;
        const int seg = z & 1;
        A += aZ * zh;
        C += cZ * zh + bZ * seg;
        const int kc = (m0 + 64 < K) ? m0 + 64 : K;
        const int half0 = ((kc + 127) >> 7) << 6;   // ceil(kc/128)*64
        kBeg = seg ? half0 : 0;
        kEnd = seg ? kc : half0;
    } else if constexpr (MODE == 2) {
        A += aZ * z; Bt += bZ * z; C += cZ * z;
        kBeg = z * kSeg; kEnd = kBeg + kSeg;
    } else if constexpr (MODE == 3) {
        A += aZ * z; Bt += bZ * z; C += cZ * z;
        kBeg = 0; kEnd = (m0 + 64 < K) ? m0 + 64 : K;
    } else {
        A += aZ * z; Bt += bZ * z; C += cZ * z;
        kBeg = 0; kEnd = K;
    }

    const TA*   ga = A  + (size_t)(m0 + srow) * lda + sk;
    const bf16* gb = Bt + (size_t)(n0 + srow) * ldb + sk;

    auto msrc = [&](int k0) -> const bf16* {
        if (k0 == m0)
            return aux + (size_t)(zh * 16 + (m0 >> 6)) * 4096
                       + (size_t)srow * 64 + sk;
        return (const bf16*)A + (size_t)(k0 + srow) * lda + m0 + sk;
    };

    float4 f00, f01, f02, f03, f10, f11, f12, f13;
    u16x8 pa00, pa01, pa10, pa11, pb00, pb01, pb10, pb11;
    u16x8 pm00, pm01, pm10, pm11;
    auto load0 = [&](int k0) {
        if constexpr (__is_same(TA, float)) {
            f00 = *(const float4*)(ga + k0);
            f01 = *(const float4*)(ga + k0 + 4);
            f02 = *(const float4*)(ga + k0 + 8);
            f03 = *(const float4*)(ga + k0 + 12);
        } else {
            pa00 = *(const u16x8*)(ga + k0);
            pa01 = *(const u16x8*)(ga + k0 + 8);
        }
        pb00 = *(const u16x8*)(gb + k0);
        pb01 = *(const u16x8*)(gb + k0 + 8);
        if constexpr (DUAL) {
            const bf16* ms = msrc(k0);
            pm00 = *(const u16x8*)ms;
            pm01 = *(const u16x8*)(ms + 8);
        }
    };
    auto load1 = [&](int k0) {
        if constexpr (__is_same(TA, float)) {
            f10 = *(const float4*)(ga + k0);
            f11 = *(const float4*)(ga + k0 + 4);
            f12 = *(const float4*)(ga + k0 + 8);
            f13 = *(const float4*)(ga + k0 + 12);
        } else {
            pa10 = *(const u16x8*)(ga + k0);
            pa11 = *(const u16x8*)(ga + k0 + 8);
        }
        pb10 = *(const u16x8*)(gb + k0);
        pb11 = *(const u16x8*)(gb + k0 + 8);
        if constexpr (DUAL) {
            const bf16* ms = msrc(k0);
            pm10 = *(const u16x8*)ms;
            pm11 = *(const u16x8*)(ms + 8);
        }
    };
    auto dep0 = [&](int buf) {
        if constexpr (__is_same(TA, float)) {
            u16x8 o0, o1;
            o0[0] = f2us(f00.x); o0[1] = f2us(f00.y); o0[2] = f2us(f00.z); o0[3] = f2us(f00.w);
            o0[4] = f2us(f01.x); o0[5] = f2us(f01.y); o0[6] = f2us(f01.z); o0[7] = f2us(f01.w);
            o1[0] = f2us(f02.x); o1[1] = f2us(f02.y); o1[2] = f2us(f02.z); o1[3] = f2us(f02.w);
            o1[4] = f2us(f03.x); o1[5] = f2us(f03.y); o1[6] = f2us(f03.z); o1[7] = f2us(f03.w);
            *(u16x8*)&As[buf][srow][sk]     = o0;
            *(u16x8*)&As[buf][srow][sk + 8] = o1;
        } else {
            *(u16x8*)&As[buf][srow][sk]     = pa00;
            *(u16x8*)&As[buf][srow][sk + 8] = pa01;
        }
        *(u16x8*)&Bs[buf][srow][sk]     = pb00;
        *(u16x8*)&Bs[buf][srow][sk + 8] = pb01;
        if constexpr (DUAL) {
            *(u16x8*)&Ms[buf][srow][sk]     = pm00;
            *(u16x8*)&Ms[buf][srow][sk + 8] = pm01;
        }
    };
    auto dep1 = [&](int buf) {
        if constexpr (__is_same(TA, float)) {
            u16x8 o0, o1;
            o0[0] = f2us(f10.x); o0[1] = f2us(f10.y); o0[2] = f2us(f10.z); o0[3] = f2us(f10.w);
            o0[4] = f2us(f11.x); o0[5] = f2us(f11.y); o0[6] = f2us(f11.z); o0[7] = f2us(f11.w);
            o1[0] = f2us(f12.x); o1[1] = f2us(f12.y); o1[2] = f2us(f12.z); o1[3] = f2us(f12.w);
            o1[4] = f2us(f13.x); o1[5] = f2us(f13.y); o1[6] = f2us(f13.z); o1[7] = f2us(f13.w);
            *(u16x8*)&As[buf][srow][sk]     = o0;
            *(u16x8*)&As[buf][srow][sk + 8] = o1;
        } else {
            *(u16x8*)&As[buf][srow][sk]     = pa10;
            *(u16x8*)&As[buf][srow][sk + 8] = pa11;
        }
        *(u16x8*)&Bs[buf][srow][sk]     = pb10;
        *(u16x8*)&Bs[buf][srow][sk + 8] = pb11;
        if constexpr (DUAL) {
            *(u16x8*)&Ms[buf][srow][sk]     = pm10;
            *(u16x8*)&Ms[buf][srow][sk + 8] = pm11;
        }
    };

    f32x16 acc;
    #pragma unroll
    for (int r = 0; r < 16; r++) acc[r] = 0.f;

    auto mfma_step = [&](int buf) {
        #pragma unroll
        for (int ks = 0; ks < 4; ks++) {
            s16x8 a = *(const s16x8*)&As[buf][wm + l31][ks * 16 + lhi * 8];
            s16x8 b = *(const s16x8*)&Bs[buf][wn + l31][ks * 16 + lhi * 8];
            acc = __builtin_amdgcn_mfma_f32_32x32x16_bf16(a, b, acc, 0, 0, 0);
            if constexpr (DUAL) {
                s16x8 m2 = *(const s16x8*)&Ms[buf][wm + l31][ks * 16 + lhi * 8];
                acc = __builtin_amdgcn_mfma_f32_32x32x16_bf16(m2, b, acc, 0, 0, 0);
            }
        }
    };

    const int NIT = (kEnd - kBeg) >> 6;
    load0(kBeg);
    load1(kBeg + 64);
    dep0(0);
    __syncthreads();

    for (int k = 0; k < NIT; k += 2) {
        if (k + 2 < NIT) load0(kBeg + (k + 2) * 64);
        mfma_step(0);
        if (k + 1 < NIT) dep1(1);
        __syncthreads();
        if (k + 1 < NIT) {
            if (k + 3 < NIT) load1(kBeg + (k + 3) * 64);
            mfma_step(1);
            if (k + 2 < NIT) dep0(0);
            __syncthreads();
        }
    }

    #pragma unroll
    for (int r = 0; r < 16; r++) {
        int row = m0 + wm + (r & 3) + 8 * (r >> 2) + 4 * lhi;
        int col = n0 + wn + l31;
        C[(size_t)row * ldc + col] = acc[r];
    }
}

extern "C" void kernel_launch(void* const* d_in, const int* in_sizes, int n_in,
                              void* d_out, int out_size, void* d_ws, size_t ws_size,
                              hipStream_t stream) {
    const int*   idx   = (const int*)  d_in[0];
    const float* dec_x = (const float*)d_in[1];   // (NH, D, N)
    const float* dec_y = (const float*)d_in[2];   // (NH, D, N)
    const float* enc   = (const float*)d_in[3];   // (NH*N, D)
    const float* emb   = (const float*)d_in[4];   // (VOCAB, D)
    const float* pose  = (const float*)d_in[5];   // (BLOCK, D)
    const float* lmh   = (const float*)d_in[6];   // (D, VOCAB)
    float* out = (float*)d_out;                   // (T, VOCAB) fp32

    // workspace layout — identical to passing r11 (ws >= 84,377,600 proven)
    char* wp = (char*)d_ws;
    float*   x    = (float*)wp;              wp += (size_t)T_SEQ * D_DIM * 4;
    bf16*    xs   = (bf16*)wp;               wp += (size_t)T_SEQ * HN * 2;
    ushort2* csT  = (ushort2*)wp;            wp += (size_t)T_SEQ * NP2 * 4;
    bf16*    sc   = (bf16*)wp;               wp += (size_t)NHEAD * T_SEQ * T_SEQ * 2;
    float*   ykv  = (float*)wp;              wp += (size_t)NHEAD * T_SEQ * D_DIM * 4;
    float*   ymlp = (float*)wp;              wp += (size_t)T_SEQ * D_DIM * 4;   // dbuf home
    bf16*    xT   = (bf16*)wp;               wp += (size_t)D_DIM * T_SEQ * 2;
    bf16*    wX   = (bf16*)wp;               wp += (size_t)NHEAD * N_DIM * D_DIM * 2;
    bf16*    wY   = (bf16*)wp;               wp += (size_t)NHEAD * N_DIM * D_DIM * 2;
    bf16*    wE   = (bf16*)wp;               wp += (size_t)D_DIM * HN * 2;
    bf16*    wL   = (bf16*)wp;               wp += (size_t)VOCABSZ * D_DIM * 2;
    const size_t BASE_NEED = (size_t)(wp - (char*)d_ws);
    bf16*    qr   = (bf16*)wp;
    const size_t FULL_NEED = BASE_NEED + (size_t)T_SEQ * HN * 2;
    bf16*  dbuf  = (bf16*)ymlp;    // 512 KB diag partials on idle ymlp keeper

    if (ws_size < BASE_NEED) {
        fill_out<<<(out_size + 255) / 256, 256, 0, stream>>>(out, (float)ws_size, out_size);
        return;
    }
    const bool USE_QR = (ws_size >= FULL_NEED);

    // bf16 A-operand homes (main path): xb on dead sc head; ymlpP16 on qr
    // head [0..12.6MB); ykv slab1 fp32 on qr+12.6MB (old ykvb home — gate
    // reads it while writing ymlpP16, regions disjoint).
    // Fallback: xb on ymlp keeper; ymlpP8 on sc.
    bf16*  xb_main = (bf16*)sc;
    bf16*  xb_fb   = (bf16*)ymlp;
    float* ymlpP16 = (float*)qr;                               // 16 slabs
    float* ykvP1   = (float*)((char*)qr + (size_t)16 * T_SEQ * D_DIM * 4);
    float* ymlpP8  = (float*)sc;                               // fallback slabs

    bf16* xb = USE_QR ? xb_main : xb_fb;

    // weight mirrors (bf16, [n][k])
    t_cvt<<<dim3(48, 3, 4), 256, 0, stream>>>(dec_x, wX, D_DIM, N_DIM,
                                              (long)D_DIM * N_DIM, (long)N_DIM * D_DIM);
    t_cvt<<<dim3(48, 3, 4), 256, 0, stream>>>(dec_y, wY, D_DIM, N_DIM,
                                              (long)D_DIM * N_DIM, (long)N_DIM * D_DIM);
    t_cvt<<<dim3(3, 192, 1), 256, 0, stream>>>(enc, wE, HN, D_DIM, 0L, 0L);
    t_cvt<<<dim3(4, 3, 1), 256, 0, stream>>>(lmh, wL, D_DIM, VOCABSZ, 0L, 0L);

    k_tables<<<(T_SEQ * NP2) / 256, 256, 0, stream>>>(csT);
    // k_embed writes x, xb AND xT (per-layer t_cvt eliminated)
    k_embed<<<T_SEQ, 64, 0, stream>>>(idx, emb, pose, x, xb, xT);

    for (int l = 0; l < NLAYER; ++l) {
        if (USE_QR) {
            // xs = relu(x @ dec_x), qr = rope(xs)
            dgemm128<1, true, bf16><<<dim3(96, 8), 256, 0, stream>>>(xb, wX, xs, qr, csT);
            // flat 1088, XCD-pinned (h,kh)
            scores64<<<dim3(1088), 256, 0, stream>>>(qr, sc, dbuf);
            // ykv = sc @ x  (causal, split-K=2, dual-A partial combine;
            // slab1 fp32 at qr+12.6MB; flat 384, XCD-pinned (h,seg))
            long segZ = (long)(ykvP1 - ykv);
            mfma_gemm<bf16, 1><<<dim3(384), 256, 0, stream>>>(
                sc, xT, ykv, dbuf, T_SEQ, 0, T_SEQ, T_SEQ, D_DIM,
                (long)T_SEQ * T_SEQ, segZ, (long)T_SEQ * D_DIM);
            // fused: ymlp slabs = (xs ⊙ relu(LN(slab0+slab1) @ decY)) @ enc
            // (k_ln2b folded into gate prologue); flat 256, XCD-pinned
            gate_ymlp<<<dim3(256), 256, 0, stream>>>(ykv, ykvP1, wY, xs, wE, ymlpP16);
            // x = LN(x + LN(sum partials)); xb + xT refreshed
            k_resid<16><<<T_SEQ, 64, 0, stream>>>(x, ymlpP16, xb, xT);
        } else {
            dgemm128<1, false, bf16><<<dim3(96, 8), 256, 0, stream>>>(xb, wX, xs, qr, csT);
            scores_fused<<<dim3(16, 16, NHEAD), 256, 0, stream>>>(xs, csT, sc);
            mfma_gemm<bf16, 3><<<dim3(3, 16, NHEAD), 256, 0, stream>>>(
                sc, xT, ykv, nullptr, T_SEQ, 0, T_SEQ, T_SEQ, D_DIM,
                (long)T_SEQ * T_SEQ, 0L, (long)T_SEQ * D_DIM);
            k_ln<<<NHEAD * T_SEQ, 64, 0, stream>>>(ykv);
            dgemm128<2, false, float><<<dim3(96, 8), 256, 0, stream>>>(
                ykv, wY, xs, nullptr, nullptr);
            mfma_gemm<bf16, 2><<<dim3(3, 16, 8), 256, 0, stream>>>(
                xs, wE, ymlpP8, nullptr, HN, HN / 8, HN, HN, D_DIM,
                0L, 0L, (long)T_SEQ * D_DIM);
            k_resid<8><<<T_SEQ, 64, 0, stream>>>(x, ymlpP8, xb, xT);
        }
    }

    // logits = x @ lm_head
    mfma_gemm<float, 0><<<dim3(4, 16, 1), 256, 0, stream>>>(
        x, wL, out, nullptr, D_DIM, 0, D_DIM, D_DIM, VOCABSZ, 0L, 0L, 0L);
}

// Round 13
// 445.942 us; speedup vs baseline: 1.1643x; 1.0459x over previous
//
#include <hip/hip_runtime.h>
#include <hip/hip_bf16.h>

using bf16 = __hip_bfloat16;

#define D_DIM   192
#define N_DIM   3072
#define NHEAD   4
#define T_SEQ   1024
#define HN      12288      // NHEAD * N_DIM
#define NP2     1536       // N_DIM/2
#define VOCABSZ 256
#define NLAYER  4
#define LN_EPS  1e-5f
#define TWO_PI  6.2831853071795864f

typedef __attribute__((ext_vector_type(8)))  short          s16x8;
typedef __attribute__((ext_vector_type(8)))  unsigned short u16x8;
typedef __attribute__((ext_vector_type(4)))  float          f32x4;
typedef __attribute__((ext_vector_type(16))) float          f32x16;

__device__ __forceinline__ float b2f(bf16 v) { return __bfloat162float(v); }
__device__ __forceinline__ float us2f(unsigned short u) {
    unsigned int x = ((unsigned int)u) << 16;
    return __builtin_bit_cast(float, x);
}
__device__ __forceinline__ unsigned short f2us(float f) {
    bf16 b = __float2bfloat16(f);
    return __builtin_bit_cast(unsigned short, b);
}

// sentinel: encode ws_size into output (fires only if ws too small)
__global__ void fill_out(float* __restrict__ out, float val, int nelem) {
    int i = blockIdx.x * 256 + threadIdx.x;
    if (i < nelem) out[i] = val;
}

// ---------------------------------------------------------------------------
// Tiled transpose + fp32->bf16: in fp32 [R][C] -> out bf16 [C][R].
// (setup-only: weight mirrors; per-layer x^T is fused into k_embed/k_resid)
// ---------------------------------------------------------------------------
__global__ void t_cvt(const float* __restrict__ in, bf16* __restrict__ out,
                      int R, int C, long inZ, long outZ) {
    __shared__ float tile[64][65];
    in  += inZ  * blockIdx.z;
    out += outZ * blockIdx.z;
    const int tx = threadIdx.x & 63, ty = threadIdx.x >> 6;
    const int r0 = blockIdx.y * 64, c0 = blockIdx.x * 64;
    #pragma unroll
    for (int rr = 0; rr < 16; rr++) {
        int row = ty * 16 + rr;
        tile[row][tx] = in[(size_t)(r0 + row) * C + c0 + tx];
    }
    __syncthreads();
    #pragma unroll
    for (int rr = 0; rr < 16; rr++) {
        int row = ty * 16 + rr;
        out[(size_t)(c0 + row) * R + r0 + tx] = __float2bfloat16(tile[tx][row]);
    }
}

// ---------------------------------------------------------------------------
// Wave-per-row LN family (64 threads/block, 3 elems/lane, butterfly reduce)
// ---------------------------------------------------------------------------
__device__ __forceinline__ void wave_sum2(float& s, float& ss) {
    #pragma unroll
    for (int off = 1; off < 64; off <<= 1) {
        s  += __shfl_xor(s,  off, 64);
        ss += __shfl_xor(ss, off, 64);
    }
}

// writes fp32 x, bf16 xb, AND transposed bf16 xT[d][t]
__global__ void k_embed(const int* __restrict__ idx, const float* __restrict__ emb,
                        const float* __restrict__ pos, float* __restrict__ x,
                        bf16* __restrict__ xb, bf16* __restrict__ xT) {
    int t = blockIdx.x, l = threadIdx.x;
    int tok = idx[t];
    const float* e = emb + tok * D_DIM;
    const float* p = pos + t * D_DIM;
    float v0 = e[l] + p[l], v1 = e[l + 64] + p[l + 64], v2 = e[l + 128] + p[l + 128];
    float s = v0 + v1 + v2, ss = v0 * v0 + v1 * v1 + v2 * v2;
    wave_sum2(s, ss);
    float m = s / D_DIM, r = rsqrtf(ss / D_DIM - m * m + LN_EPS);
    float* xr = x + t * D_DIM;
    bf16*  xo = xb + (size_t)t * D_DIM;
    float o0 = (v0 - m) * r, o1 = (v1 - m) * r, o2 = (v2 - m) * r;
    xr[l] = o0; xr[l + 64] = o1; xr[l + 128] = o2;
    bf16 b0 = __float2bfloat16(o0), b1 = __float2bfloat16(o1), b2 = __float2bfloat16(o2);
    xo[l] = b0; xo[l + 64] = b1; xo[l + 128] = b2;
    bf16* col = xT + t;
    col[(size_t)l * T_SEQ]         = b0;
    col[(size_t)(l + 64) * T_SEQ]  = b1;
    col[(size_t)(l + 128) * T_SEQ] = b2;
}

__global__ void k_ln(float* __restrict__ buf) {
    int l = threadIdx.x;
    float* row = buf + (size_t)blockIdx.x * D_DIM;
    float v0 = row[l], v1 = row[l + 64], v2 = row[l + 128];
    float s = v0 + v1 + v2, ss = v0 * v0 + v1 * v1 + v2 * v2;
    wave_sum2(s, ss);
    float m = s / D_DIM, r = rsqrtf(ss / D_DIM - m * m + LN_EPS);
    row[l] = (v0 - m) * r; row[l + 64] = (v1 - m) * r; row[l + 128] = (v2 - m) * r;
}

// x = LN(x + LN(sum of NSLAB split-K partial slabs)); writes xb + xT too
template <int NSLAB>
__global__ void k_resid(float* __restrict__ x, const float* __restrict__ P,
                        bf16* __restrict__ xb, bf16* __restrict__ xT) {
    int l = threadIdx.x, t = blockIdx.x;
    float y0 = 0.f, y1 = 0.f, y2 = 0.f;
    #pragma unroll
    for (int p = 0; p < NSLAB; p++) {
        const float* r = P + (size_t)p * T_SEQ * D_DIM + (size_t)t * D_DIM;
        y0 += r[l]; y1 += r[l + 64]; y2 += r[l + 128];
    }
    float* xr = x + (size_t)t * D_DIM;
    float s = y0 + y1 + y2, ss = y0 * y0 + y1 * y1 + y2 * y2;
    wave_sum2(s, ss);
    float m1 = s / D_DIM, r1 = rsqrtf(ss / D_DIM - m1 * m1 + LN_EPS);
    float v0 = xr[l] + (y0 - m1) * r1;
    float v1 = xr[l + 64] + (y1 - m1) * r1;
    float v2 = xr[l + 128] + (y2 - m1) * r1;
    s = v0 + v1 + v2; ss = v0 * v0 + v1 * v1 + v2 * v2;
    wave_sum2(s, ss);
    float m2 = s / D_DIM, r2 = rsqrtf(ss / D_DIM - m2 * m2 + LN_EPS);
    float o0 = (v0 - m2) * r2, o1 = (v1 - m2) * r2, o2 = (v2 - m2) * r2;
    xr[l] = o0; xr[l + 64] = o1; xr[l + 128] = o2;
    bf16 b0 = __float2bfloat16(o0), b1 = __float2bfloat16(o1), b2 = __float2bfloat16(o2);
    bf16* xo = xb + (size_t)t * D_DIM;
    xo[l] = b0; xo[l + 64] = b1; xo[l + 128] = b2;
    bf16* col = xT + t;
    col[(size_t)l * T_SEQ]         = b0;
    col[(size_t)(l + 64) * T_SEQ]  = b1;
    col[(size_t)(l + 128) * T_SEQ] = b2;
}

// RoPE cos/sin tables, interleaved bf16 pairs csT[t][p] = (cos, sin)
__global__ void k_tables(ushort2* __restrict__ csT) {
    int gid = blockIdx.x * 256 + threadIdx.x;
    int t = gid / NP2, p = gid % NP2;
    float qf = (float)(2 * p);
    float f = exp2f(qf * (-16.0f / 3072.0f)) * (1.0f / (float)TWO_PI);
    float ph = fmodf((float)t * f, 1.0f) * (float)TWO_PI;
    ushort2 cs;
    cs.x = f2us(cosf(ph));
    cs.y = f2us(sinf(ph));
    csT[gid] = cs;
}

// ---------------------------------------------------------------------------
// scores64: partial scores, split-K=2, FLAT 1-D grid of 1088 with XCD
// pinning: xcd = bid&7 -> (h = xcd>>1, kh = xcd&1), L = bid>>3.
// 64x64 tile, 4 waves x one 32x32x16 MFMA acc, BK=64, double-buffered LDS +
// 2-deep register prefetch, LDS-staged coalesced epilogue.
// ---------------------------------------------------------------------------
__launch_bounds__(256, 4)
__global__ void scores64(const bf16* __restrict__ qr, bf16* __restrict__ sc,
                         bf16* __restrict__ dbuf) {
    const int bid = blockIdx.x;
    const int xcd = bid & 7;
    const int h   = xcd >> 1;
    const int kh  = xcd & 1;
    const int L   = bid >> 3;                      // 0..135, in-order per XCD
    int i = 0;
    while (((i + 1) * (i + 2)) >> 1 <= L) ++i;
    int j = L - ((i * (i + 1)) >> 1);
    const int t0 = i * 64, s0 = j * 64;
    const bool diag = (i == j);

    int arow = t0, brow = s0;
    if (kh == 1 && !diag) { arow = s0; brow = t0; }

    __shared__ short As[2][64][72];
    __shared__ short Bs[2][64][72];

    const int tid = threadIdx.x;
    const int lane = tid & 63, w = tid >> 6;
    const int wtm = (w >> 1) * 32, wtn = (w & 1) * 32;
    const int l31 = lane & 31, lhi = lane >> 5;
    const int r0 = tid >> 2;
    const int kq = (tid & 3) * 16;

    const int kBeg = kh * (N_DIM / 2);
    const bf16* gA = qr + (size_t)(arow + r0) * HN + h * N_DIM + kBeg + kq;
    const bf16* gB = qr + (size_t)(brow + r0) * HN + h * N_DIM + kBeg + kq;

    u16x8 pa0, pa1, pb0, pb1;
    u16x8 qa0, qa1, qb0, qb1;
    auto load0 = [&](int k0) {
        pa0 = *(const u16x8*)(gA + k0);
        pa1 = *(const u16x8*)(gA + k0 + 8);
        pb0 = *(const u16x8*)(gB + k0);
        pb1 = *(const u16x8*)(gB + k0 + 8);
    };
    auto load1 = [&](int k0) {
        qa0 = *(const u16x8*)(gA + k0);
        qa1 = *(const u16x8*)(gA + k0 + 8);
        qb0 = *(const u16x8*)(gB + k0);
        qb1 = *(const u16x8*)(gB + k0 + 8);
    };
    auto dep0 = [&](int buf) {
        *(u16x8*)&As[buf][r0][kq]     = pa0;
        *(u16x8*)&As[buf][r0][kq + 8] = pa1;
        *(u16x8*)&Bs[buf][r0][kq]     = pb0;
        *(u16x8*)&Bs[buf][r0][kq + 8] = pb1;
    };
    auto dep1 = [&](int buf) {
        *(u16x8*)&As[buf][r0][kq]     = qa0;
        *(u16x8*)&As[buf][r0][kq + 8] = qa1;
        *(u16x8*)&Bs[buf][r0][kq]     = qb0;
        *(u16x8*)&Bs[buf][r0][kq + 8] = qb1;
    };

    f32x16 acc;
    #pragma unroll
    for (int r = 0; r < 16; r++) acc[r] = 0.f;

    auto mfma_step = [&](int buf) {
        #pragma unroll
        for (int ks = 0; ks < 4; ks++) {
            s16x8 a = *(const s16x8*)&As[buf][wtm + l31][ks * 16 + lhi * 8];
            s16x8 b = *(const s16x8*)&Bs[buf][wtn + l31][ks * 16 + lhi * 8];
            acc = __builtin_amdgcn_mfma_f32_32x32x16_bf16(a, b, acc, 0, 0, 0);
        }
    };

    const int NIT = (N_DIM / 2) / 64;   // 24 (even)
    load0(0);
    load1(64);
    dep0(0);
    __syncthreads();

    for (int k = 0; k < NIT; k += 2) {
        if (k + 2 < NIT) load0((k + 2) * 64);
        mfma_step(0);
        if (k + 1 < NIT) dep1(1);
        __syncthreads();
        if (k + 1 < NIT) {
            if (k + 3 < NIT) load1((k + 3) * 64);
            mfma_step(1);
            if (k + 2 < NIT) dep0(0);
            __syncthreads();
        }
    }

    __syncthreads();
    short (*S)[72] = (short(*)[72])&As[0][0][0];
    const bool trS = (kh == 1) && !diag;
    #pragma unroll
    for (int r = 0; r < 16; r++) {
        int rr = wtm + (r & 3) + 8 * (r >> 2) + 4 * lhi;
        int cc = wtn + l31;
        float v = acc[r];
        if (diag && cc >= rr) v = 0.f;
        if (trS) S[cc][rr] = (short)f2us(v);
        else     S[rr][cc] = (short)f2us(v);
    }
    __syncthreads();
    if (kh == 1 && diag) {
        bf16* P = dbuf + (size_t)(h * 16 + i) * 4096;
        #pragma unroll
        for (int e = 0; e < 2; e++) {
            int idxe = tid + e * 256;
            int row = idxe >> 3, cg = (idxe & 7) * 8;
            u16x8 v = *(const u16x8*)&S[row][cg];
            *(u16x8*)(P + row * 64 + cg) = v;
        }
    } else {
        bf16* C = sc + (size_t)h * T_SEQ * T_SEQ;
        #pragma unroll
        for (int e = 0; e < 2; e++) {
            int idxe = tid + e * 256;
            int row = idxe >> 3, cg = (idxe & 7) * 8;
            u16x8 v = *(const u16x8*)&S[row][cg];
            *(u16x8*)(C + (size_t)(arow + row) * T_SEQ + brow + cg) = v;
        }
    }
}

// ---------------------------------------------------------------------------
// scores fallback (no qr buffer): 64x64, rope fused into staging.
// ---------------------------------------------------------------------------
__device__ __forceinline__ void stage_rope8(short* dst, const bf16* src,
                                            const ushort2* csP) {
    u16x8 v  = *(const u16x8*)src;
    u16x8 cs = *(const u16x8*)csP;
    u16x8 o;
    #pragma unroll
    for (int i = 0; i < 4; i++) {
        float e  = us2f(v[2 * i]), od = us2f(v[2 * i + 1]);
        float c  = us2f(cs[2 * i]), s = us2f(cs[2 * i + 1]);
        o[2 * i]     = f2us(e * c - od * s);
        o[2 * i + 1] = f2us(od * c + e * s);
    }
    *(u16x8*)dst = o;
}

__launch_bounds__(256)
__global__ void scores_fused(const bf16* __restrict__ xs,
                             const ushort2* __restrict__ csT,
                             bf16* __restrict__ sc) {
    const int h  = blockIdx.z;
    const int s0 = blockIdx.x * 64, t0 = blockIdx.y * 64;
    if (s0 > t0) return;
    __shared__ short As[64][40];
    __shared__ short Bs[64][40];
    const int tid  = threadIdx.x;
    const int srow = tid >> 2, kq = (tid & 3) * 8;
    const int lane = tid & 63, w = tid >> 6, qd = lane >> 4, lc = lane & 15;
    const int tA = t0 + srow, tB = s0 + srow;
    const bf16* gA = xs + (size_t)tA * HN + h * N_DIM + kq;
    const bf16* gB = xs + (size_t)tB * HN + h * N_DIM + kq;
    const ushort2* cA = csT + (size_t)tA * NP2 + (kq >> 1);
    const ushort2* cB = csT + (size_t)tB * NP2 + (kq >> 1);
    f32x4 acc[4] = {{0.f,0.f,0.f,0.f},{0.f,0.f,0.f,0.f},
                    {0.f,0.f,0.f,0.f},{0.f,0.f,0.f,0.f}};
    for (int k0 = 0; k0 < N_DIM; k0 += 32) {
        stage_rope8(&As[srow][kq], gA + k0, cA + (k0 >> 1));
        stage_rope8(&Bs[srow][kq], gB + k0, cB + (k0 >> 1));
        __syncthreads();
        s16x8 a = *(const s16x8*)&As[w * 16 + lc][qd * 8];
        #pragma unroll
        for (int j = 0; j < 4; j++) {
            s16x8 b = *(const s16x8*)&Bs[j * 16 + lc][qd * 8];
            acc[j] = __builtin_amdgcn_mfma_f32_16x16x32_bf16(a, b, acc[j], 0, 0, 0);
        }
        __syncthreads();
    }
    bf16* C = sc + (size_t)h * T_SEQ * T_SEQ;
    const bool diag = (s0 == t0);
    const int tbase = t0 + w * 16 + qd * 4;
    #pragma unroll
    for (int j = 0; j < 4; j++) {
        int s = s0 + j * 16 + lc;
        #pragma unroll
        for (int r = 0; r < 4; r++) {
            int t = tbase + r;
            C[(size_t)t * T_SEQ + s] =
                __float2bfloat16((!diag || s < t) ? acc[j][r] : 0.f);
        }
    }
}

// ---------------------------------------------------------------------------
// dgemm128: 128x128 tile, 4 waves x (64x64 = 2x2 of 32x32x16 MFMA accs),
// K=192 (BK=32), double-buffered LDS + 2-deep register prefetch, LDS-staged
// coalesced epilogue (relu / rope / gate). TA = bf16 or float.
// ---------------------------------------------------------------------------
template <int EPI, bool WQR, typename TA>
__launch_bounds__(256)
__global__ void dgemm128(const TA* __restrict__ A, const bf16* __restrict__ Bt,
                         bf16* __restrict__ xs, bf16* __restrict__ qr,
                         const ushort2* __restrict__ csT) {
    __shared__ __align__(16) short pool[2 * 2 * 128 * 40];   // 40 KB
    short (*As)[128][40] = (short(*)[128][40])pool;
    short (*Bs)[128][40] = (short(*)[128][40])(pool + 2 * 128 * 40);

    const int tid = threadIdx.x;
    const int lane = tid & 63, w = tid >> 6;
    const int l31 = lane & 31, lhi = lane >> 5;
    const int wtm = (w >> 1) * 64, wtn = (w & 1) * 64;
    const int n0 = blockIdx.x * 128, m0 = blockIdx.y * 128;
    if constexpr (EPI == 2) A += (size_t)(n0 / N_DIM) * T_SEQ * D_DIM;

    const int r0 = tid >> 2, r1 = r0 + 64;
    const int kq = (tid & 3) * 8;

    const TA*   gA = A  + kq;
    const bf16* gB = Bt + kq;

    float4 fa00, fa01, fa02, fa03, fa10, fa11, fa12, fa13;
    u16x8 ba00, ba01, ba10, ba11;
    u16x8 pb00, pb01, pb10, pb11;
    auto load0 = [&](int k0) {
        if constexpr (__is_same(TA, float)) {
            const TA* a0 = gA + (size_t)(m0 + r0) * D_DIM + k0;
            const TA* a1 = gA + (size_t)(m0 + r1) * D_DIM + k0;
            fa00 = *(const float4*)a0; fa01 = *(const float4*)(a0 + 4);
            fa02 = *(const float4*)a1; fa03 = *(const float4*)(a1 + 4);
        } else {
            ba00 = *(const u16x8*)(gA + (size_t)(m0 + r0) * D_DIM + k0);
            ba01 = *(const u16x8*)(gA + (size_t)(m0 + r1) * D_DIM + k0);
        }
        pb00 = *(const u16x8*)(gB + (size_t)(n0 + r0) * D_DIM + k0);
        pb01 = *(const u16x8*)(gB + (size_t)(n0 + r1) * D_DIM + k0);
    };
    auto load1 = [&](int k0) {
        if constexpr (__is_same(TA, float)) {
            const TA* a0 = gA + (size_t)(m0 + r0) * D_DIM + k0;
            const TA* a1 = gA + (size_t)(m0 + r1) * D_DIM + k0;
            fa10 = *(const float4*)a0; fa11 = *(const float4*)(a0 + 4);
            fa12 = *(const float4*)a1; fa13 = *(const float4*)(a1 + 4);
        } else {
            ba10 = *(const u16x8*)(gA + (size_t)(m0 + r0) * D_DIM + k0);
            ba11 = *(const u16x8*)(gA + (size_t)(m0 + r1) * D_DIM + k0);
        }
        pb10 = *(const u16x8*)(gB + (size_t)(n0 + r0) * D_DIM + k0);
        pb11 = *(const u16x8*)(gB + (size_t)(n0 + r1) * D_DIM + k0);
    };
    auto dep0 = [&](int buf) {
        if constexpr (__is_same(TA, float)) {
            u16x8 o0, o1;
            o0[0] = f2us(fa00.x); o0[1] = f2us(fa00.y); o0[2] = f2us(fa00.z); o0[3] = f2us(fa00.w);
            o0[4] = f2us(fa01.x); o0[5] = f2us(fa01.y); o0[6] = f2us(fa01.z); o0[7] = f2us(fa01.w);
            o1[0] = f2us(fa02.x); o1[1] = f2us(fa02.y); o1[2] = f2us(fa02.z); o1[3] = f2us(fa02.w);
            o1[4] = f2us(fa03.x); o1[5] = f2us(fa03.y); o1[6] = f2us(fa03.z); o1[7] = f2us(fa03.w);
            *(u16x8*)&As[buf][r0][kq] = o0;
            *(u16x8*)&As[buf][r1][kq] = o1;
        } else {
            *(u16x8*)&As[buf][r0][kq] = ba00;
            *(u16x8*)&As[buf][r1][kq] = ba01;
        }
        *(u16x8*)&Bs[buf][r0][kq] = pb00;
        *(u16x8*)&Bs[buf][r1][kq] = pb01;
    };
    auto dep1 = [&](int buf) {
        if constexpr (__is_same(TA, float)) {
            u16x8 o0, o1;
            o0[0] = f2us(fa10.x); o0[1] = f2us(fa10.y); o0[2] = f2us(fa10.z); o0[3] = f2us(fa10.w);
            o0[4] = f2us(fa11.x); o0[5] = f2us(fa11.y); o0[6] = f2us(fa11.z); o0[7] = f2us(fa11.w);
            o1[0] = f2us(fa12.x); o1[1] = f2us(fa12.y); o1[2] = f2us(fa12.z); o1[3] = f2us(fa12.w);
            o1[4] = f2us(fa13.x); o1[5] = f2us(fa13.y); o1[6] = f2us(fa13.z); o1[7] = f2us(fa13.w);
            *(u16x8*)&As[buf][r0][kq] = o0;
            *(u16x8*)&As[buf][r1][kq] = o1;
        } else {
            *(u16x8*)&As[buf][r0][kq] = ba10;
            *(u16x8*)&As[buf][r1][kq] = ba11;
        }
        *(u16x8*)&Bs[buf][r0][kq] = pb10;
        *(u16x8*)&Bs[buf][r1][kq] = pb11;
    };

    f32x16 acc00, acc01, acc10, acc11;
    #pragma unroll
    for (int r = 0; r < 16; r++) { acc00[r] = 0.f; acc01[r] = 0.f; acc10[r] = 0.f; acc11[r] = 0.f; }

    auto mfma_step = [&](int buf) {
        #pragma unroll
        for (int ks = 0; ks < 2; ks++) {
            s16x8 a0 = *(const s16x8*)&As[buf][wtm + l31][ks * 16 + lhi * 8];
            s16x8 a1 = *(const s16x8*)&As[buf][wtm + 32 + l31][ks * 16 + lhi * 8];
            s16x8 b0 = *(const s16x8*)&Bs[buf][wtn + l31][ks * 16 + lhi * 8];
            s16x8 b1 = *(const s16x8*)&Bs[buf][wtn + 32 + l31][ks * 16 + lhi * 8];
            acc00 = __builtin_amdgcn_mfma_f32_32x32x16_bf16(a0, b0, acc00, 0, 0, 0);
            acc01 = __builtin_amdgcn_mfma_f32_32x32x16_bf16(a0, b1, acc01, 0, 0, 0);
            acc10 = __builtin_amdgcn_mfma_f32_32x32x16_bf16(a1, b0, acc10, 0, 0, 0);
            acc11 = __builtin_amdgcn_mfma_f32_32x32x16_bf16(a1, b1, acc11, 0, 0, 0);
        }
    };

    const int NIT = D_DIM / 32;   // 6 (even)
    load0(0);
    load1(32);
    dep0(0);
    __syncthreads();
    for (int k = 0; k < NIT; k += 2) {
        if (k + 2 < NIT) load0((k + 2) * 32);
        mfma_step(0);
        if (k + 1 < NIT) dep1(1);
        __syncthreads();
        if (k + 1 < NIT) {
            if (k + 3 < NIT) load1((k + 3) * 32);
            mfma_step(1);
            if (k + 2 < NIT) dep0(0);
            __syncthreads();
        }
    }

    // -------- LDS-staged epilogue --------
    short (*S)[136] = (short(*)[136])pool; // 128 x 136 shorts = 34.8 KB <= 40 KB
    #pragma unroll
    for (int r = 0; r < 16; r++) {
        int rb = (r & 3) + 8 * (r >> 2) + 4 * lhi;
        S[wtm + rb     ][wtn + l31     ] = (short)f2us(fmaxf(acc00[r], 0.f));
        S[wtm + rb     ][wtn + 32 + l31] = (short)f2us(fmaxf(acc01[r], 0.f));
        S[wtm + 32 + rb][wtn + l31     ] = (short)f2us(fmaxf(acc10[r], 0.f));
        S[wtm + 32 + rb][wtn + 32 + l31] = (short)f2us(fmaxf(acc11[r], 0.f));
    }
    __syncthreads();
    #pragma unroll
    for (int e = 0; e < 8; e++) {
        int idxe = tid + e * 256;
        int row = idxe >> 4, cg = idxe & 15;
        u16x8 v = *(const u16x8*)&S[row][cg * 8];
        int t = m0 + row, ngg = n0 + cg * 8;
        size_t ci = (size_t)t * HN + ngg;
        if constexpr (EPI == 1) {
            *(u16x8*)(xs + ci) = v;
            if constexpr (WQR) {
                int p0 = (ngg % N_DIM) >> 1;
                u16x8 cs8 = *(const u16x8*)&csT[(size_t)t * NP2 + p0];
                u16x8 o;
                #pragma unroll
                for (int q = 0; q < 4; q++) {
                    float ev = us2f(v[2 * q]), ov = us2f(v[2 * q + 1]);
                    float c = us2f(cs8[2 * q]), s = us2f(cs8[2 * q + 1]);
                    o[2 * q]     = f2us(ev * c - ov * s);
                    o[2 * q + 1] = f2us(ov * c + ev * s);
                }
                *(u16x8*)(qr + ci) = o;
            }
        } else {
            u16x8 g = *(const u16x8*)(xs + ci);
            u16x8 o;
            #pragma unroll
            for (int q = 0; q < 8; q++) o[q] = f2us(us2f(g[q]) * us2f(v[q]));
            *(u16x8*)(xs + ci) = o;
        }
    }
}

// ---------------------------------------------------------------------------
// gate_ymlp: fused  ymlp_slab = (xs ⊙ relu(LN(ykv0+ykv1) @ decY)) @ enc.
// LN slab-combine fused in prologue. NOW with full register prefetch of all
// staged operands (T14 async-STAGE): ldXS(c)+ldB2(c) issued at chunk top and
// ldB1(c+1) right after B1 is consumed — every global staging load is in
// flight across >=1 MFMA stage instead of serially exposed between barriers.
// FLAT grid of 256 with XCD pinning: s = (bid&7) + 8*(bid>>7), tb=(bid>>3)&15.
// ---------------------------------------------------------------------------
__launch_bounds__(256, 2)
__global__ void gate_ymlp(const float* __restrict__ ykv0, const float* __restrict__ ykv1,
                          const bf16* __restrict__ wY,
                          const bf16* __restrict__ xs, const bf16* __restrict__ wE,
                          float* __restrict__ P) {
    const int bid = blockIdx.x;
    const int s   = (bid & 7) + ((bid >> 7) << 3);   // 0..15, pinned by XCD
    const int tb  = (bid >> 3) & 15;                 // 0..15
    const int t0  = tb * 64;
    const int h   = s >> 2;               // 4 segments of 768 per head
    const int ng0 = s * 768;              // global n base of this slab
    const int nh0 = (s & 3) * 768;        // within-head n base

    __shared__ __align__(16) short A1s[64][200];   // LN(ykv) tile (25.6 KB)
    __shared__ __align__(16) short Bsh[192][72];   // B2 view      (27.6 KB)
    __shared__ __align__(16) short xyA[64][72];    // xy chunk     ( 9.2 KB)
    short (*B1)[200] = (short(*)[200])&Bsh[0][0];  // B1 overlays B2 (12800<=13824)

    const int tid = threadIdx.x;
    const int lane = tid & 63, w = tid >> 6;
    const int l31 = lane & 31, lhi = lane >> 5;
    const int wm  = (w >> 1) * 32;        // t-offset of wave
    const int wn1 = (w & 1) * 32;         // n-offset (stage1)
    const int wn2 = (w & 1) * 96;         // d-offset (stage2)

    const int srow = tid >> 2, sq = tid & 3;   // staging row / quarter

    // ---- register prefetch sets (all statically indexed after unroll) ----
    u16x8 rb[6];   // next B1 chunk (wY rows)
    u16x8 re[6];   // this chunk's B2 (wE rows)
    u16x8 rx0, rx1;  // this chunk's xs
    auto ldB1 = [&](int c) {
        const bf16* src = wY + ((size_t)h * N_DIM + nh0 + c * 64 + srow) * D_DIM
                        + sq * 48;
        #pragma unroll
        for (int jj = 0; jj < 6; jj++) rb[jj] = *(const u16x8*)(src + jj * 8);
    };
    auto depB1 = [&]() {
        #pragma unroll
        for (int jj = 0; jj < 6; jj++)
            *(u16x8*)&B1[srow][sq * 48 + jj * 8] = rb[jj];
    };
    auto ldB2 = [&](int c) {
        #pragma unroll
        for (int jj = 0; jj < 3; jj++) {
            int d  = srow * 3 + jj;               // 0..191
            const bf16* src = wE + (size_t)d * HN + ng0 + c * 64 + sq * 16;
            re[2 * jj]     = *(const u16x8*)src;
            re[2 * jj + 1] = *(const u16x8*)(src + 8);
        }
    };
    auto depB2 = [&]() {
        #pragma unroll
        for (int jj = 0; jj < 3; jj++) {
            int d  = srow * 3 + jj;
            *(u16x8*)&Bsh[d][sq * 16]     = re[2 * jj];
            *(u16x8*)&Bsh[d][sq * 16 + 8] = re[2 * jj + 1];
        }
    };
    auto ldXS = [&](int c) {
        const bf16* sx = xs + (size_t)(t0 + srow) * HN + ng0 + c * 64 + sq * 16;
        rx0 = *(const u16x8*)sx;
        rx1 = *(const u16x8*)(sx + 8);
    };

    // ---- fused slab-combine + LN + bf16 -> A1s ----
    {
        size_t off = ((size_t)h * T_SEQ + t0 + srow) * D_DIM + sq * 48;
        const float* p0 = ykv0 + off;
        const float* p1 = ykv1 + off;
        float v[48];
        float sm = 0.f, ssq = 0.f;
        #pragma unroll
        for (int e = 0; e < 12; e++) {
            float4 a = *(const float4*)(p0 + e * 4);
            float4 b = *(const float4*)(p1 + e * 4);
            float c0 = a.x + b.x, c1 = a.y + b.y, c2 = a.z + b.z, c3 = a.w + b.w;
            v[e * 4 + 0] = c0; v[e * 4 + 1] = c1; v[e * 4 + 2] = c2; v[e * 4 + 3] = c3;
            sm  += c0 + c1 + c2 + c3;
            ssq += c0 * c0 + c1 * c1 + c2 * c2 + c3 * c3;
        }
        sm  += __shfl_xor(sm, 1, 64);  ssq += __shfl_xor(ssq, 1, 64);
        sm  += __shfl_xor(sm, 2, 64);  ssq += __shfl_xor(ssq, 2, 64);
        float m = sm / D_DIM, r = rsqrtf(ssq / D_DIM - m * m + LN_EPS);
        #pragma unroll
        for (int e = 0; e < 6; e++) {
            u16x8 o;
            #pragma unroll
            for (int k2 = 0; k2 < 8; k2++) o[k2] = f2us((v[e * 8 + k2] - m) * r);
            *(u16x8*)&A1s[srow][sq * 48 + e * 8] = o;
        }
    }

    f32x16 oc0, oc1, oc2;
    #pragma unroll
    for (int r = 0; r < 16; r++) { oc0[r] = 0.f; oc1[r] = 0.f; oc2[r] = 0.f; }

    ldB1(0);                               // B1(0) in flight over the barrier
    __syncthreads();

    for (int c = 0; c < 12; c++) {
        const int nc = c * 64;
        ldXS(c);                           // consumed at RMW (~2 stages away)
        ldB2(c);                           // consumed at stage2 (~2 stages away)
        depB1();                           // B1(c) regs -> LDS
        __syncthreads();
        if (c + 1 < 12) ldB1(c + 1);       // in flight across stage1..stage2
        // stage1: ys(64x64) over K=192
        f32x16 ys;
        #pragma unroll
        for (int r = 0; r < 16; r++) ys[r] = 0.f;
        #pragma unroll
        for (int ks = 0; ks < 12; ks++) {
            s16x8 a = *(const s16x8*)&A1s[wm + l31][ks * 16 + lhi * 8];
            s16x8 b = *(const s16x8*)&B1[wn1 + l31][ks * 16 + lhi * 8];
            ys = __builtin_amdgcn_mfma_f32_32x32x16_bf16(a, b, ys, 0, 0, 0);
        }
        __syncthreads();                   // B1 consumed / prev xyA consumed
        // scatter relu(ys) -> xyA (bf16)
        #pragma unroll
        for (int r = 0; r < 16; r++) {
            int rr = wm + (r & 3) + 8 * (r >> 2) + 4 * lhi;
            xyA[rr][wn1 + l31] = (short)f2us(fmaxf(ys[r], 0.f));
        }
        __syncthreads();
        // RMW xyA with prefetched xs regs (no global load here)
        {
            u16x8 y0 = *(const u16x8*)&xyA[srow][sq * 16];
            u16x8 y1 = *(const u16x8*)&xyA[srow][sq * 16 + 8];
            u16x8 o0, o1;
            #pragma unroll
            for (int q = 0; q < 8; q++) {
                o0[q] = f2us(us2f(rx0[q]) * us2f(y0[q]));
                o1[q] = f2us(us2f(rx1[q]) * us2f(y1[q]));
            }
            *(u16x8*)&xyA[srow][sq * 16]     = o0;
            *(u16x8*)&xyA[srow][sq * 16 + 8] = o1;
        }
        depB2();                           // B2(c) regs -> Bsh (B1 dead)
        __syncthreads();
        // stage2: out += xyA(64x64) @ wE-chunk^T(192x64), K=64
        #pragma unroll
        for (int ks = 0; ks < 4; ks++) {
            s16x8 a  = *(const s16x8*)&xyA[wm + l31][ks * 16 + lhi * 8];
            s16x8 b0 = *(const s16x8*)&Bsh[wn2 + l31     ][ks * 16 + lhi * 8];
            s16x8 b1 = *(const s16x8*)&Bsh[wn2 + 32 + l31][ks * 16 + lhi * 8];
            s16x8 b2 = *(const s16x8*)&Bsh[wn2 + 64 + l31][ks * 16 + lhi * 8];
            oc0 = __builtin_amdgcn_mfma_f32_32x32x16_bf16(a, b0, oc0, 0, 0, 0);
            oc1 = __builtin_amdgcn_mfma_f32_32x32x16_bf16(a, b1, oc1, 0, 0, 0);
            oc2 = __builtin_amdgcn_mfma_f32_32x32x16_bf16(a, b2, oc2, 0, 0, 0);
        }
        __syncthreads();                   // before next chunk's B1/xyA writes
    }

    // write slab P[s][t][d]
    float* O = P + (size_t)s * T_SEQ * D_DIM;
    #pragma unroll
    for (int r = 0; r < 16; r++) {
        int rt = t0 + wm + (r & 3) + 8 * (r >> 2) + 4 * lhi;
        O[(size_t)rt * D_DIM + wn2 +      l31] = oc0[r];
        O[(size_t)rt * D_DIM + wn2 + 32 + l31] = oc1[r];
        O[(size_t)rt * D_DIM + wn2 + 64 + l31] = oc2[r];
    }
}

// ---------------------------------------------------------------------------
// mfma_gemm (64x64): MODE 0 = plain, 1 = causal split-K=2 WITH dual-A partial
// combine AND flat-grid XCD pinning (bid&7 = z = head*2+seg), 2 = split-K
// slabs over z (fallback ymlp), 3 = causal full (fallback). 32x32x16 MFMA,
// BK=64, double-buffered LDS + 2-deep prefetch.
// ---------------------------------------------------------------------------
template <typename TA, int MODE>
__launch_bounds__(256)
__global__ void mfma_gemm(const TA* __restrict__ A, const bf16* __restrict__ Bt,
                          float* __restrict__ C, const bf16* __restrict__ aux,
                          int K, int kSeg, int lda, int ldb, int ldc,
                          long aZ, long bZ, long cZ) {
    constexpr bool DUAL = (MODE == 1);
    constexpr int TILES = DUAL ? 6 : 4;
    __shared__ __align__(16) short pool[TILES * 64 * 72];
    short (*As)[64][72] = (short(*)[64][72])pool;
    short (*Bs)[64][72] = (short(*)[64][72])(pool + 2 * 64 * 72);
    short (*Ms)[64][72] = (short(*)[64][72])(pool + 4 * 64 * 72);

    int bx, by, z;
    if constexpr (MODE == 1) {
        // flat grid 384: xcd = bid&7 = z (head*2+seg); rest enumerates (x,y)
        const int bid  = blockIdx.x;
        z = bid & 7;
        const int rest = bid >> 3;      // 0..47
        bx = rest % 3;
        by = rest / 3;
    } else {
        bx = blockIdx.x; by = blockIdx.y; z = blockIdx.z;
    }

    const int tid = threadIdx.x;
    const int n0 = bx * 64, m0 = by * 64;
    const int srow = tid >> 2, sk = (tid & 3) * 16;
    const int lane = tid & 63, w = tid >> 6;
    const int l31 = lane & 31, lhi = lane >> 5;
    const int wm = (w >> 1) * 32, wn = (w & 1) * 32;

    int kBeg, kEnd, zh = 0;
    if constexpr (MODE == 1) {
        zh = z >> 1;
        const int seg = z & 1;
        A += aZ * zh;
        C += cZ * zh + bZ * seg;
        const int kc = (m0 + 64 < K) ? m0 + 64 : K;
        const int half0 = ((kc + 127) >> 7) << 6;   // ceil(kc/128)*64
        kBeg = seg ? half0 : 0;
        kEnd = seg ? kc : half0;
    } else if constexpr (MODE == 2) {
        A += aZ * z; Bt += bZ * z; C += cZ * z;
        kBeg = z * kSeg; kEnd = kBeg + kSeg;
    } else if constexpr (MODE == 3) {
        A += aZ * z; Bt += bZ * z; C += cZ * z;
        kBeg = 0; kEnd = (m0 + 64 < K) ? m0 + 64 : K;
    } else {
        A += aZ * z; Bt += bZ * z; C += cZ * z;
        kBeg = 0; kEnd = K;
    }

    const TA*   ga = A  + (size_t)(m0 + srow) * lda + sk;
    const bf16* gb = Bt + (size_t)(n0 + srow) * ldb + sk;

    auto msrc = [&](int k0) -> const bf16* {
        if (k0 == m0)
            return aux + (size_t)(zh * 16 + (m0 >> 6)) * 4096
                       + (size_t)srow * 64 + sk;
        return (const bf16*)A + (size_t)(k0 + srow) * lda + m0 + sk;
    };

    float4 f00, f01, f02, f03, f10, f11, f12, f13;
    u16x8 pa00, pa01, pa10, pa11, pb00, pb01, pb10, pb11;
    u16x8 pm00, pm01, pm10, pm11;
    auto load0 = [&](int k0) {
        if constexpr (__is_same(TA, float)) {
            f00 = *(const float4*)(ga + k0);
            f01 = *(const float4*)(ga + k0 + 4);
            f02 = *(const float4*)(ga + k0 + 8);
            f03 = *(const float4*)(ga + k0 + 12);
        } else {
            pa00 = *(const u16x8*)(ga + k0);
            pa01 = *(const u16x8*)(ga + k0 + 8);
        }
        pb00 = *(const u16x8*)(gb + k0);
        pb01 = *(const u16x8*)(gb + k0 + 8);
        if constexpr (DUAL) {
            const bf16* ms = msrc(k0);
            pm00 = *(const u16x8*)ms;
            pm01 = *(const u16x8*)(ms + 8);
        }
    };
    auto load1 = [&](int k0) {
        if constexpr (__is_same(TA, float)) {
            f10 = *(const float4*)(ga + k0);
            f11 = *(const float4*)(ga + k0 + 4);
            f12 = *(const float4*)(ga + k0 + 8);
            f13 = *(const float4*)(ga + k0 + 12);
        } else {
            pa10 = *(const u16x8*)(ga + k0);
            pa11 = *(const u16x8*)(ga + k0 + 8);
        }
        pb10 = *(const u16x8*)(gb + k0);
        pb11 = *(const u16x8*)(gb + k0 + 8);
        if constexpr (DUAL) {
            const bf16* ms = msrc(k0);
            pm10 = *(const u16x8*)ms;
            pm11 = *(const u16x8*)(ms + 8);
        }
    };
    auto dep0 = [&](int buf) {
        if constexpr (__is_same(TA, float)) {
            u16x8 o0, o1;
            o0[0] = f2us(f00.x); o0[1] = f2us(f00.y); o0[2] = f2us(f00.z); o0[3] = f2us(f00.w);
            o0[4] = f2us(f01.x); o0[5] = f2us(f01.y); o0[6] = f2us(f01.z); o0[7] = f2us(f01.w);
            o1[0] = f2us(f02.x); o1[1] = f2us(f02.y); o1[2] = f2us(f02.z); o1[3] = f2us(f02.w);
            o1[4] = f2us(f03.x); o1[5] = f2us(f03.y); o1[6] = f2us(f03.z); o1[7] = f2us(f03.w);
            *(u16x8*)&As[buf][srow][sk]     = o0;
            *(u16x8*)&As[buf][srow][sk + 8] = o1;
        } else {
            *(u16x8*)&As[buf][srow][sk]     = pa00;
            *(u16x8*)&As[buf][srow][sk + 8] = pa01;
        }
        *(u16x8*)&Bs[buf][srow][sk]     = pb00;
        *(u16x8*)&Bs[buf][srow][sk + 8] = pb01;
        if constexpr (DUAL) {
            *(u16x8*)&Ms[buf][srow][sk]     = pm00;
            *(u16x8*)&Ms[buf][srow][sk + 8] = pm01;
        }
    };
    auto dep1 = [&](int buf) {
        if constexpr (__is_same(TA, float)) {
            u16x8 o0, o1;
            o0[0] = f2us(f10.x); o0[1] = f2us(f10.y); o0[2] = f2us(f10.z); o0[3] = f2us(f10.w);
            o0[4] = f2us(f11.x); o0[5] = f2us(f11.y); o0[6] = f2us(f11.z); o0[7] = f2us(f11.w);
            o1[0] = f2us(f12.x); o1[1] = f2us(f12.y); o1[2] = f2us(f12.z); o1[3] = f2us(f12.w);
            o1[4] = f2us(f13.x); o1[5] = f2us(f13.y); o1[6] = f2us(f13.z); o1[7] = f2us(f13.w);
            *(u16x8*)&As[buf][srow][sk]     = o0;
            *(u16x8*)&As[buf][srow][sk + 8] = o1;
        } else {
            *(u16x8*)&As[buf][srow][sk]     = pa10;
            *(u16x8*)&As[buf][srow][sk + 8] = pa11;
        }
        *(u16x8*)&Bs[buf][srow][sk]     = pb10;
        *(u16x8*)&Bs[buf][srow][sk + 8] = pb11;
        if constexpr (DUAL) {
            *(u16x8*)&Ms[buf][srow][sk]     = pm10;
            *(u16x8*)&Ms[buf][srow][sk + 8] = pm11;
        }
    };

    f32x16 acc;
    #pragma unroll
    for (int r = 0; r < 16; r++) acc[r] = 0.f;

    auto mfma_step = [&](int buf) {
        #pragma unroll
        for (int ks = 0; ks < 4; ks++) {
            s16x8 a = *(const s16x8*)&As[buf][wm + l31][ks * 16 + lhi * 8];
            s16x8 b = *(const s16x8*)&Bs[buf][wn + l31][ks * 16 + lhi * 8];
            acc = __builtin_amdgcn_mfma_f32_32x32x16_bf16(a, b, acc, 0, 0, 0);
            if constexpr (DUAL) {
                s16x8 m2 = *(const s16x8*)&Ms[buf][wm + l31][ks * 16 + lhi * 8];
                acc = __builtin_amdgcn_mfma_f32_32x32x16_bf16(m2, b, acc, 0, 0, 0);
            }
        }
    };

    const int NIT = (kEnd - kBeg) >> 6;
    load0(kBeg);
    load1(kBeg + 64);
    dep0(0);
    __syncthreads();

    for (int k = 0; k < NIT; k += 2) {
        if (k + 2 < NIT) load0(kBeg + (k + 2) * 64);
        mfma_step(0);
        if (k + 1 < NIT) dep1(1);
        __syncthreads();
        if (k + 1 < NIT) {
            if (k + 3 < NIT) load1(kBeg + (k + 3) * 64);
            mfma_step(1);
            if (k + 2 < NIT) dep0(0);
            __syncthreads();
        }
    }

    #pragma unroll
    for (int r = 0; r < 16; r++) {
        int row = m0 + wm + (r & 3) + 8 * (r >> 2) + 4 * lhi;
        int col = n0 + wn + l31;
        C[(size_t)row * ldc + col] = acc[r];
    }
}

extern "C" void kernel_launch(void* const* d_in, const int* in_sizes, int n_in,
                              void* d_out, int out_size, void* d_ws, size_t ws_size,
                              hipStream_t stream) {
    const int*   idx   = (const int*)  d_in[0];
    const float* dec_x = (const float*)d_in[1];   // (NH, D, N)
    const float* dec_y = (const float*)d_in[2];   // (NH, D, N)
    const float* enc   = (const float*)d_in[3];   // (NH*N, D)
    const float* emb   = (const float*)d_in[4];   // (VOCAB, D)
    const float* pose  = (const float*)d_in[5];   // (BLOCK, D)
    const float* lmh   = (const float*)d_in[6];   // (D, VOCAB)
    float* out = (float*)d_out;                   // (T, VOCAB) fp32

    // workspace layout — identical to passing r11 (ws >= 84,377,600 proven)
    char* wp = (char*)d_ws;
    float*   x    = (float*)wp;              wp += (size_t)T_SEQ * D_DIM * 4;
    bf16*    xs   = (bf16*)wp;               wp += (size_t)T_SEQ * HN * 2;
    ushort2* csT  = (ushort2*)wp;            wp += (size_t)T_SEQ * NP2 * 4;
    bf16*    sc   = (bf16*)wp;               wp += (size_t)NHEAD * T_SEQ * T_SEQ * 2;
    float*   ykv  = (float*)wp;              wp += (size_t)NHEAD * T_SEQ * D_DIM * 4;
    float*   ymlp = (float*)wp;              wp += (size_t)T_SEQ * D_DIM * 4;   // dbuf home
    bf16*    xT   = (bf16*)wp;               wp += (size_t)D_DIM * T_SEQ * 2;
    bf16*    wX   = (bf16*)wp;               wp += (size_t)NHEAD * N_DIM * D_DIM * 2;
    bf16*    wY   = (bf16*)wp;               wp += (size_t)NHEAD * N_DIM * D_DIM * 2;
    bf16*    wE   = (bf16*)wp;               wp += (size_t)D_DIM * HN * 2;
    bf16*    wL   = (bf16*)wp;               wp += (size_t)VOCABSZ * D_DIM * 2;
    const size_t BASE_NEED = (size_t)(wp - (char*)d_ws);
    bf16*    qr   = (bf16*)wp;
    const size_t FULL_NEED = BASE_NEED + (size_t)T_SEQ * HN * 2;
    bf16*  dbuf  = (bf16*)ymlp;    // 512 KB diag partials on idle ymlp keeper

    if (ws_size < BASE_NEED) {
        fill_out<<<(out_size + 255) / 256, 256, 0, stream>>>(out, (float)ws_size, out_size);
        return;
    }
    const bool USE_QR = (ws_size >= FULL_NEED);

    // bf16 A-operand homes (main path): xb on dead sc head; ymlpP16 on qr
    // head; ykv slab1 fp32 on qr+12.6MB. Fallback: xb on ymlp keeper.
    bf16*  xb_main = (bf16*)sc;
    bf16*  xb_fb   = (bf16*)ymlp;
    float* ymlpP16 = (float*)qr;                               // 16 slabs
    float* ykvP1   = (float*)((char*)qr + (size_t)16 * T_SEQ * D_DIM * 4);
    float* ymlpP8  = (float*)sc;                               // fallback slabs

    bf16* xb = USE_QR ? xb_main : xb_fb;

    // weight mirrors (bf16, [n][k])
    t_cvt<<<dim3(48, 3, 4), 256, 0, stream>>>(dec_x, wX, D_DIM, N_DIM,
                                              (long)D_DIM * N_DIM, (long)N_DIM * D_DIM);
    t_cvt<<<dim3(48, 3, 4), 256, 0, stream>>>(dec_y, wY, D_DIM, N_DIM,
                                              (long)D_DIM * N_DIM, (long)N_DIM * D_DIM);
    t_cvt<<<dim3(3, 192, 1), 256, 0, stream>>>(enc, wE, HN, D_DIM, 0L, 0L);
    t_cvt<<<dim3(4, 3, 1), 256, 0, stream>>>(lmh, wL, D_DIM, VOCABSZ, 0L, 0L);

    k_tables<<<(T_SEQ * NP2) / 256, 256, 0, stream>>>(csT);
    // k_embed writes x, xb AND xT
    k_embed<<<T_SEQ, 64, 0, stream>>>(idx, emb, pose, x, xb, xT);

    for (int l = 0; l < NLAYER; ++l) {
        if (USE_QR) {
            // xs = relu(x @ dec_x), qr = rope(xs)
            dgemm128<1, true, bf16><<<dim3(96, 8), 256, 0, stream>>>(xb, wX, xs, qr, csT);
            // flat 1088, XCD-pinned (h,kh)
            scores64<<<dim3(1088), 256, 0, stream>>>(qr, sc, dbuf);
            // ykv = sc @ x  (causal, split-K=2, dual-A partial combine;
            // slab1 fp32 at qr+12.6MB; flat 384, XCD-pinned (h,seg))
            long segZ = (long)(ykvP1 - ykv);
            mfma_gemm<bf16, 1><<<dim3(384), 256, 0, stream>>>(
                sc, xT, ykv, dbuf, T_SEQ, 0, T_SEQ, T_SEQ, D_DIM,
                (long)T_SEQ * T_SEQ, segZ, (long)T_SEQ * D_DIM);
            // fused: ymlp slabs = (xs ⊙ relu(LN(slab0+slab1) @ decY)) @ enc
            gate_ymlp<<<dim3(256), 256, 0, stream>>>(ykv, ykvP1, wY, xs, wE, ymlpP16);
            // x = LN(x + LN(sum partials)); xb + xT refreshed
            k_resid<16><<<T_SEQ, 64, 0, stream>>>(x, ymlpP16, xb, xT);
        } else {
            dgemm128<1, false, bf16><<<dim3(96, 8), 256, 0, stream>>>(xb, wX, xs, qr, csT);
            scores_fused<<<dim3(16, 16, NHEAD), 256, 0, stream>>>(xs, csT, sc);
            mfma_gemm<bf16, 3><<<dim3(3, 16, NHEAD), 256, 0, stream>>>(
                sc, xT, ykv, nullptr, T_SEQ, 0, T_SEQ, T_SEQ, D_DIM,
                (long)T_SEQ * T_SEQ, 0L, (long)T_SEQ * D_DIM);
            k_ln<<<NHEAD * T_SEQ, 64, 0, stream>>>(ykv);
            dgemm128<2, false, float><<<dim3(96, 8), 256, 0, stream>>>(
                ykv, wY, xs, nullptr, nullptr);
            mfma_gemm<bf16, 2><<<dim3(3, 16, 8), 256, 0, stream>>>(
                xs, wE, ymlpP8, nullptr, HN, HN / 8, HN, HN, D_DIM,
                0L, 0L, (long)T_SEQ * D_DIM);
            k_resid<8><<<T_SEQ, 64, 0, stream>>>(x, ymlpP8, xb, xT);
        }
    }

    // logits = x @ lm_head
    mfma_gemm<float, 0><<<dim3(4, 16, 1), 256, 0, stream>>>(
        x, wL, out, nullptr, D_DIM, 0, D_DIM, D_DIM, VOCABSZ, 0L, 0L, 0L);
}

// Round 14
// 441.646 us; speedup vs baseline: 1.1756x; 1.0097x over previous
//
#include <hip/hip_runtime.h>
#include <hip/hip_bf16.h>

using bf16 = __hip_bfloat16;

#define D_DIM   192
#define N_DIM   3072
#define NHEAD   4
#define T_SEQ   1024
#define HN      12288      // NHEAD * N_DIM
#define NP2     1536       // N_DIM/2
#define VOCABSZ 256
#define NLAYER  4
#define LN_EPS  1e-5f
#define TWO_PI  6.2831853071795864f

typedef __attribute__((ext_vector_type(8)))  short          s16x8;
typedef __attribute__((ext_vector_type(8)))  unsigned short u16x8;
typedef __attribute__((ext_vector_type(4)))  float          f32x4;
typedef __attribute__((ext_vector_type(16))) float          f32x16;

__device__ __forceinline__ float b2f(bf16 v) { return __bfloat162float(v); }
__device__ __forceinline__ float us2f(unsigned short u) {
    unsigned int x = ((unsigned int)u) << 16;
    return __builtin_bit_cast(float, x);
}
__device__ __forceinline__ unsigned short f2us(float f) {
    bf16 b = __float2bfloat16(f);
    return __builtin_bit_cast(unsigned short, b);
}

// sentinel: encode ws_size into output (fires only if ws too small)
__global__ void fill_out(float* __restrict__ out, float val, int nelem) {
    int i = blockIdx.x * 256 + threadIdx.x;
    if (i < nelem) out[i] = val;
}

// ---------------------------------------------------------------------------
// Tiled transpose + fp32->bf16: in fp32 [R][C] -> out bf16 [C][R].
// (setup-only: weight mirrors)
// ---------------------------------------------------------------------------
__global__ void t_cvt(const float* __restrict__ in, bf16* __restrict__ out,
                      int R, int C, long inZ, long outZ) {
    __shared__ float tile[64][65];
    in  += inZ  * blockIdx.z;
    out += outZ * blockIdx.z;
    const int tx = threadIdx.x & 63, ty = threadIdx.x >> 6;
    const int r0 = blockIdx.y * 64, c0 = blockIdx.x * 64;
    #pragma unroll
    for (int rr = 0; rr < 16; rr++) {
        int row = ty * 16 + rr;
        tile[row][tx] = in[(size_t)(r0 + row) * C + c0 + tx];
    }
    __syncthreads();
    #pragma unroll
    for (int rr = 0; rr < 16; rr++) {
        int row = ty * 16 + rr;
        out[(size_t)(c0 + row) * R + r0 + tx] = __float2bfloat16(tile[tx][row]);
    }
}

// ---------------------------------------------------------------------------
// Wave-per-row LN family (64 threads/block, 3 elems/lane, butterfly reduce)
// ---------------------------------------------------------------------------
__device__ __forceinline__ void wave_sum2(float& s, float& ss) {
    #pragma unroll
    for (int off = 1; off < 64; off <<= 1) {
        s  += __shfl_xor(s,  off, 64);
        ss += __shfl_xor(ss, off, 64);
    }
}

// writes fp32 x, bf16 xb, AND transposed bf16 xT[d][t]
__global__ void k_embed(const int* __restrict__ idx, const float* __restrict__ emb,
                        const float* __restrict__ pos, float* __restrict__ x,
                        bf16* __restrict__ xb, bf16* __restrict__ xT) {
    int t = blockIdx.x, l = threadIdx.x;
    int tok = idx[t];
    const float* e = emb + tok * D_DIM;
    const float* p = pos + t * D_DIM;
    float v0 = e[l] + p[l], v1 = e[l + 64] + p[l + 64], v2 = e[l + 128] + p[l + 128];
    float s = v0 + v1 + v2, ss = v0 * v0 + v1 * v1 + v2 * v2;
    wave_sum2(s, ss);
    float m = s / D_DIM, r = rsqrtf(ss / D_DIM - m * m + LN_EPS);
    float* xr = x + t * D_DIM;
    bf16*  xo = xb + (size_t)t * D_DIM;
    float o0 = (v0 - m) * r, o1 = (v1 - m) * r, o2 = (v2 - m) * r;
    xr[l] = o0; xr[l + 64] = o1; xr[l + 128] = o2;
    bf16 b0 = __float2bfloat16(o0), b1 = __float2bfloat16(o1), b2 = __float2bfloat16(o2);
    xo[l] = b0; xo[l + 64] = b1; xo[l + 128] = b2;
    bf16* col = xT + t;
    col[(size_t)l * T_SEQ]         = b0;
    col[(size_t)(l + 64) * T_SEQ]  = b1;
    col[(size_t)(l + 128) * T_SEQ] = b2;
}

__global__ void k_ln(float* __restrict__ buf) {
    int l = threadIdx.x;
    float* row = buf + (size_t)blockIdx.x * D_DIM;
    float v0 = row[l], v1 = row[l + 64], v2 = row[l + 128];
    float s = v0 + v1 + v2, ss = v0 * v0 + v1 * v1 + v2 * v2;
    wave_sum2(s, ss);
    float m = s / D_DIM, r = rsqrtf(ss / D_DIM - m * m + LN_EPS);
    row[l] = (v0 - m) * r; row[l + 64] = (v1 - m) * r; row[l + 128] = (v2 - m) * r;
}

// x = LN(x + LN(sum of NSLAB split-K partial slabs)); writes xb + xT too
template <int NSLAB>
__global__ void k_resid(float* __restrict__ x, const float* __restrict__ P,
                        bf16* __restrict__ xb, bf16* __restrict__ xT) {
    int l = threadIdx.x, t = blockIdx.x;
    float y0 = 0.f, y1 = 0.f, y2 = 0.f;
    #pragma unroll
    for (int p = 0; p < NSLAB; p++) {
        const float* r = P + (size_t)p * T_SEQ * D_DIM + (size_t)t * D_DIM;
        y0 += r[l]; y1 += r[l + 64]; y2 += r[l + 128];
    }
    float* xr = x + (size_t)t * D_DIM;
    float s = y0 + y1 + y2, ss = y0 * y0 + y1 * y1 + y2 * y2;
    wave_sum2(s, ss);
    float m1 = s / D_DIM, r1 = rsqrtf(ss / D_DIM - m1 * m1 + LN_EPS);
    float v0 = xr[l] + (y0 - m1) * r1;
    float v1 = xr[l + 64] + (y1 - m1) * r1;
    float v2 = xr[l + 128] + (y2 - m1) * r1;
    s = v0 + v1 + v2; ss = v0 * v0 + v1 * v1 + v2 * v2;
    wave_sum2(s, ss);
    float m2 = s / D_DIM, r2 = rsqrtf(ss / D_DIM - m2 * m2 + LN_EPS);
    float o0 = (v0 - m2) * r2, o1 = (v1 - m2) * r2, o2 = (v2 - m2) * r2;
    xr[l] = o0; xr[l + 64] = o1; xr[l + 128] = o2;
    bf16 b0 = __float2bfloat16(o0), b1 = __float2bfloat16(o1), b2 = __float2bfloat16(o2);
    bf16* xo = xb + (size_t)t * D_DIM;
    xo[l] = b0; xo[l + 64] = b1; xo[l + 128] = b2;
    bf16* col = xT + t;
    col[(size_t)l * T_SEQ]         = b0;
    col[(size_t)(l + 64) * T_SEQ]  = b1;
    col[(size_t)(l + 128) * T_SEQ] = b2;
}

// RoPE cos/sin tables, interleaved bf16 pairs csT[t][p] = (cos, sin)
__global__ void k_tables(ushort2* __restrict__ csT) {
    int gid = blockIdx.x * 256 + threadIdx.x;
    int t = gid / NP2, p = gid % NP2;
    float qf = (float)(2 * p);
    float f = exp2f(qf * (-16.0f / 3072.0f)) * (1.0f / (float)TWO_PI);
    float ph = fmodf((float)t * f, 1.0f) * (float)TWO_PI;
    ushort2 cs;
    cs.x = f2us(cosf(ph));
    cs.y = f2us(sinf(ph));
    csT[gid] = cs;
}

// ---------------------------------------------------------------------------
// scores64: partial scores, split-K=2, FLAT 1-D grid of 1088 with XCD
// pinning: xcd = bid&7 -> (h = xcd>>1, kh = xcd&1), L = bid>>3.
// 64x64 tile, 4 waves x one 32x32x16 MFMA acc, BK=64, double-buffered LDS +
// 2-deep register prefetch, LDS-staged coalesced epilogue.
// ---------------------------------------------------------------------------
__launch_bounds__(256, 4)
__global__ void scores64(const bf16* __restrict__ qr, bf16* __restrict__ sc,
                         bf16* __restrict__ dbuf) {
    const int bid = blockIdx.x;
    const int xcd = bid & 7;
    const int h   = xcd >> 1;
    const int kh  = xcd & 1;
    const int L   = bid >> 3;                      // 0..135, in-order per XCD
    int i = 0;
    while (((i + 1) * (i + 2)) >> 1 <= L) ++i;
    int j = L - ((i * (i + 1)) >> 1);
    const int t0 = i * 64, s0 = j * 64;
    const bool diag = (i == j);

    int arow = t0, brow = s0;
    if (kh == 1 && !diag) { arow = s0; brow = t0; }

    __shared__ short As[2][64][72];
    __shared__ short Bs[2][64][72];

    const int tid = threadIdx.x;
    const int lane = tid & 63, w = tid >> 6;
    const int wtm = (w >> 1) * 32, wtn = (w & 1) * 32;
    const int l31 = lane & 31, lhi = lane >> 5;
    const int r0 = tid >> 2;
    const int kq = (tid & 3) * 16;

    const int kBeg = kh * (N_DIM / 2);
    const bf16* gA = qr + (size_t)(arow + r0) * HN + h * N_DIM + kBeg + kq;
    const bf16* gB = qr + (size_t)(brow + r0) * HN + h * N_DIM + kBeg + kq;

    u16x8 pa0, pa1, pb0, pb1;
    u16x8 qa0, qa1, qb0, qb1;
    auto load0 = [&](int k0) {
        pa0 = *(const u16x8*)(gA + k0);
        pa1 = *(const u16x8*)(gA + k0 + 8);
        pb0 = *(const u16x8*)(gB + k0);
        pb1 = *(const u16x8*)(gB + k0 + 8);
    };
    auto load1 = [&](int k0) {
        qa0 = *(const u16x8*)(gA + k0);
        qa1 = *(const u16x8*)(gA + k0 + 8);
        qb0 = *(const u16x8*)(gB + k0);
        qb1 = *(const u16x8*)(gB + k0 + 8);
    };
    auto dep0 = [&](int buf) {
        *(u16x8*)&As[buf][r0][kq]     = pa0;
        *(u16x8*)&As[buf][r0][kq + 8] = pa1;
        *(u16x8*)&Bs[buf][r0][kq]     = pb0;
        *(u16x8*)&Bs[buf][r0][kq + 8] = pb1;
    };
    auto dep1 = [&](int buf) {
        *(u16x8*)&As[buf][r0][kq]     = qa0;
        *(u16x8*)&As[buf][r0][kq + 8] = qa1;
        *(u16x8*)&Bs[buf][r0][kq]     = qb0;
        *(u16x8*)&Bs[buf][r0][kq + 8] = qb1;
    };

    f32x16 acc;
    #pragma unroll
    for (int r = 0; r < 16; r++) acc[r] = 0.f;

    auto mfma_step = [&](int buf) {
        #pragma unroll
        for (int ks = 0; ks < 4; ks++) {
            s16x8 a = *(const s16x8*)&As[buf][wtm + l31][ks * 16 + lhi * 8];
            s16x8 b = *(const s16x8*)&Bs[buf][wtn + l31][ks * 16 + lhi * 8];
            acc = __builtin_amdgcn_mfma_f32_32x32x16_bf16(a, b, acc, 0, 0, 0);
        }
    };

    const int NIT = (N_DIM / 2) / 64;   // 24 (even)
    load0(0);
    load1(64);
    dep0(0);
    __syncthreads();

    for (int k = 0; k < NIT; k += 2) {
        if (k + 2 < NIT) load0((k + 2) * 64);
        mfma_step(0);
        if (k + 1 < NIT) dep1(1);
        __syncthreads();
        if (k + 1 < NIT) {
            if (k + 3 < NIT) load1((k + 3) * 64);
            mfma_step(1);
            if (k + 2 < NIT) dep0(0);
            __syncthreads();
        }
    }

    __syncthreads();
    short (*S)[72] = (short(*)[72])&As[0][0][0];
    const bool trS = (kh == 1) && !diag;
    #pragma unroll
    for (int r = 0; r < 16; r++) {
        int rr = wtm + (r & 3) + 8 * (r >> 2) + 4 * lhi;
        int cc = wtn + l31;
        float v = acc[r];
        if (diag && cc >= rr) v = 0.f;
        if (trS) S[cc][rr] = (short)f2us(v);
        else     S[rr][cc] = (short)f2us(v);
    }
    __syncthreads();
    if (kh == 1 && diag) {
        bf16* P = dbuf + (size_t)(h * 16 + i) * 4096;
        #pragma unroll
        for (int e = 0; e < 2; e++) {
            int idxe = tid + e * 256;
            int row = idxe >> 3, cg = (idxe & 7) * 8;
            u16x8 v = *(const u16x8*)&S[row][cg];
            *(u16x8*)(P + row * 64 + cg) = v;
        }
    } else {
        bf16* C = sc + (size_t)h * T_SEQ * T_SEQ;
        #pragma unroll
        for (int e = 0; e < 2; e++) {
            int idxe = tid + e * 256;
            int row = idxe >> 3, cg = (idxe & 7) * 8;
            u16x8 v = *(const u16x8*)&S[row][cg];
            *(u16x8*)(C + (size_t)(arow + row) * T_SEQ + brow + cg) = v;
        }
    }
}

// ---------------------------------------------------------------------------
// scores fallback (no qr buffer): 64x64, rope fused into staging.
// ---------------------------------------------------------------------------
__device__ __forceinline__ void stage_rope8(short* dst, const bf16* src,
                                            const ushort2* csP) {
    u16x8 v  = *(const u16x8*)src;
    u16x8 cs = *(const u16x8*)csP;
    u16x8 o;
    #pragma unroll
    for (int i = 0; i < 4; i++) {
        float e  = us2f(v[2 * i]), od = us2f(v[2 * i + 1]);
        float c  = us2f(cs[2 * i]), s = us2f(cs[2 * i + 1]);
        o[2 * i]     = f2us(e * c - od * s);
        o[2 * i + 1] = f2us(od * c + e * s);
    }
    *(u16x8*)dst = o;
}

__launch_bounds__(256)
__global__ void scores_fused(const bf16* __restrict__ xs,
                             const ushort2* __restrict__ csT,
                             bf16* __restrict__ sc) {
    const int h  = blockIdx.z;
    const int s0 = blockIdx.x * 64, t0 = blockIdx.y * 64;
    if (s0 > t0) return;
    __shared__ short As[64][40];
    __shared__ short Bs[64][40];
    const int tid  = threadIdx.x;
    const int srow = tid >> 2, kq = (tid & 3) * 8;
    const int lane = tid & 63, w = tid >> 6, qd = lane >> 4, lc = lane & 15;
    const int tA = t0 + srow, tB = s0 + srow;
    const bf16* gA = xs + (size_t)tA * HN + h * N_DIM + kq;
    const bf16* gB = xs + (size_t)tB * HN + h * N_DIM + kq;
    const ushort2* cA = csT + (size_t)tA * NP2 + (kq >> 1);
    const ushort2* cB = csT + (size_t)tB * NP2 + (kq >> 1);
    f32x4 acc[4] = {{0.f,0.f,0.f,0.f},{0.f,0.f,0.f,0.f},
                    {0.f,0.f,0.f,0.f},{0.f,0.f,0.f,0.f}};
    for (int k0 = 0; k0 < N_DIM; k0 += 32) {
        stage_rope8(&As[srow][kq], gA + k0, cA + (k0 >> 1));
        stage_rope8(&Bs[srow][kq], gB + k0, cB + (k0 >> 1));
        __syncthreads();
        s16x8 a = *(const s16x8*)&As[w * 16 + lc][qd * 8];
        #pragma unroll
        for (int j = 0; j < 4; j++) {
            s16x8 b = *(const s16x8*)&Bs[j * 16 + lc][qd * 8];
            acc[j] = __builtin_amdgcn_mfma_f32_16x16x32_bf16(a, b, acc[j], 0, 0, 0);
        }
        __syncthreads();
    }
    bf16* C = sc + (size_t)h * T_SEQ * T_SEQ;
    const bool diag = (s0 == t0);
    const int tbase = t0 + w * 16 + qd * 4;
    #pragma unroll
    for (int j = 0; j < 4; j++) {
        int s = s0 + j * 16 + lc;
        #pragma unroll
        for (int r = 0; r < 4; r++) {
            int t = tbase + r;
            C[(size_t)t * T_SEQ + s] =
                __float2bfloat16((!diag || s < t) ? acc[j][r] : 0.f);
        }
    }
}

// ---------------------------------------------------------------------------
// dgemm128: 128x128 tile, 4 waves x (64x64 = 2x2 of 32x32x16 MFMA accs),
// K=192 (BK=32), double-buffered LDS + 2-deep register prefetch, LDS-staged
// coalesced epilogue (relu / rope / gate). TA = bf16 or float.
// ---------------------------------------------------------------------------
template <int EPI, bool WQR, typename TA>
__launch_bounds__(256)
__global__ void dgemm128(const TA* __restrict__ A, const bf16* __restrict__ Bt,
                         bf16* __restrict__ xs, bf16* __restrict__ qr,
                         const ushort2* __restrict__ csT) {
    __shared__ __align__(16) short pool[2 * 2 * 128 * 40];   // 40 KB
    short (*As)[128][40] = (short(*)[128][40])pool;
    short (*Bs)[128][40] = (short(*)[128][40])(pool + 2 * 128 * 40);

    const int tid = threadIdx.x;
    const int lane = tid & 63, w = tid >> 6;
    const int l31 = lane & 31, lhi = lane >> 5;
    const int wtm = (w >> 1) * 64, wtn = (w & 1) * 64;
    const int n0 = blockIdx.x * 128, m0 = blockIdx.y * 128;
    if constexpr (EPI == 2) A += (size_t)(n0 / N_DIM) * T_SEQ * D_DIM;

    const int r0 = tid >> 2, r1 = r0 + 64;
    const int kq = (tid & 3) * 8;

    const TA*   gA = A  + kq;
    const bf16* gB = Bt + kq;

    float4 fa00, fa01, fa02, fa03, fa10, fa11, fa12, fa13;
    u16x8 ba00, ba01, ba10, ba11;
    u16x8 pb00, pb01, pb10, pb11;
    auto load0 = [&](int k0) {
        if constexpr (__is_same(TA, float)) {
            const TA* a0 = gA + (size_t)(m0 + r0) * D_DIM + k0;
            const TA* a1 = gA + (size_t)(m0 + r1) * D_DIM + k0;
            fa00 = *(const float4*)a0; fa01 = *(const float4*)(a0 + 4);
            fa02 = *(const float4*)a1; fa03 = *(const float4*)(a1 + 4);
        } else {
            ba00 = *(const u16x8*)(gA + (size_t)(m0 + r0) * D_DIM + k0);
            ba01 = *(const u16x8*)(gA + (size_t)(m0 + r1) * D_DIM + k0);
        }
        pb00 = *(const u16x8*)(gB + (size_t)(n0 + r0) * D_DIM + k0);
        pb01 = *(const u16x8*)(gB + (size_t)(n0 + r1) * D_DIM + k0);
    };
    auto load1 = [&](int k0) {
        if constexpr (__is_same(TA, float)) {
            const TA* a0 = gA + (size_t)(m0 + r0) * D_DIM + k0;
            const TA* a1 = gA + (size_t)(m0 + r1) * D_DIM + k0;
            fa10 = *(const float4*)a0; fa11 = *(const float4*)(a0 + 4);
            fa12 = *(const float4*)a1; fa13 = *(const float4*)(a1 + 4);
        } else {
            ba10 = *(const u16x8*)(gA + (size_t)(m0 + r0) * D_DIM + k0);
            ba11 = *(const u16x8*)(gA + (size_t)(m0 + r1) * D_DIM + k0);
        }
        pb10 = *(const u16x8*)(gB + (size_t)(n0 + r0) * D_DIM + k0);
        pb11 = *(const u16x8*)(gB + (size_t)(n0 + r1) * D_DIM + k0);
    };
    auto dep0 = [&](int buf) {
        if constexpr (__is_same(TA, float)) {
            u16x8 o0, o1;
            o0[0] = f2us(fa00.x); o0[1] = f2us(fa00.y); o0[2] = f2us(fa00.z); o0[3] = f2us(fa00.w);
            o0[4] = f2us(fa01.x); o0[5] = f2us(fa01.y); o0[6] = f2us(fa01.z); o0[7] = f2us(fa01.w);
            o1[0] = f2us(fa02.x); o1[1] = f2us(fa02.y); o1[2] = f2us(fa02.z); o1[3] = f2us(fa02.w);
            o1[4] = f2us(fa03.x); o1[5] = f2us(fa03.y); o1[6] = f2us(fa03.z); o1[7] = f2us(fa03.w);
            *(u16x8*)&As[buf][r0][kq] = o0;
            *(u16x8*)&As[buf][r1][kq] = o1;
        } else {
            *(u16x8*)&As[buf][r0][kq] = ba00;
            *(u16x8*)&As[buf][r1][kq] = ba01;
        }
        *(u16x8*)&Bs[buf][r0][kq] = pb00;
        *(u16x8*)&Bs[buf][r1][kq] = pb01;
    };
    auto dep1 = [&](int buf) {
        if constexpr (__is_same(TA, float)) {
            u16x8 o0, o1;
            o0[0] = f2us(fa10.x); o0[1] = f2us(fa10.y); o0[2] = f2us(fa10.z); o0[3] = f2us(fa10.w);
            o0[4] = f2us(fa11.x); o0[5] = f2us(fa11.y); o0[6] = f2us(fa11.z); o0[7] = f2us(fa11.w);
            o1[0] = f2us(fa12.x); o1[1] = f2us(fa12.y); o1[2] = f2us(fa12.z); o1[3] = f2us(fa12.w);
            o1[4] = f2us(fa13.x); o1[5] = f2us(fa13.y); o1[6] = f2us(fa13.z); o1[7] = f2us(fa13.w);
            *(u16x8*)&As[buf][r0][kq] = o0;
            *(u16x8*)&As[buf][r1][kq] = o1;
        } else {
            *(u16x8*)&As[buf][r0][kq] = ba10;
            *(u16x8*)&As[buf][r1][kq] = ba11;
        }
        *(u16x8*)&Bs[buf][r0][kq] = pb10;
        *(u16x8*)&Bs[buf][r1][kq] = pb11;
    };

    f32x16 acc00, acc01, acc10, acc11;
    #pragma unroll
    for (int r = 0; r < 16; r++) { acc00[r] = 0.f; acc01[r] = 0.f; acc10[r] = 0.f; acc11[r] = 0.f; }

    auto mfma_step = [&](int buf) {
        #pragma unroll
        for (int ks = 0; ks < 2; ks++) {
            s16x8 a0 = *(const s16x8*)&As[buf][wtm + l31][ks * 16 + lhi * 8];
            s16x8 a1 = *(const s16x8*)&As[buf][wtm + 32 + l31][ks * 16 + lhi * 8];
            s16x8 b0 = *(const s16x8*)&Bs[buf][wtn + l31][ks * 16 + lhi * 8];
            s16x8 b1 = *(const s16x8*)&Bs[buf][wtn + 32 + l31][ks * 16 + lhi * 8];
            acc00 = __builtin_amdgcn_mfma_f32_32x32x16_bf16(a0, b0, acc00, 0, 0, 0);
            acc01 = __builtin_amdgcn_mfma_f32_32x32x16_bf16(a0, b1, acc01, 0, 0, 0);
            acc10 = __builtin_amdgcn_mfma_f32_32x32x16_bf16(a1, b0, acc10, 0, 0, 0);
            acc11 = __builtin_amdgcn_mfma_f32_32x32x16_bf16(a1, b1, acc11, 0, 0, 0);
        }
    };

    const int NIT = D_DIM / 32;   // 6 (even)
    load0(0);
    load1(32);
    dep0(0);
    __syncthreads();
    for (int k = 0; k < NIT; k += 2) {
        if (k + 2 < NIT) load0((k + 2) * 32);
        mfma_step(0);
        if (k + 1 < NIT) dep1(1);
        __syncthreads();
        if (k + 1 < NIT) {
            if (k + 3 < NIT) load1((k + 3) * 32);
            mfma_step(1);
            if (k + 2 < NIT) dep0(0);
            __syncthreads();
        }
    }

    // -------- LDS-staged epilogue --------
    short (*S)[136] = (short(*)[136])pool; // 128 x 136 shorts = 34.8 KB <= 40 KB
    #pragma unroll
    for (int r = 0; r < 16; r++) {
        int rb = (r & 3) + 8 * (r >> 2) + 4 * lhi;
        S[wtm + rb     ][wtn + l31     ] = (short)f2us(fmaxf(acc00[r], 0.f));
        S[wtm + rb     ][wtn + 32 + l31] = (short)f2us(fmaxf(acc01[r], 0.f));
        S[wtm + 32 + rb][wtn + l31     ] = (short)f2us(fmaxf(acc10[r], 0.f));
        S[wtm + 32 + rb][wtn + 32 + l31] = (short)f2us(fmaxf(acc11[r], 0.f));
    }
    __syncthreads();
    #pragma unroll
    for (int e = 0; e < 8; e++) {
        int idxe = tid + e * 256;
        int row = idxe >> 4, cg = idxe & 15;
        u16x8 v = *(const u16x8*)&S[row][cg * 8];
        int t = m0 + row, ngg = n0 + cg * 8;
        size_t ci = (size_t)t * HN + ngg;
        if constexpr (EPI == 1) {
            *(u16x8*)(xs + ci) = v;
            if constexpr (WQR) {
                int p0 = (ngg % N_DIM) >> 1;
                u16x8 cs8 = *(const u16x8*)&csT[(size_t)t * NP2 + p0];
                u16x8 o;
                #pragma unroll
                for (int q = 0; q < 4; q++) {
                    float ev = us2f(v[2 * q]), ov = us2f(v[2 * q + 1]);
                    float c = us2f(cs8[2 * q]), s = us2f(cs8[2 * q + 1]);
                    o[2 * q]     = f2us(ev * c - ov * s);
                    o[2 * q + 1] = f2us(ov * c + ev * s);
                }
                *(u16x8*)(qr + ci) = o;
            }
        } else {
            u16x8 g = *(const u16x8*)(xs + ci);
            u16x8 o;
            #pragma unroll
            for (int q = 0; q < 8; q++) o[q] = f2us(us2f(g[q]) * us2f(v[q]));
            *(u16x8*)(xs + ci) = o;
        }
    }
}

// ---------------------------------------------------------------------------
// gate_ymlp: fused  ymlp_slab = (xs ⊙ relu(LN(ykv0+ykv1) @ decY)) @ enc.
// LN slab-combine fused in prologue. T14 register prefetch of all staged
// operands. THIS ROUND: (1) stage1 uses 2-way k-split accumulators (halves
// the 12-MFMA serial dependency chain — only 2 waves/SIMD here); (2) relu
// and the xs gate are fused into the xyA scatter (xs prefetched in fragment
// layout) — removes the RMW LDS pass and one barrier per chunk (5 -> 4).
// FLAT grid of 256 with XCD pinning: s = (bid&7) + 8*(bid>>7), tb=(bid>>3)&15.
// ---------------------------------------------------------------------------
__launch_bounds__(256, 2)
__global__ void gate_ymlp(const float* __restrict__ ykv0, const float* __restrict__ ykv1,
                          const bf16* __restrict__ wY,
                          const bf16* __restrict__ xs, const bf16* __restrict__ wE,
                          float* __restrict__ P) {
    const int bid = blockIdx.x;
    const int s   = (bid & 7) + ((bid >> 7) << 3);   // 0..15, pinned by XCD
    const int tb  = (bid >> 3) & 15;                 // 0..15
    const int t0  = tb * 64;
    const int h   = s >> 2;               // 4 segments of 768 per head
    const int ng0 = s * 768;              // global n base of this slab
    const int nh0 = (s & 3) * 768;        // within-head n base

    __shared__ __align__(16) short A1s[64][200];   // LN(ykv) tile (25.6 KB)
    __shared__ __align__(16) short Bsh[192][72];   // B2 view      (27.6 KB)
    __shared__ __align__(16) short xyA[64][72];    // xy chunk     ( 9.2 KB)
    short (*B1)[200] = (short(*)[200])&Bsh[0][0];  // B1 overlays B2 (12800<=13824)

    const int tid = threadIdx.x;
    const int lane = tid & 63, w = tid >> 6;
    const int l31 = lane & 31, lhi = lane >> 5;
    const int wm  = (w >> 1) * 32;        // t-offset of wave
    const int wn1 = (w & 1) * 32;         // n-offset (stage1)
    const int wn2 = (w & 1) * 96;         // d-offset (stage2)

    const int srow = tid >> 2, sq = tid & 3;   // staging row / quarter

    // ---- register prefetch sets (all statically indexed after unroll) ----
    u16x8 rb[6];            // next B1 chunk (wY rows)
    u16x8 re[6];            // this chunk's B2 (wE rows)
    unsigned short rxf[16]; // this chunk's xs in FRAGMENT layout
    auto ldB1 = [&](int c) {
        const bf16* src = wY + ((size_t)h * N_DIM + nh0 + c * 64 + srow) * D_DIM
                        + sq * 48;
        #pragma unroll
        for (int jj = 0; jj < 6; jj++) rb[jj] = *(const u16x8*)(src + jj * 8);
    };
    auto depB1 = [&]() {
        #pragma unroll
        for (int jj = 0; jj < 6; jj++)
            *(u16x8*)&B1[srow][sq * 48 + jj * 8] = rb[jj];
    };
    auto ldB2 = [&](int c) {
        #pragma unroll
        for (int jj = 0; jj < 3; jj++) {
            int d  = srow * 3 + jj;               // 0..191
            const bf16* src = wE + (size_t)d * HN + ng0 + c * 64 + sq * 16;
            re[2 * jj]     = *(const u16x8*)src;
            re[2 * jj + 1] = *(const u16x8*)(src + 8);
        }
    };
    auto depB2 = [&]() {
        #pragma unroll
        for (int jj = 0; jj < 3; jj++) {
            int d  = srow * 3 + jj;
            *(u16x8*)&Bsh[d][sq * 16]     = re[2 * jj];
            *(u16x8*)&Bsh[d][sq * 16 + 8] = re[2 * jj + 1];
        }
    };
    auto ldXSf = [&](int c) {
        #pragma unroll
        for (int r = 0; r < 16; r++) {
            int rr = wm + (r & 3) + 8 * (r >> 2) + 4 * lhi;
            rxf[r] = *(const unsigned short*)
                     (xs + (size_t)(t0 + rr) * HN + ng0 + c * 64 + wn1 + l31);
        }
    };

    // ---- fused slab-combine + LN + bf16 -> A1s ----
    {
        size_t off = ((size_t)h * T_SEQ + t0 + srow) * D_DIM + sq * 48;
        const float* p0 = ykv0 + off;
        const float* p1 = ykv1 + off;
        float v[48];
        float sm = 0.f, ssq = 0.f;
        #pragma unroll
        for (int e = 0; e < 12; e++) {
            float4 a = *(const float4*)(p0 + e * 4);
            float4 b = *(const float4*)(p1 + e * 4);
            float c0 = a.x + b.x, c1 = a.y + b.y, c2 = a.z + b.z, c3 = a.w + b.w;
            v[e * 4 + 0] = c0; v[e * 4 + 1] = c1; v[e * 4 + 2] = c2; v[e * 4 + 3] = c3;
            sm  += c0 + c1 + c2 + c3;
            ssq += c0 * c0 + c1 * c1 + c2 * c2 + c3 * c3;
        }
        sm  += __shfl_xor(sm, 1, 64);  ssq += __shfl_xor(ssq, 1, 64);
        sm  += __shfl_xor(sm, 2, 64);  ssq += __shfl_xor(ssq, 2, 64);
        float m = sm / D_DIM, r = rsqrtf(ssq / D_DIM - m * m + LN_EPS);
        #pragma unroll
        for (int e = 0; e < 6; e++) {
            u16x8 o;
            #pragma unroll
            for (int k2 = 0; k2 < 8; k2++) o[k2] = f2us((v[e * 8 + k2] - m) * r);
            *(u16x8*)&A1s[srow][sq * 48 + e * 8] = o;
        }
    }

    f32x16 oc0, oc1, oc2;
    #pragma unroll
    for (int r = 0; r < 16; r++) { oc0[r] = 0.f; oc1[r] = 0.f; oc2[r] = 0.f; }

    ldB1(0);                               // B1(0) in flight over the barrier
    __syncthreads();

    for (int c = 0; c < 12; c++) {
        ldXSf(c);                          // consumed at scatter (1 stage away)
        ldB2(c);                           // consumed at stage2 (2 stages away)
        depB1();                           // B1(c) regs -> LDS
        __syncthreads();                   // bar 1
        if (c + 1 < 12) ldB1(c + 1);       // in flight across stage1..stage2
        // stage1: ys(64x64) over K=192 — 2-way k-split accumulators
        f32x16 ysA, ysB;
        #pragma unroll
        for (int r = 0; r < 16; r++) { ysA[r] = 0.f; ysB[r] = 0.f; }
        #pragma unroll
        for (int ks = 0; ks < 6; ks++) {
            s16x8 aA = *(const s16x8*)&A1s[wm + l31][ks * 16 + lhi * 8];
            s16x8 bA = *(const s16x8*)&B1[wn1 + l31][ks * 16 + lhi * 8];
            ysA = __builtin_amdgcn_mfma_f32_32x32x16_bf16(aA, bA, ysA, 0, 0, 0);
            s16x8 aB = *(const s16x8*)&A1s[wm + l31][(ks + 6) * 16 + lhi * 8];
            s16x8 bB = *(const s16x8*)&B1[wn1 + l31][(ks + 6) * 16 + lhi * 8];
            ysB = __builtin_amdgcn_mfma_f32_32x32x16_bf16(aB, bB, ysB, 0, 0, 0);
        }
        __syncthreads();                   // bar 2: B1 consumed, prev xyA consumed
        // fused scatter: xyA = xs * relu(ys)  (no RMW pass, no extra barrier)
        #pragma unroll
        for (int r = 0; r < 16; r++) {
            int rr = wm + (r & 3) + 8 * (r >> 2) + 4 * lhi;
            float prod = fmaxf(ysA[r] + ysB[r], 0.f) * us2f(rxf[r]);
            xyA[rr][wn1 + l31] = (short)f2us(prod);
        }
        depB2();                           // B2(c) regs -> Bsh (B1 dead)
        __syncthreads();                   // bar 3: xyA + Bsh visible
        // stage2: out += xyA(64x64) @ wE-chunk^T(192x64), K=64
        #pragma unroll
        for (int ks = 0; ks < 4; ks++) {
            s16x8 a  = *(const s16x8*)&xyA[wm + l31][ks * 16 + lhi * 8];
            s16x8 b0 = *(const s16x8*)&Bsh[wn2 + l31     ][ks * 16 + lhi * 8];
            s16x8 b1 = *(const s16x8*)&Bsh[wn2 + 32 + l31][ks * 16 + lhi * 8];
            s16x8 b2 = *(const s16x8*)&Bsh[wn2 + 64 + l31][ks * 16 + lhi * 8];
            oc0 = __builtin_amdgcn_mfma_f32_32x32x16_bf16(a, b0, oc0, 0, 0, 0);
            oc1 = __builtin_amdgcn_mfma_f32_32x32x16_bf16(a, b1, oc1, 0, 0, 0);
            oc2 = __builtin_amdgcn_mfma_f32_32x32x16_bf16(a, b2, oc2, 0, 0, 0);
        }
        __syncthreads();                   // bar 4: before next depB1/xyA writes
    }

    // write slab P[s][t][d]
    float* O = P + (size_t)s * T_SEQ * D_DIM;
    #pragma unroll
    for (int r = 0; r < 16; r++) {
        int rt = t0 + wm + (r & 3) + 8 * (r >> 2) + 4 * lhi;
        O[(size_t)rt * D_DIM + wn2 +      l31] = oc0[r];
        O[(size_t)rt * D_DIM + wn2 + 32 + l31] = oc1[r];
        O[(size_t)rt * D_DIM + wn2 + 64 + l31] = oc2[r];
    }
}

// ---------------------------------------------------------------------------
// mfma_gemm (64x64): MODE 0 = plain, 1 = causal split-K=2 WITH dual-A partial
// combine AND flat-grid XCD pinning (bid&7 = z = head*2+seg), 2 = split-K
// slabs over z (fallback ymlp), 3 = causal full (fallback). 32x32x16 MFMA,
// BK=64, double-buffered LDS + 2-deep prefetch. THIS ROUND: DUAL uses
// separate accumulators for the A-stream and mirror-stream (halves the
// 8-MFMA serial chain at 2 waves/SIMD), summed in fp32 at the epilogue.
// ---------------------------------------------------------------------------
template <typename TA, int MODE>
__launch_bounds__(256)
__global__ void mfma_gemm(const TA* __restrict__ A, const bf16* __restrict__ Bt,
                          float* __restrict__ C, const bf16* __restrict__ aux,
                          int K, int kSeg, int lda, int ldb, int ldc,
                          long aZ, long bZ, long cZ) {
    constexpr bool DUAL = (MODE == 1);
    constexpr int TILES = DUAL ? 6 : 4;
    __shared__ __align__(16) short pool[TILES * 64 * 72];
    short (*As)[64][72] = (short(*)[64][72])pool;
    short (*Bs)[64][72] = (short(*)[64][72])(pool + 2 * 64 * 72);
    short (*Ms)[64][72] = (short(*)[64][72])(pool + 4 * 64 * 72);

    int bx, by, z;
    if constexpr (MODE == 1) {
        const int bid  = blockIdx.x;
        z = bid & 7;
        const int rest = bid >> 3;      // 0..47
        bx = rest % 3;
        by = rest / 3;
    } else {
        bx = blockIdx.x; by = blockIdx.y; z = blockIdx.z;
    }

    const int tid = threadIdx.x;
    const int n0 = bx * 64, m0 = by * 64;
    const int srow = tid >> 2, sk = (tid & 3) * 16;
    const int lane = tid & 63, w = tid >> 6;
    const int l31 = lane & 31, lhi = lane >> 5;
    const int wm = (w >> 1) * 32, wn = (w & 1) * 32;

    int kBeg, kEnd, zh = 0;
    if constexpr (MODE == 1) {
        zh = z >> 1;
        const int seg = z & 1;
        A += aZ * zh;
        C += cZ * zh + bZ * seg;
        const int kc = (m0 + 64 < K) ? m0 + 64 : K;
        const int half0 = ((kc + 127) >> 7) << 6;   // ceil(kc/128)*64
        kBeg = seg ? half0 : 0;
        kEnd = seg ? kc : half0;
    } else if constexpr (MODE == 2) {
        A += aZ * z; Bt += bZ * z; C += cZ * z;
        kBeg = z * kSeg; kEnd = kBeg + kSeg;
    } else if constexpr (MODE == 3) {
        A += aZ * z; Bt += bZ * z; C += cZ * z;
        kBeg = 0; kEnd = (m0 + 64 < K) ? m0 + 64 : K;
    } else {
        A += aZ * z; Bt += bZ * z; C += cZ * z;
        kBeg = 0; kEnd = K;
    }

    const TA*   ga = A  + (size_t)(m0 + srow) * lda + sk;
    const bf16* gb = Bt + (size_t)(n0 + srow) * ldb + sk;

    auto msrc = [&](int k0) -> const bf16* {
        if (k0 == m0)
            return aux + (size_t)(zh * 16 + (m0 >> 6)) * 4096
                       + (size_t)srow * 64 + sk;
        return (const bf16*)A + (size_t)(k0 + srow) * lda + m0 + sk;
    };

    float4 f00, f01, f02, f03, f10, f11, f12, f13;
    u16x8 pa00, pa01, pa10, pa11, pb00, pb01, pb10, pb11;
    u16x8 pm00, pm01, pm10, pm11;
    auto load0 = [&](int k0) {
        if constexpr (__is_same(TA, float)) {
            f00 = *(const float4*)(ga + k0);
            f01 = *(const float4*)(ga + k0 + 4);
            f02 = *(const float4*)(ga + k0 + 8);
            f03 = *(const float4*)(ga + k0 + 12);
        } else {
            pa00 = *(const u16x8*)(ga + k0);
            pa01 = *(const u16x8*)(ga + k0 + 8);
        }
        pb00 = *(const u16x8*)(gb + k0);
        pb01 = *(const u16x8*)(gb + k0 + 8);
        if constexpr (DUAL) {
            const bf16* ms = msrc(k0);
            pm00 = *(const u16x8*)ms;
            pm01 = *(const u16x8*)(ms + 8);
        }
    };
    auto load1 = [&](int k0) {
        if constexpr (__is_same(TA, float)) {
            f10 = *(const float4*)(ga + k0);
            f11 = *(const float4*)(ga + k0 + 4);
            f12 = *(const float4*)(ga + k0 + 8);
            f13 = *(const float4*)(ga + k0 + 12);
        } else {
            pa10 = *(const u16x8*)(ga + k0);
            pa11 = *(const u16x8*)(ga + k0 + 8);
        }
        pb10 = *(const u16x8*)(gb + k0);
        pb11 = *(const u16x8*)(gb + k0 + 8);
        if constexpr (DUAL) {
            const bf16* ms = msrc(k0);
            pm10 = *(const u16x8*)ms;
            pm11 = *(const u16x8*)(ms + 8);
        }
    };
    auto dep0 = [&](int buf) {
        if constexpr (__is_same(TA, float)) {
            u16x8 o0, o1;
            o0[0] = f2us(f00.x); o0[1] = f2us(f00.y); o0[2] = f2us(f00.z); o0[3] = f2us(f00.w);
            o0[4] = f2us(f01.x); o0[5] = f2us(f01.y); o0[6] = f2us(f01.z); o0[7] = f2us(f01.w);
            o1[0] = f2us(f02.x); o1[1] = f2us(f02.y); o1[2] = f2us(f02.z); o1[3] = f2us(f02.w);
            o1[4] = f2us(f03.x); o1[5] = f2us(f03.y); o1[6] = f2us(f03.z); o1[7] = f2us(f03.w);
            *(u16x8*)&As[buf][srow][sk]     = o0;
            *(u16x8*)&As[buf][srow][sk + 8] = o1;
        } else {
            *(u16x8*)&As[buf][srow][sk]     = pa00;
            *(u16x8*)&As[buf][srow][sk + 8] = pa01;
        }
        *(u16x8*)&Bs[buf][srow][sk]     = pb00;
        *(u16x8*)&Bs[buf][srow][sk + 8] = pb01;
        if constexpr (DUAL) {
            *(u16x8*)&Ms[buf][srow][sk]     = pm00;
            *(u16x8*)&Ms[buf][srow][sk + 8] = pm01;
        }
    };
    auto dep1 = [&](int buf) {
        if constexpr (__is_same(TA, float)) {
            u16x8 o0, o1;
            o0[0] = f2us(f10.x); o0[1] = f2us(f10.y); o0[2] = f2us(f10.z); o0[3] = f2us(f10.w);
            o0[4] = f2us(f11.x); o0[5] = f2us(f11.y); o0[6] = f2us(f11.z); o0[7] = f2us(f11.w);
            o1[0] = f2us(f12.x); o1[1] = f2us(f12.y); o1[2] = f2us(f12.z); o1[3] = f2us(f12.w);
            o1[4] = f2us(f13.x); o1[5] = f2us(f13.y); o1[6] = f2us(f13.z); o1[7] = f2us(f13.w);
            *(u16x8*)&As[buf][srow][sk]     = o0;
            *(u16x8*)&As[buf][srow][sk + 8] = o1;
        } else {
            *(u16x8*)&As[buf][srow][sk]     = pa10;
            *(u16x8*)&As[buf][srow][sk + 8] = pa11;
        }
        *(u16x8*)&Bs[buf][srow][sk]     = pb10;
        *(u16x8*)&Bs[buf][srow][sk + 8] = pb11;
        if constexpr (DUAL) {
            *(u16x8*)&Ms[buf][srow][sk]     = pm10;
            *(u16x8*)&Ms[buf][srow][sk + 8] = pm11;
        }
    };

    f32x16 acc, acc2;
    #pragma unroll
    for (int r = 0; r < 16; r++) { acc[r] = 0.f; acc2[r] = 0.f; }

    auto mfma_step = [&](int buf) {
        #pragma unroll
        for (int ks = 0; ks < 4; ks++) {
            s16x8 a = *(const s16x8*)&As[buf][wm + l31][ks * 16 + lhi * 8];
            s16x8 b = *(const s16x8*)&Bs[buf][wn + l31][ks * 16 + lhi * 8];
            acc = __builtin_amdgcn_mfma_f32_32x32x16_bf16(a, b, acc, 0, 0, 0);
            if constexpr (DUAL) {
                s16x8 m2 = *(const s16x8*)&Ms[buf][wm + l31][ks * 16 + lhi * 8];
                acc2 = __builtin_amdgcn_mfma_f32_32x32x16_bf16(m2, b, acc2, 0, 0, 0);
            }
        }
    };

    const int NIT = (kEnd - kBeg) >> 6;
    load0(kBeg);
    load1(kBeg + 64);
    dep0(0);
    __syncthreads();

    for (int k = 0; k < NIT; k += 2) {
        if (k + 2 < NIT) load0(kBeg + (k + 2) * 64);
        mfma_step(0);
        if (k + 1 < NIT) dep1(1);
        __syncthreads();
        if (k + 1 < NIT) {
            if (k + 3 < NIT) load1(kBeg + (k + 3) * 64);
            mfma_step(1);
            if (k + 2 < NIT) dep0(0);
            __syncthreads();
        }
    }

    #pragma unroll
    for (int r = 0; r < 16; r++) {
        int row = m0 + wm + (r & 3) + 8 * (r >> 2) + 4 * lhi;
        int col = n0 + wn + l31;
        float v = acc[r];
        if constexpr (DUAL) v += acc2[r];
        C[(size_t)row * ldc + col] = v;
    }
}

extern "C" void kernel_launch(void* const* d_in, const int* in_sizes, int n_in,
                              void* d_out, int out_size, void* d_ws, size_t ws_size,
                              hipStream_t stream) {
    const int*   idx   = (const int*)  d_in[0];
    const float* dec_x = (const float*)d_in[1];   // (NH, D, N)
    const float* dec_y = (const float*)d_in[2];   // (NH, D, N)
    const float* enc   = (const float*)d_in[3];   // (NH*N, D)
    const float* emb   = (const float*)d_in[4];   // (VOCAB, D)
    const float* pose  = (const float*)d_in[5];   // (BLOCK, D)
    const float* lmh   = (const float*)d_in[6];   // (D, VOCAB)
    float* out = (float*)d_out;                   // (T, VOCAB) fp32

    // workspace layout — identical to passing r11 (ws >= 84,377,600 proven)
    char* wp = (char*)d_ws;
    float*   x    = (float*)wp;              wp += (size_t)T_SEQ * D_DIM * 4;
    bf16*    xs   = (bf16*)wp;               wp += (size_t)T_SEQ * HN * 2;
    ushort2* csT  = (ushort2*)wp;            wp += (size_t)T_SEQ * NP2 * 4;
    bf16*    sc   = (bf16*)wp;               wp += (size_t)NHEAD * T_SEQ * T_SEQ * 2;
    float*   ykv  = (float*)wp;              wp += (size_t)NHEAD * T_SEQ * D_DIM * 4;
    float*   ymlp = (float*)wp;              wp += (size_t)T_SEQ * D_DIM * 4;   // dbuf home
    bf16*    xT   = (bf16*)wp;               wp += (size_t)D_DIM * T_SEQ * 2;
    bf16*    wX   = (bf16*)wp;               wp += (size_t)NHEAD * N_DIM * D_DIM * 2;
    bf16*    wY   = (bf16*)wp;               wp += (size_t)NHEAD * N_DIM * D_DIM * 2;
    bf16*    wE   = (bf16*)wp;               wp += (size_t)D_DIM * HN * 2;
    bf16*    wL   = (bf16*)wp;               wp += (size_t)VOCABSZ * D_DIM * 2;
    const size_t BASE_NEED = (size_t)(wp - (char*)d_ws);
    bf16*    qr   = (bf16*)wp;
    const size_t FULL_NEED = BASE_NEED + (size_t)T_SEQ * HN * 2;
    bf16*  dbuf  = (bf16*)ymlp;    // 512 KB diag partials on idle ymlp keeper

    if (ws_size < BASE_NEED) {
        fill_out<<<(out_size + 255) / 256, 256, 0, stream>>>(out, (float)ws_size, out_size);
        return;
    }
    const bool USE_QR = (ws_size >= FULL_NEED);

    // bf16 A-operand homes (main path): xb on dead sc head; ymlpP16 on qr
    // head; ykv slab1 fp32 on qr+12.6MB. Fallback: xb on ymlp keeper.
    bf16*  xb_main = (bf16*)sc;
    bf16*  xb_fb   = (bf16*)ymlp;
    float* ymlpP16 = (float*)qr;                               // 16 slabs
    float* ykvP1   = (float*)((char*)qr + (size_t)16 * T_SEQ * D_DIM * 4);
    float* ymlpP8  = (float*)sc;                               // fallback slabs

    bf16* xb = USE_QR ? xb_main : xb_fb;

    // weight mirrors (bf16, [n][k])
    t_cvt<<<dim3(48, 3, 4), 256, 0, stream>>>(dec_x, wX, D_DIM, N_DIM,
                                              (long)D_DIM * N_DIM, (long)N_DIM * D_DIM);
    t_cvt<<<dim3(48, 3, 4), 256, 0, stream>>>(dec_y, wY, D_DIM, N_DIM,
                                              (long)D_DIM * N_DIM, (long)N_DIM * D_DIM);
    t_cvt<<<dim3(3, 192, 1), 256, 0, stream>>>(enc, wE, HN, D_DIM, 0L, 0L);
    t_cvt<<<dim3(4, 3, 1), 256, 0, stream>>>(lmh, wL, D_DIM, VOCABSZ, 0L, 0L);

    k_tables<<<(T_SEQ * NP2) / 256, 256, 0, stream>>>(csT);
    // k_embed writes x, xb AND xT
    k_embed<<<T_SEQ, 64, 0, stream>>>(idx, emb, pose, x, xb, xT);

    for (int l = 0; l < NLAYER; ++l) {
        if (USE_QR) {
            // xs = relu(x @ dec_x), qr = rope(xs)
            dgemm128<1, true, bf16><<<dim3(96, 8), 256, 0, stream>>>(xb, wX, xs, qr, csT);
            // flat 1088, XCD-pinned (h,kh)
            scores64<<<dim3(1088), 256, 0, stream>>>(qr, sc, dbuf);
            // ykv = sc @ x  (causal, split-K=2, dual-A split-acc combine;
            // slab1 fp32 at qr+12.6MB; flat 384, XCD-pinned (h,seg))
            long segZ = (long)(ykvP1 - ykv);
            mfma_gemm<bf16, 1><<<dim3(384), 256, 0, stream>>>(
                sc, xT, ykv, dbuf, T_SEQ, 0, T_SEQ, T_SEQ, D_DIM,
                (long)T_SEQ * T_SEQ, segZ, (long)T_SEQ * D_DIM);
            // fused: ymlp slabs = (xs ⊙ relu(LN(slab0+slab1) @ decY)) @ enc
            gate_ymlp<<<dim3(256), 256, 0, stream>>>(ykv, ykvP1, wY, xs, wE, ymlpP16);
            // x = LN(x + LN(sum partials)); xb + xT refreshed
            k_resid<16><<<T_SEQ, 64, 0, stream>>>(x, ymlpP16, xb, xT);
        } else {
            dgemm128<1, false, bf16><<<dim3(96, 8), 256, 0, stream>>>(xb, wX, xs, qr, csT);
            scores_fused<<<dim3(16, 16, NHEAD), 256, 0, stream>>>(xs, csT, sc);
            mfma_gemm<bf16, 3><<<dim3(3, 16, NHEAD), 256, 0, stream>>>(
                sc, xT, ykv, nullptr, T_SEQ, 0, T_SEQ, T_SEQ, D_DIM,
                (long)T_SEQ * T_SEQ, 0L, (long)T_SEQ * D_DIM);
            k_ln<<<NHEAD * T_SEQ, 64, 0, stream>>>(ykv);
            dgemm128<2, false, float><<<dim3(96, 8), 256, 0, stream>>>(
                ykv, wY, xs, nullptr, nullptr);
            mfma_gemm<bf16, 2><<<dim3(3, 16, 8), 256, 0, stream>>>(
                xs, wE, ymlpP8, nullptr, HN, HN / 8, HN, HN, D_DIM,
                0L, 0L, (long)T_SEQ * D_DIM);
            k_resid<8><<<T_SEQ, 64, 0, stream>>>(x, ymlpP8, xb, xT);
        }
    }

    // logits = x @ lm_head
    mfma_gemm<float, 0><<<dim3(4, 16, 1), 256, 0, stream>>>(
        x, wL, out, nullptr, D_DIM, 0, D_DIM, D_DIM, VOCABSZ, 0L, 0L, 0L);
}